// Round 1
// baseline (620.871 us; speedup 1.0000x reference)
//
#include <hip/hip_runtime.h>
#include <hip/hip_bf16.h>

// ContextModule: context-biasing cross-attention + top-k re-attention + LN.
// f32 correctness-first pipeline. ws usage ~57 MB, every region written
// before read each call (graph-capture / re-poison safe).

typedef short short8v __attribute__((ext_vector_type(8)));

#define SCALE 0.08838834764831845f  // 1/sqrt(128)

// ---- ws layout (float offsets) ----
#define OFF_Q      ((size_t)0)                  // 8192x512
#define OFF_KC     ((size_t)4194304)            // 2000x512 (dead after scores gemm)
#define OFF_PART   (OFF_KC)                     // 256x2000
#define OFF_CS     (OFF_KC + 512000)            // 2048
#define OFF_IDX    (OFF_KC + 514048)            // 128 ints
#define OFF_CTXF   (OFF_KC + 514176)            // 101x512 (pad)
#define OFF_K2     (OFF_KC + 566400)            // 101x512 (pad)
#define OFF_V2     (OFF_KC + 618624)            // 101x512 (pad)
#define OFF_SC     ((size_t)5218304)            // scores 4x1024x2000 (dead after colsum)
#define OFF_O      (OFF_SC)                     // 8192x512 (reuses scores region)
#define OFF_TMP    (OFF_SC + 4194304)           // 8192x512
#define OFF_WOT    (OFF_SC + 8388608)           // 512x512
#define OFF_WC2    (OFF_WOT + 262144)           // 512x512
#define OFF_BC2    (OFF_WC2 + 262144)           // 512
// total = 14,131,712 floats = 56.5 MB

__device__ __forceinline__ float bf2f(short u) {
    union { float f; unsigned int i; } x;
    x.i = ((unsigned int)(unsigned short)u) << 16;
    return x.f;
}

// ---------------------------------------------------------------------------
// Generic tiled NT GEMM: C[m][n] = alpha * sum_k A[m][k]*W[n][k] (+ bias[n])
// 64x64 tile, 256 threads, 4x4 per thread, K multiple of 16.
// Optional batching over blockIdx.z via element strides sAz/sWz/sCz.
// ---------------------------------------------------------------------------
__global__ __launch_bounds__(256) void gemm_nt(
    const float* __restrict__ A, int lda, long long sAz,
    const float* __restrict__ W, int ldw, long long sWz,
    const float* __restrict__ bias,
    float* __restrict__ C, int ldc, long long sCz,
    int M, int N, int K, float alpha)
{
    // [k][m] / [k][n] layout, row stride 68 floats (16B-aligned, conflict-light)
    __shared__ __align__(16) float Ast[16][68];
    __shared__ __align__(16) float Bst[16][68];
    const int tid = threadIdx.x;
    const int tx = tid & 15, ty = tid >> 4;
    const int r = tid >> 2;            // 0..63
    const int c4 = (tid & 3) << 2;     // 0,4,8,12
    const int bm = blockIdx.y * 64, bn = blockIdx.x * 64;
    A += (size_t)blockIdx.z * (size_t)sAz;
    W += (size_t)blockIdx.z * (size_t)sWz;
    C += (size_t)blockIdx.z * (size_t)sCz;

    float acc[4][4];
    #pragma unroll
    for (int i = 0; i < 4; ++i)
        #pragma unroll
        for (int j = 0; j < 4; ++j) acc[i][j] = 0.f;

    for (int k0 = 0; k0 < K; k0 += 16) {
        float4 av = make_float4(0.f, 0.f, 0.f, 0.f);
        float4 wv = make_float4(0.f, 0.f, 0.f, 0.f);
        const int gm = bm + r;
        const int gn = bn + r;
        if (gm < M) av = *(const float4*)(A + (size_t)gm * lda + k0 + c4);
        if (gn < N) wv = *(const float4*)(W + (size_t)gn * ldw + k0 + c4);
        __syncthreads();   // previous tile fully consumed before overwrite
        Ast[c4 + 0][r] = av.x; Ast[c4 + 1][r] = av.y;
        Ast[c4 + 2][r] = av.z; Ast[c4 + 3][r] = av.w;
        Bst[c4 + 0][r] = wv.x; Bst[c4 + 1][r] = wv.y;
        Bst[c4 + 2][r] = wv.z; Bst[c4 + 3][r] = wv.w;
        __syncthreads();
        #pragma unroll
        for (int kk = 0; kk < 16; ++kk) {
            const float4 a = *(const float4*)&Ast[kk][ty << 2];
            const float4 b = *(const float4*)&Bst[kk][tx << 2];
            const float aa[4] = {a.x, a.y, a.z, a.w};
            const float bb4[4] = {b.x, b.y, b.z, b.w};
            #pragma unroll
            for (int i = 0; i < 4; ++i)
                #pragma unroll
                for (int j = 0; j < 4; ++j)
                    acc[i][j] += aa[i] * bb4[j];
        }
    }
    #pragma unroll
    for (int i = 0; i < 4; ++i) {
        const int gm = bm + (ty << 2) + i;
        if (gm >= M) continue;
        #pragma unroll
        for (int j = 0; j < 4; ++j) {
            const int gn = bn + (tx << 2) + j;
            if (gn >= N) continue;
            float v = acc[i][j] * alpha;
            if (bias) v += bias[gn];
            C[(size_t)gm * ldc + gn] = v;
        }
    }
}

// ---------------------------------------------------------------------------
// Stage-1 softmax over n=2000 per (h,t) row + per-wave partial column sums.
// grid 64 x 256; wave w of block b owns slot = b*4+w, rows slot*16..+15.
// Pure-shfl reductions, zero barriers in the hot loop. Deterministic.
// ---------------------------------------------------------------------------
__global__ __launch_bounds__(256) void softmax_colsum_kernel(
    const float* __restrict__ sc, float* __restrict__ part)
{
    const int wave = threadIdx.x >> 6, lane = threadIdx.x & 63;
    const int slot = blockIdx.x * 4 + wave;      // 0..255
    float acc[32];
    #pragma unroll
    for (int i = 0; i < 32; ++i) acc[i] = 0.f;
    for (int rr = 0; rr < 16; ++rr) {
        const float* row = sc + (size_t)(slot * 16 + rr) * 2000;
        float v[32];
        float m = -1e30f;
        #pragma unroll
        for (int i = 0; i < 32; ++i) {
            const int n = lane + 64 * i;
            v[i] = (n < 2000) ? row[n] : -1e30f;
            m = fmaxf(m, v[i]);
        }
        #pragma unroll
        for (int off = 32; off; off >>= 1) m = fmaxf(m, __shfl_xor(m, off));
        float sum = 0.f;
        #pragma unroll
        for (int i = 0; i < 32; ++i) { v[i] = __expf(v[i] - m); sum += v[i]; }
        #pragma unroll
        for (int off = 32; off; off >>= 1) sum += __shfl_xor(sum, off);
        const float inv = 1.f / sum;
        #pragma unroll
        for (int i = 0; i < 32; ++i) acc[i] += v[i] * inv;
    }
    float* p = part + (size_t)slot * 2000;
    #pragma unroll
    for (int i = 0; i < 32; ++i) {
        const int n = lane + 64 * i;
        if (n < 2000) p[n] = acc[i];
    }
}

__global__ void reduce_partials_kernel(const float* __restrict__ part,
                                       float* __restrict__ cs)
{
    const int n = blockIdx.x * 256 + threadIdx.x;
    if (n >= 2000) return;
    float s = 0.f;
    for (int sl = 0; sl < 256; ++sl) s += part[(size_t)sl * 2000 + n];
    cs[n] = s;
}

// ---------------------------------------------------------------------------
// Top-101 of 2000: single wave, iterative argmax, tie -> lowest index
// (matches jax.lax.top_k; downstream only needs the set anyway).
// ---------------------------------------------------------------------------
__global__ void topk_kernel(const float* __restrict__ cs, int* __restrict__ idx)
{
    __shared__ float scs[2048];
    const int lane = threadIdx.x;  // block of 64
    for (int n = lane; n < 2048; n += 64) scs[n] = (n < 2000) ? cs[n] : -1e30f;
    __syncthreads();
    for (int it = 0; it < 101; ++it) {
        float bv = -1e30f; int bi = 1 << 30;
        #pragma unroll
        for (int j = 0; j < 32; ++j) {
            const int n = lane + 64 * j;          // ascending: keeps lowest on tie
            const float v = scs[n];
            if (v > bv) { bv = v; bi = n; }
        }
        #pragma unroll
        for (int off = 32; off; off >>= 1) {
            const float ov = __shfl_xor(bv, off);
            const int oi = __shfl_xor(bi, off);
            if (ov > bv || (ov == bv && oi < bi)) { bv = ov; bi = oi; }
        }
        if (lane == 0) { idx[it] = bi; scs[bi] = -1e30f; }
        __syncthreads();
    }
}

__global__ void gather_kernel(const float* __restrict__ ce,
                              const int* __restrict__ idx,
                              float* __restrict__ ctxf)
{
    const int r = blockIdx.x;
    const int src = idx[r];
    const int tid = threadIdx.x;
    const float2 v = *(const float2*)(ce + (size_t)src * 512 + tid * 2);
    *(float2*)(ctxf + (size_t)r * 512 + tid * 2) = v;
}

__global__ void transpose512(const float* __restrict__ in, float* __restrict__ out)
{
    __shared__ float tile[32][33];
    const int tx = threadIdx.x & 31, ty = threadIdx.x >> 5;  // 32x8
    const int bx = blockIdx.x * 32, by = blockIdx.y * 32;
    #pragma unroll
    for (int rr = 0; rr < 4; ++rr)
        tile[ty + 8 * rr][tx] = in[(size_t)(by + ty + 8 * rr) * 512 + bx + tx];
    __syncthreads();
    #pragma unroll
    for (int rr = 0; rr < 4; ++rr)
        out[(size_t)(bx + ty + 8 * rr) * 512 + by + tx] = tile[tx][ty + 8 * rr];
}

__global__ void bc2_kernel(const float* __restrict__ wc, const float* __restrict__ bo,
                           const float* __restrict__ bcb, float* __restrict__ bc2)
{
    const int d = blockIdx.x * 256 + threadIdx.x;
    float s = bcb[d];
    const float4* wr = (const float4*)(wc + (size_t)d * 512);
    const float4* br = (const float4*)bo;
    for (int m4 = 0; m4 < 128; ++m4) {
        const float4 w4 = wr[m4], b4 = br[m4];
        s += w4.x * b4.x + w4.y * b4.y + w4.z * b4.z + w4.w * b4.w;
    }
    bc2[d] = s;
}

// ---------------------------------------------------------------------------
// Stage-2 attention over the 101 selected contexts, fused AV.
// Block = one (b,h) x 64 t's; K2/V2 head slices staged in LDS as bf16.
// K rows XOR-swizzled on 16B chunks to kill the stride-272B bank conflict.
// ---------------------------------------------------------------------------
__global__ __launch_bounds__(256) void attn2_kernel(
    const float* __restrict__ q, const float* __restrict__ k2,
    const float* __restrict__ v2, float* __restrict__ o)
{
    __shared__ __align__(16) __hip_bfloat16 ks[101][136];
    __shared__ __align__(16) __hip_bfloat16 vs[101][136];
    __shared__ float qs[4][128];
    const int tid = threadIdx.x, wave = tid >> 6, lane = tid & 63;
    const int bh = blockIdx.y, b = bh >> 2, h = bh & 3;
    const int t0 = blockIdx.x * 64 + wave * 16;

    for (int e = tid; e < 101 * 128; e += 256) {
        const int n = e >> 7, d = e & 127;
        const int c = d >> 3, dn = d & 7;
        ks[n][((c ^ (n & 7)) << 3) | dn] =
            __float2bfloat16(k2[(size_t)n * 512 + h * 128 + d]);
        vs[n][d] = __float2bfloat16(v2[(size_t)n * 512 + h * 128 + d]);
    }
    __syncthreads();
    const short* vsp = (const short*)vs;

    for (int tt = 0; tt < 16; ++tt) {
        const int t = t0 + tt;
        const float* qrow = q + ((size_t)(b * 1024 + t)) * 512 + h * 128;
        qs[wave][lane] = qrow[lane];
        qs[wave][lane + 64] = qrow[lane + 64];
        __syncthreads();

        const int n1 = (lane < 37) ? 64 + lane : 100;
        float s0 = 0.f, s1 = 0.f;
        #pragma unroll
        for (int c = 0; c < 16; ++c) {
            const short8v kv0 = *(const short8v*)&ks[lane][(c ^ (lane & 7)) << 3];
            const short8v kv1 = *(const short8v*)&ks[n1][(c ^ (n1 & 7)) << 3];
            #pragma unroll
            for (int j = 0; j < 8; ++j) {
                const float qd = qs[wave][(c << 3) + j];
                s0 += qd * bf2f(kv0[j]);
                s1 += qd * bf2f(kv1[j]);
            }
        }
        s0 *= SCALE; s1 *= SCALE;
        float m = (lane < 37) ? fmaxf(s0, s1) : s0;
        #pragma unroll
        for (int off = 32; off; off >>= 1) m = fmaxf(m, __shfl_xor(m, off));
        const float p0 = __expf(s0 - m);
        const float p1 = (lane < 37) ? __expf(s1 - m) : 0.f;
        float sum = p0 + p1;
        #pragma unroll
        for (int off = 32; off; off >>= 1) sum += __shfl_xor(sum, off);
        const float inv = 1.f / sum;
        const float a0 = p0 * inv, a1 = p1 * inv;

        float o0 = 0.f, o1 = 0.f;
        #pragma unroll
        for (int nn = 0; nn < 101; ++nn) {
            const float a = (nn < 64) ? __shfl(a0, nn) : __shfl(a1, nn - 64);
            o0 += a * bf2f(vsp[nn * 136 + lane]);
            o1 += a * bf2f(vsp[nn * 136 + 64 + lane]);
        }
        float* orow = o + ((size_t)(b * 1024 + t)) * 512 + h * 128;
        orow[lane] = o0;
        orow[lane + 64] = o1;
        __syncthreads();
    }
}

// ---------------------------------------------------------------------------
// Residual + LayerNorm: out = LN(tmp + enc) * g + b, per 512-wide row.
// ---------------------------------------------------------------------------
__global__ __launch_bounds__(256) void ln_kernel(
    const float* __restrict__ tmp, const float* __restrict__ enc,
    const float* __restrict__ g, const float* __restrict__ bta,
    float* __restrict__ out)
{
    __shared__ float rs[4], rv[4];
    const int row = blockIdx.x, tid = threadIdx.x;
    const int wave = tid >> 6, lane = tid & 63;
    const size_t base = (size_t)row * 512;
    const float x0 = tmp[base + tid] + enc[base + tid];
    const float x1 = tmp[base + tid + 256] + enc[base + tid + 256];
    float s = x0 + x1;
    #pragma unroll
    for (int off = 32; off; off >>= 1) s += __shfl_xor(s, off);
    if (lane == 0) rs[wave] = s;
    __syncthreads();
    const float mu = (rs[0] + rs[1] + rs[2] + rs[3]) * (1.f / 512.f);
    const float d0 = x0 - mu, d1 = x1 - mu;
    float vv = d0 * d0 + d1 * d1;
    #pragma unroll
    for (int off = 32; off; off >>= 1) vv += __shfl_xor(vv, off);
    if (lane == 0) rv[wave] = vv;
    __syncthreads();
    const float var = (rv[0] + rv[1] + rv[2] + rv[3]) * (1.f / 512.f);
    const float rstd = rsqrtf(var + 1e-5f);
    out[base + tid] = d0 * rstd * g[tid] + bta[tid];
    out[base + tid + 256] = d1 * rstd * g[tid + 256] + bta[tid + 256];
}

extern "C" void kernel_launch(void* const* d_in, const int* in_sizes, int n_in,
                              void* d_out, int out_size, void* d_ws, size_t ws_size,
                              hipStream_t stream)
{
    const float* ce  = (const float*)d_in[0];
    const float* enc = (const float*)d_in[1];
    const float* wq  = (const float*)d_in[2];
    const float* bq  = (const float*)d_in[3];
    const float* wk  = (const float*)d_in[4];
    const float* bk  = (const float*)d_in[5];
    const float* wv  = (const float*)d_in[6];
    const float* bv  = (const float*)d_in[7];
    const float* wo  = (const float*)d_in[8];
    const float* bo  = (const float*)d_in[9];
    const float* wc  = (const float*)d_in[10];
    const float* bcb = (const float*)d_in[11];
    const float* lng = (const float*)d_in[12];
    const float* lnb = (const float*)d_in[13];
    float* ws  = (float*)d_ws;
    float* out = (float*)d_out;

    float* q    = ws + OFF_Q;
    float* kc   = ws + OFF_KC;
    float* part = ws + OFF_PART;
    float* cs   = ws + OFF_CS;
    int*   idx  = (int*)(ws + OFF_IDX);
    float* ctxf = ws + OFF_CTXF;
    float* k2   = ws + OFF_K2;
    float* v2   = ws + OFF_V2;
    float* sc   = ws + OFF_SC;
    float* o    = ws + OFF_O;
    float* tmp  = ws + OFF_TMP;
    float* woT  = ws + OFF_WOT;
    float* Wc2  = ws + OFF_WC2;
    float* bc2  = ws + OFF_BC2;

    // q = enc @ wq^T + bq            [8192,512]
    gemm_nt<<<dim3(8, 128, 1), 256, 0, stream>>>(enc, 512, 0, wq, 512, 0, bq,
                                                 q, 512, 0, 8192, 512, 512, 1.f);
    // kc = ctx @ wk^T + bk           [2000,512] (batch-independent)
    gemm_nt<<<dim3(8, 32, 1), 256, 0, stream>>>(ce, 512, 0, wk, 512, 0, bk,
                                                kc, 512, 0, 2000, 512, 512, 1.f);
    // stage-1 scores, b=0 only, batched over heads: [4][1024][2000]
    gemm_nt<<<dim3(32, 16, 4), 256, 0, stream>>>(q, 512, 128, kc, 512, 128, nullptr,
                                                 sc, 2000, 2048000LL,
                                                 1024, 2000, 128, SCALE);
    softmax_colsum_kernel<<<64, 256, 0, stream>>>(sc, part);
    reduce_partials_kernel<<<8, 256, 0, stream>>>(part, cs);
    topk_kernel<<<1, 64, 0, stream>>>(cs, idx);
    gather_kernel<<<101, 256, 0, stream>>>(ce, idx, ctxf);
    // k2/v2 projections of the 101 selected contexts
    gemm_nt<<<dim3(8, 2, 1), 256, 0, stream>>>(ctxf, 512, 0, wk, 512, 0, bk,
                                               k2, 512, 0, 101, 512, 512, 1.f);
    gemm_nt<<<dim3(8, 2, 1), 256, 0, stream>>>(ctxf, 512, 0, wv, 512, 0, bv,
                                               v2, 512, 0, 101, 512, 512, 1.f);
    // fold wo/w_comb: Wc2 = wc @ wo, bc2 = wc @ bo + bc
    transpose512<<<dim3(16, 16), 256, 0, stream>>>(wo, woT);
    bc2_kernel<<<2, 256, 0, stream>>>(wc, bo, bcb, bc2);
    gemm_nt<<<dim3(8, 8, 1), 256, 0, stream>>>(wc, 512, 0, woT, 512, 0, nullptr,
                                               Wc2, 512, 0, 512, 512, 512, 1.f);
    // stage-2 attention (softmax over 101) + AV, per (b,h) x 64 t's
    attn2_kernel<<<dim3(16, 32), 256, 0, stream>>>(q, k2, v2, o);
    // combined output projection: tmp = o @ Wc2^T + bc2
    gemm_nt<<<dim3(8, 128, 1), 256, 0, stream>>>(o, 512, 0, Wc2, 512, 0, bc2,
                                                 tmp, 512, 0, 8192, 512, 512, 1.f);
    // residual + LayerNorm
    ln_kernel<<<8192, 256, 0, stream>>>(tmp, enc, lng, lnb, out);
    (void)in_sizes; (void)n_in; (void)out_size; (void)ws_size;
}

// Round 3
// 570.630 us; speedup vs baseline: 1.0880x; 1.0880x over previous
//
#include <hip/hip_runtime.h>
#include <hip/hip_bf16.h>

// ContextModule: context-biasing cross-attention + top-k re-attention + LN.
// R3: = R2 + fix vs OOB read (pad V rows 101..103 to finite zeros; 0*NaN bug).
// ws usage 56.5 MB, every region written before read each call.

typedef short short8v __attribute__((ext_vector_type(8)));

#define SCALE 0.08838834764831845f  // 1/sqrt(128)

// ---- ws layout (float offsets) ----
#define OFF_Q      ((size_t)0)                  // 8192x512
#define OFF_KC     ((size_t)4194304)            // 2000x512 (dead after scores gemm)
#define OFF_PART   (OFF_KC)                     // 512x2000 = 1,024,000 (aliases kc)
#define OFF_SC     ((size_t)5218304)            // scores 4x1024x2000 (dead after colsum)
#define OFF_O      (OFF_SC)                     // 8192x512 (aliases scores)
#define OFF_TMP    (OFF_SC + 4194304)           // 8192x512 (written last; early aliases below)
#define OFF_PART2  (OFF_TMP)                    // 4x2000 (dead before tmp written)
#define OFF_IDX    (OFF_TMP + 8192)             // 128 ints
#define OFF_CTXF   (OFF_TMP + 8320)             // 101x512 (pad)
#define OFF_K2     (OFF_TMP + 60544)            // 101x512 (pad)
#define OFF_V2     (OFF_TMP + 112768)           // 101x512 (pad)
#define OFF_WOT    (OFF_SC + 8388608)           // 512x512
#define OFF_WC2    (OFF_WOT + 262144)           // 512x512
#define OFF_BC2    (OFF_WC2 + 262144)           // 512
// total = 14,131,712 floats = 56.5 MB

__device__ __forceinline__ float bf2f(short u) {
    union { float f; unsigned int i; } x;
    x.i = ((unsigned int)(unsigned short)u) << 16;
    return x.f;
}

// ---------------------------------------------------------------------------
// Generic tiled NT GEMM: C[m][n] = alpha * sum_k A[m][k]*W[n][k] (+ bias[n])
// 64x64 tile, 256 threads, 4x4 per thread, K multiple of 16.
// ---------------------------------------------------------------------------
__global__ __launch_bounds__(256) void gemm_nt(
    const float* __restrict__ A, int lda, long long sAz,
    const float* __restrict__ W, int ldw, long long sWz,
    const float* __restrict__ bias,
    float* __restrict__ C, int ldc, long long sCz,
    int M, int N, int K, float alpha)
{
    __shared__ __align__(16) float Ast[16][68];
    __shared__ __align__(16) float Bst[16][68];
    const int tid = threadIdx.x;
    const int tx = tid & 15, ty = tid >> 4;
    const int r = tid >> 2;            // 0..63
    const int c4 = (tid & 3) << 2;     // 0,4,8,12
    const int bm = blockIdx.y * 64, bn = blockIdx.x * 64;
    A += (size_t)blockIdx.z * (size_t)sAz;
    W += (size_t)blockIdx.z * (size_t)sWz;
    C += (size_t)blockIdx.z * (size_t)sCz;

    float acc[4][4];
    #pragma unroll
    for (int i = 0; i < 4; ++i)
        #pragma unroll
        for (int j = 0; j < 4; ++j) acc[i][j] = 0.f;

    for (int k0 = 0; k0 < K; k0 += 16) {
        float4 av = make_float4(0.f, 0.f, 0.f, 0.f);
        float4 wv = make_float4(0.f, 0.f, 0.f, 0.f);
        const int gm = bm + r;
        const int gn = bn + r;
        if (gm < M) av = *(const float4*)(A + (size_t)gm * lda + k0 + c4);
        if (gn < N) wv = *(const float4*)(W + (size_t)gn * ldw + k0 + c4);
        __syncthreads();
        Ast[c4 + 0][r] = av.x; Ast[c4 + 1][r] = av.y;
        Ast[c4 + 2][r] = av.z; Ast[c4 + 3][r] = av.w;
        Bst[c4 + 0][r] = wv.x; Bst[c4 + 1][r] = wv.y;
        Bst[c4 + 2][r] = wv.z; Bst[c4 + 3][r] = wv.w;
        __syncthreads();
        #pragma unroll
        for (int kk = 0; kk < 16; ++kk) {
            const float4 a = *(const float4*)&Ast[kk][ty << 2];
            const float4 b = *(const float4*)&Bst[kk][tx << 2];
            const float aa[4] = {a.x, a.y, a.z, a.w};
            const float bb4[4] = {b.x, b.y, b.z, b.w};
            #pragma unroll
            for (int i = 0; i < 4; ++i)
                #pragma unroll
                for (int j = 0; j < 4; ++j)
                    acc[i][j] += aa[i] * bb4[j];
        }
    }
    #pragma unroll
    for (int i = 0; i < 4; ++i) {
        const int gm = bm + (ty << 2) + i;
        if (gm >= M) continue;
        #pragma unroll
        for (int j = 0; j < 4; ++j) {
            const int gn = bn + (tx << 2) + j;
            if (gn >= N) continue;
            float v = acc[i][j] * alpha;
            if (bias) v += bias[gn];
            C[(size_t)gm * ldc + gn] = v;
        }
    }
}

// ---------------------------------------------------------------------------
// Stage-1 softmax over n=2000 per (h,t) row + per-wave partial column sums.
// 128 blocks x 4 waves = 512 slots x 8 rows. Pure-shfl, no barriers.
// ---------------------------------------------------------------------------
__global__ __launch_bounds__(256) void softmax_colsum_kernel(
    const float* __restrict__ sc, float* __restrict__ part)
{
    const int wave = threadIdx.x >> 6, lane = threadIdx.x & 63;
    const int slot = blockIdx.x * 4 + wave;      // 0..511
    float acc[32];
    #pragma unroll
    for (int i = 0; i < 32; ++i) acc[i] = 0.f;
    for (int rr = 0; rr < 8; ++rr) {
        const float* row = sc + (size_t)(slot * 8 + rr) * 2000;
        float v[32];
        float m = -1e30f;
        #pragma unroll
        for (int i = 0; i < 32; ++i) {
            const int n = lane + 64 * i;
            v[i] = (n < 2000) ? row[n] : -1e30f;
            m = fmaxf(m, v[i]);
        }
        #pragma unroll
        for (int off = 32; off; off >>= 1) m = fmaxf(m, __shfl_xor(m, off));
        float sum = 0.f;
        #pragma unroll
        for (int i = 0; i < 32; ++i) { v[i] = __expf(v[i] - m); sum += v[i]; }
        #pragma unroll
        for (int off = 32; off; off >>= 1) sum += __shfl_xor(sum, off);
        const float inv = 1.f / sum;
        #pragma unroll
        for (int i = 0; i < 32; ++i) acc[i] += v[i] * inv;
    }
    float* p = part + (size_t)slot * 2000;
    #pragma unroll
    for (int i = 0; i < 32; ++i) {
        const int n = lane + 64 * i;
        if (n < 2000) p[n] = acc[i];
    }
}

// part[512][2000] -> part2[4][2000]; grid (8,4)
__global__ void reduce_partials_kernel(const float* __restrict__ part,
                                       float* __restrict__ part2)
{
    const int n = blockIdx.x * 256 + threadIdx.x;
    if (n >= 2000) return;
    const int q = blockIdx.y;
    float s = 0.f;
    for (int sl = q * 128; sl < q * 128 + 128; ++sl) s += part[(size_t)sl * 2000 + n];
    part2[(size_t)q * 2000 + n] = s;
}

// ---------------------------------------------------------------------------
// Top-101 of 2000 (sums the 4 part2 slices on load). 256 threads.
// Iterative argmax, tie -> lowest index (matches jax.lax.top_k).
// ---------------------------------------------------------------------------
__global__ __launch_bounds__(256) void topk_kernel(const float* __restrict__ part2,
                                                   int* __restrict__ idx)
{
    __shared__ float scs[2048];
    __shared__ float bvw[4];
    __shared__ int biw[4];
    const int tid = threadIdx.x, wave = tid >> 6, lane = tid & 63;
    for (int n = tid; n < 2048; n += 256)
        scs[n] = (n < 2000)
            ? part2[n] + part2[2000 + n] + part2[4000 + n] + part2[6000 + n]
            : -1e30f;
    __syncthreads();
    for (int it = 0; it < 101; ++it) {
        float bv = -1e30f; int bi = 1 << 30;
        #pragma unroll
        for (int j = 0; j < 8; ++j) {
            const int n = tid + 256 * j;
            const float v = scs[n];
            if (v > bv) { bv = v; bi = n; }
        }
        #pragma unroll
        for (int off = 32; off; off >>= 1) {
            const float ov = __shfl_xor(bv, off);
            const int oi = __shfl_xor(bi, off);
            if (ov > bv || (ov == bv && oi < bi)) { bv = ov; bi = oi; }
        }
        if (lane == 0) { bvw[wave] = bv; biw[wave] = bi; }
        __syncthreads();
        if (tid == 0) {
            float fv = bvw[0]; int fi = biw[0];
            #pragma unroll
            for (int w = 1; w < 4; ++w)
                if (bvw[w] > fv || (bvw[w] == fv && biw[w] < fi)) { fv = bvw[w]; fi = biw[w]; }
            idx[it] = fi; scs[fi] = -1e30f;
        }
        __syncthreads();
    }
}

__global__ void gather_kernel(const float* __restrict__ ce,
                              const int* __restrict__ idx,
                              float* __restrict__ ctxf)
{
    const int r = blockIdx.x;
    const int src = idx[r];
    const int tid = threadIdx.x;
    const float2 v = *(const float2*)(ce + (size_t)src * 512 + tid * 2);
    *(float2*)(ctxf + (size_t)r * 512 + tid * 2) = v;
}

__global__ void transpose512(const float* __restrict__ in, float* __restrict__ out)
{
    __shared__ float tile[32][33];
    const int tx = threadIdx.x & 31, ty = threadIdx.x >> 5;  // 32x8
    const int bx = blockIdx.x * 32, by = blockIdx.y * 32;
    #pragma unroll
    for (int rr = 0; rr < 4; ++rr)
        tile[ty + 8 * rr][tx] = in[(size_t)(by + ty + 8 * rr) * 512 + bx + tx];
    __syncthreads();
    #pragma unroll
    for (int rr = 0; rr < 4; ++rr)
        out[(size_t)(bx + ty + 8 * rr) * 512 + by + tx] = tile[tx][ty + 8 * rr];
}

__global__ void bc2_kernel(const float* __restrict__ wc, const float* __restrict__ bo,
                           const float* __restrict__ bcb, float* __restrict__ bc2)
{
    const int d = blockIdx.x * 256 + threadIdx.x;
    float s = bcb[d];
    const float4* wr = (const float4*)(wc + (size_t)d * 512);
    const float4* br = (const float4*)bo;
    for (int m4 = 0; m4 < 128; ++m4) {
        const float4 w4 = wr[m4], b4 = br[m4];
        s += w4.x * b4.x + w4.y * b4.y + w4.z * b4.z + w4.w * b4.w;
    }
    bc2[d] = s;
}

// ---------------------------------------------------------------------------
// Stage-2 attention over 101 selected contexts, fused AV.
// Block = one (b,h) x 64 t's (4 waves x 16 t). K/V staged bf16 in LDS.
// ks: row stride 256B + chunk swizzle c^(n&7) -> b128 conflict floor.
// vs: [104][128], rows 101..103 zero-padded (AV float4 loop covers 104).
// NO barriers in the t-loop: qs/as are wave-private.
// ---------------------------------------------------------------------------
__global__ __launch_bounds__(256) void attn2_kernel(
    const float* __restrict__ q, const float* __restrict__ k2,
    const float* __restrict__ v2, float* __restrict__ o)
{
    __shared__ __align__(16) __hip_bfloat16 ks[101 * 128];
    __shared__ __align__(16) __hip_bfloat16 vs[104 * 128];
    __shared__ float qs[4][128];
    __shared__ float as[4][104];
    const int tid = threadIdx.x, wave = tid >> 6, lane = tid & 63;
    const int bh = blockIdx.y, b = bh >> 2, h = bh & 3;
    const int t0 = blockIdx.x * 64 + wave * 16;

    for (int e = tid; e < 101 * 128; e += 256) {
        const int n = e >> 7, d = e & 127;
        const int c = d >> 3;
        ks[n * 128 + (((c ^ (n & 7)) << 3) | (d & 7))] =
            __float2bfloat16(k2[(size_t)n * 512 + h * 128 + d]);
        vs[e] = __float2bfloat16(v2[(size_t)n * 512 + h * 128 + d]);
    }
    for (int e = tid; e < 3 * 128; e += 256)
        vs[101 * 128 + e] = __float2bfloat16(0.f);   // finite pad rows 101..103
    if (lane >= 37 && lane < 40) as[wave][64 + lane] = 0.f;  // pad 101..103
    __syncthreads();
    const unsigned int* vsp = (const unsigned int*)vs;

    for (int tt = 0; tt < 16; ++tt) {
        const int t = t0 + tt;
        const float* qrow = q + ((size_t)(b * 1024 + t)) * 512 + h * 128;
        qs[wave][lane] = qrow[lane];
        qs[wave][lane + 64] = qrow[lane + 64];
        // same-wave LDS write->read: in-order per wave, no barrier needed

        const int n1 = (lane < 37) ? 64 + lane : 100;
        float s0 = 0.f, s1 = 0.f;
        #pragma unroll
        for (int c = 0; c < 16; ++c) {
            const short8v kv0 = *(const short8v*)&ks[lane * 128 + ((c ^ (lane & 7)) << 3)];
            const short8v kv1 = *(const short8v*)&ks[n1 * 128 + ((c ^ (n1 & 7)) << 3)];
            const float4 qa = *(const float4*)&qs[wave][c * 8];
            const float4 qb = *(const float4*)&qs[wave][c * 8 + 4];
            s0 += qa.x * bf2f(kv0[0]) + qa.y * bf2f(kv0[1])
                + qa.z * bf2f(kv0[2]) + qa.w * bf2f(kv0[3])
                + qb.x * bf2f(kv0[4]) + qb.y * bf2f(kv0[5])
                + qb.z * bf2f(kv0[6]) + qb.w * bf2f(kv0[7]);
            s1 += qa.x * bf2f(kv1[0]) + qa.y * bf2f(kv1[1])
                + qa.z * bf2f(kv1[2]) + qa.w * bf2f(kv1[3])
                + qb.x * bf2f(kv1[4]) + qb.y * bf2f(kv1[5])
                + qb.z * bf2f(kv1[6]) + qb.w * bf2f(kv1[7]);
        }
        s0 *= SCALE; s1 *= SCALE;
        float m = (lane < 37) ? fmaxf(s0, s1) : s0;
        #pragma unroll
        for (int off = 32; off; off >>= 1) m = fmaxf(m, __shfl_xor(m, off));
        const float p0 = __expf(s0 - m);
        const float p1 = (lane < 37) ? __expf(s1 - m) : 0.f;
        float sum = p0 + p1;
        #pragma unroll
        for (int off = 32; off; off >>= 1) sum += __shfl_xor(sum, off);
        const float inv = 1.f / sum;
        as[wave][lane] = p0 * inv;
        if (lane < 37) as[wave][64 + lane] = p1 * inv;

        float o0 = 0.f, o1 = 0.f;
        #pragma unroll
        for (int c26 = 0; c26 < 26; ++c26) {
            const float4 a4 = *(const float4*)&as[wave][c26 * 4];
            const float aa[4] = {a4.x, a4.y, a4.z, a4.w};
            #pragma unroll
            for (int j = 0; j < 4; ++j) {
                const unsigned int vv = vsp[(c26 * 4 + j) * 64 + lane];
                o0 += aa[j] * bf2f((short)(vv & 0xffff));
                o1 += aa[j] * bf2f((short)(vv >> 16));
            }
        }
        float2 ov; ov.x = o0; ov.y = o1;
        *(float2*)(o + ((size_t)(b * 1024 + t)) * 512 + h * 128 + 2 * lane) = ov;
    }
}

// ---------------------------------------------------------------------------
// Residual + LayerNorm: out = LN(tmp + enc) * g + b, per 512-wide row.
// ---------------------------------------------------------------------------
__global__ __launch_bounds__(256) void ln_kernel(
    const float* __restrict__ tmp, const float* __restrict__ enc,
    const float* __restrict__ g, const float* __restrict__ bta,
    float* __restrict__ out)
{
    __shared__ float rs[4], rv[4];
    const int row = blockIdx.x, tid = threadIdx.x;
    const int wave = tid >> 6, lane = tid & 63;
    const size_t base = (size_t)row * 512;
    const float x0 = tmp[base + tid] + enc[base + tid];
    const float x1 = tmp[base + tid + 256] + enc[base + tid + 256];
    float s = x0 + x1;
    #pragma unroll
    for (int off = 32; off; off >>= 1) s += __shfl_xor(s, off);
    if (lane == 0) rs[wave] = s;
    __syncthreads();
    const float mu = (rs[0] + rs[1] + rs[2] + rs[3]) * (1.f / 512.f);
    const float d0 = x0 - mu, d1 = x1 - mu;
    float vv = d0 * d0 + d1 * d1;
    #pragma unroll
    for (int off = 32; off; off >>= 1) vv += __shfl_xor(vv, off);
    if (lane == 0) rv[wave] = vv;
    __syncthreads();
    const float var = (rv[0] + rv[1] + rv[2] + rv[3]) * (1.f / 512.f);
    const float rstd = rsqrtf(var + 1e-5f);
    out[base + tid] = d0 * rstd * g[tid] + bta[tid];
    out[base + tid + 256] = d1 * rstd * g[tid + 256] + bta[tid + 256];
}

extern "C" void kernel_launch(void* const* d_in, const int* in_sizes, int n_in,
                              void* d_out, int out_size, void* d_ws, size_t ws_size,
                              hipStream_t stream)
{
    const float* ce  = (const float*)d_in[0];
    const float* enc = (const float*)d_in[1];
    const float* wq  = (const float*)d_in[2];
    const float* bq  = (const float*)d_in[3];
    const float* wk  = (const float*)d_in[4];
    const float* bk  = (const float*)d_in[5];
    const float* wv  = (const float*)d_in[6];
    const float* bv  = (const float*)d_in[7];
    const float* wo  = (const float*)d_in[8];
    const float* bo  = (const float*)d_in[9];
    const float* wc  = (const float*)d_in[10];
    const float* bcb = (const float*)d_in[11];
    const float* lng = (const float*)d_in[12];
    const float* lnb = (const float*)d_in[13];
    float* ws  = (float*)d_ws;
    float* out = (float*)d_out;

    float* q     = ws + OFF_Q;
    float* kc    = ws + OFF_KC;
    float* part  = ws + OFF_PART;
    float* part2 = ws + OFF_PART2;
    int*   idx   = (int*)(ws + OFF_IDX);
    float* ctxf  = ws + OFF_CTXF;
    float* k2    = ws + OFF_K2;
    float* v2    = ws + OFF_V2;
    float* sc    = ws + OFF_SC;
    float* o     = ws + OFF_O;
    float* tmp   = ws + OFF_TMP;
    float* woT   = ws + OFF_WOT;
    float* Wc2   = ws + OFF_WC2;
    float* bc2   = ws + OFF_BC2;

    // q = enc @ wq^T + bq            [8192,512]
    gemm_nt<<<dim3(8, 128, 1), 256, 0, stream>>>(enc, 512, 0, wq, 512, 0, bq,
                                                 q, 512, 0, 8192, 512, 512, 1.f);
    // kc = ctx @ wk^T + bk           [2000,512] (batch-independent)
    gemm_nt<<<dim3(8, 32, 1), 256, 0, stream>>>(ce, 512, 0, wk, 512, 0, bk,
                                                kc, 512, 0, 2000, 512, 512, 1.f);
    // stage-1 scores, b=0 only, batched over heads: [4][1024][2000]
    gemm_nt<<<dim3(32, 16, 4), 256, 0, stream>>>(q, 512, 128, kc, 512, 128, nullptr,
                                                 sc, 2000, 2048000LL,
                                                 1024, 2000, 128, SCALE);
    softmax_colsum_kernel<<<128, 256, 0, stream>>>(sc, part);
    reduce_partials_kernel<<<dim3(8, 4), 256, 0, stream>>>(part, part2);
    topk_kernel<<<1, 256, 0, stream>>>(part2, idx);
    gather_kernel<<<101, 256, 0, stream>>>(ce, idx, ctxf);
    // k2/v2 projections of the 101 selected contexts
    gemm_nt<<<dim3(8, 2, 1), 256, 0, stream>>>(ctxf, 512, 0, wk, 512, 0, bk,
                                               k2, 512, 0, 101, 512, 512, 1.f);
    gemm_nt<<<dim3(8, 2, 1), 256, 0, stream>>>(ctxf, 512, 0, wv, 512, 0, bv,
                                               v2, 512, 0, 101, 512, 512, 1.f);
    // fold wo/w_comb: Wc2 = wc @ wo, bc2 = wc @ bo + bc
    transpose512<<<dim3(16, 16), 256, 0, stream>>>(wo, woT);
    bc2_kernel<<<2, 256, 0, stream>>>(wc, bo, bcb, bc2);
    gemm_nt<<<dim3(8, 8, 1), 256, 0, stream>>>(wc, 512, 0, woT, 512, 0, nullptr,
                                               Wc2, 512, 0, 512, 512, 512, 1.f);
    // stage-2 attention (softmax over 101) + AV, per (b,h) x 64 t's
    attn2_kernel<<<dim3(16, 32), 256, 0, stream>>>(q, k2, v2, o);
    // combined output projection: tmp = o @ Wc2^T + bc2
    gemm_nt<<<dim3(8, 128, 1), 256, 0, stream>>>(o, 512, 0, Wc2, 512, 0, bc2,
                                                 tmp, 512, 0, 8192, 512, 512, 1.f);
    // residual + LayerNorm
    ln_kernel<<<8192, 256, 0, stream>>>(tmp, enc, lng, lnb, out);
    (void)in_sizes; (void)n_in; (void)out_size; (void)ws_size;
}

// Round 4
// 463.975 us; speedup vs baseline: 1.3382x; 1.2299x over previous
//
#include <hip/hip_runtime.h>
#include <hip/hip_bf16.h>

// ContextModule R4: all large GEMMs -> bf16 MFMA (16x16x32), bf16 plumbing.
// ws 42.0 MB, every region written before read each call (replay-safe).

typedef short short8v __attribute__((ext_vector_type(8)));
typedef short bhalf8 __attribute__((ext_vector_type(8)));   // 8 bf16 = 4 VGPR
typedef float f32x4 __attribute__((ext_vector_type(4)));

#define SCALE 0.08838834764831845f  // 1/sqrt(128)

// ---- ws layout (float offsets) ----
#define OFF_QBF    ((size_t)0)              // q bf16 [8192][512] = 1,048,576 fl
#define OFF_SC     ((size_t)1048576)        // region 4,096,000 fl:
                                            //   enc_bf (1,048,576 fl) -> scores bf16
                                            //   [4][1024][2000] -> o_bf (2,097,152 fl)
#define OFF_KCBF   ((size_t)5144576)        // kc bf16 [2000][512] = 512,000 fl
#define OFF_TMP    ((size_t)5656576)        // tmp f32 [8192][512] = 4,194,304 fl
#define OFF_CEBF   (OFF_TMP)                //   ce_bf 512,000 fl (dead before part)
#define OFF_PART   (OFF_TMP)                //   part [512][2000] f32
#define OFF_PART2  (OFF_TMP + 1024000)      //   [4][2000]
#define OFF_IDX    (OFF_TMP + 1032000)      //   128 ints
#define OFF_CTXF   (OFF_TMP + 1032128)      //   101x512 f32
#define OFF_K2     (OFF_TMP + 1083840)      //   101x512 f32
#define OFF_V2     (OFF_TMP + 1135552)      //   101x512 f32
#define OFF_WQBF   ((size_t)9850880)        // 131,072 fl each below
#define OFF_WKBF   ((size_t)9981952)
#define OFF_WCBF   ((size_t)10113024)
#define OFF_WOTBF  ((size_t)10244096)
#define OFF_WC2BF  ((size_t)10375168)
#define OFF_BC2    ((size_t)10506240)       // 512
// total 10,506,752 fl = 42.0 MB (< 56.5 MB proven available)

__device__ __forceinline__ float bf2f(short u) {
    union { float f; unsigned int i; } x;
    x.i = ((unsigned int)(unsigned short)u) << 16;
    return x.f;
}
__device__ __forceinline__ ushort f2b(float f) {
    union { float f; unsigned int i; } x; x.f = f;
    return (ushort)((x.i + 0x7fff + ((x.i >> 16) & 1)) >> 16);  // RNE
}

// f32 -> bf16 bulk convert, 4 elems/thread
__global__ __launch_bounds__(256) void cvt_bf16_kernel(
    const float* __restrict__ in, ushort* __restrict__ out, int n4)
{
    const int i = blockIdx.x * 256 + threadIdx.x;
    if (i >= n4) return;
    const float4 v = ((const float4*)in)[i];
    ushort4 r;
    r.x = f2b(v.x); r.y = f2b(v.y); r.z = f2b(v.z); r.w = f2b(v.w);
    ((ushort4*)out)[i] = r;
}

// ---------------------------------------------------------------------------
// bf16 MFMA NT GEMM: C[m][n] = alpha*sum_k A[m][k]*W[n][k] (+bias[n])
// 128x128 tile, BK=32, 256 thr = 4 waves (2x2), wave tile 64x64 (4x4 frags).
// LDS row-major [128][32] bf16, 16B-chunk XOR swizzle (c ^ (row&3)):
// both ds_write_b128 and ds_read_b128 sit at the conflict-free b128 floor.
// Frag layouts (m89/m91-verified): A/B lane: row=l&15, k=(l>>4)*8+[0..7];
// C/D lane: col=l&15, row=(l>>4)*4+reg.
// ---------------------------------------------------------------------------
__global__ __launch_bounds__(256) void gemm_mfma(
    const ushort* __restrict__ A, int lda, long long sAz,
    const ushort* __restrict__ W, int ldw, long long sWz,
    const float* __restrict__ bias,
    float* __restrict__ C, ushort* __restrict__ Cbf,
    int ldc, long long sCz,
    int M, int N, int K, float alpha)
{
    __shared__ __align__(16) ushort As[128 * 32];
    __shared__ __align__(16) ushort Bs[128 * 32];
    const int tid = threadIdx.x;
    const int wave = tid >> 6, lane = tid & 63;
    const int wm = wave >> 1, wn = wave & 1;
    const int mr = lane & 15, g = lane >> 4;
    const int bm = blockIdx.y * 128, bn = blockIdx.x * 128;
    A += (size_t)blockIdx.z * (size_t)sAz;
    W += (size_t)blockIdx.z * (size_t)sWz;

    f32x4 acc[4][4];
    #pragma unroll
    for (int i = 0; i < 4; ++i)
        #pragma unroll
        for (int j = 0; j < 4; ++j)
            #pragma unroll
            for (int p = 0; p < 4; ++p) acc[i][j][p] = 0.f;

    const int r0 = tid >> 2;     // 0..63
    const int c0 = tid & 3;      // 16B chunk in 32-k row
    const int sw0 = (r0 * 4 + (c0 ^ (r0 & 3))) * 8;
    const int sw1 = ((r0 + 64) * 4 + (c0 ^ (r0 & 3))) * 8;
    const uint4 zz = make_uint4(0u, 0u, 0u, 0u);

    for (int k0 = 0; k0 < K; k0 += 32) {
        const int ka = k0 + c0 * 8;
        uint4 av0 = zz, av1 = zz, bv0 = zz, bv1 = zz;
        if (bm + r0 < M)      av0 = *(const uint4*)(A + (size_t)(bm + r0) * lda + ka);
        if (bm + r0 + 64 < M) av1 = *(const uint4*)(A + (size_t)(bm + r0 + 64) * lda + ka);
        if (bn + r0 < N)      bv0 = *(const uint4*)(W + (size_t)(bn + r0) * ldw + ka);
        if (bn + r0 + 64 < N) bv1 = *(const uint4*)(W + (size_t)(bn + r0 + 64) * ldw + ka);
        __syncthreads();   // previous tile fully consumed
        *(uint4*)&As[sw0] = av0;
        *(uint4*)&As[sw1] = av1;
        *(uint4*)&Bs[sw0] = bv0;
        *(uint4*)&Bs[sw1] = bv1;
        __syncthreads();
        bhalf8 a[4], b[4];
        const int ksw = (g ^ (mr & 3)) << 3;
        #pragma unroll
        for (int i = 0; i < 4; ++i)
            a[i] = *(const bhalf8*)&As[(wm * 64 + i * 16 + mr) * 32 + ksw];
        #pragma unroll
        for (int j = 0; j < 4; ++j)
            b[j] = *(const bhalf8*)&Bs[(wn * 64 + j * 16 + mr) * 32 + ksw];
        #pragma unroll
        for (int i = 0; i < 4; ++i)
            #pragma unroll
            for (int j = 0; j < 4; ++j)
                acc[i][j] = __builtin_amdgcn_mfma_f32_16x16x32_bf16(
                    a[i], b[j], acc[i][j], 0, 0, 0);
    }

    if (C)   C   += (size_t)blockIdx.z * (size_t)sCz;
    if (Cbf) Cbf += (size_t)blockIdx.z * (size_t)sCz;
    #pragma unroll
    for (int i = 0; i < 4; ++i) {
        #pragma unroll
        for (int j = 0; j < 4; ++j) {
            const int gn = bn + wn * 64 + j * 16 + mr;
            if (gn >= N) continue;
            const float bb = bias ? bias[gn] : 0.f;
            #pragma unroll
            for (int p = 0; p < 4; ++p) {
                const int gm = bm + wm * 64 + i * 16 + g * 4 + p;
                if (gm >= M) continue;
                const float v = acc[i][j][p] * alpha + bb;
                if (C)   C[(size_t)gm * ldc + gn] = v;
                if (Cbf) Cbf[(size_t)gm * ldc + gn] = f2b(v);
            }
        }
    }
}

// ---------------------------------------------------------------------------
// f32 tiled NT GEMM (kept for tiny 101-row k2/v2 projections)
// ---------------------------------------------------------------------------
__global__ __launch_bounds__(256) void gemm_nt(
    const float* __restrict__ A, int lda, long long sAz,
    const float* __restrict__ W, int ldw, long long sWz,
    const float* __restrict__ bias,
    float* __restrict__ C, int ldc, long long sCz,
    int M, int N, int K, float alpha)
{
    __shared__ __align__(16) float Ast[16][68];
    __shared__ __align__(16) float Bst[16][68];
    const int tid = threadIdx.x;
    const int tx = tid & 15, ty = tid >> 4;
    const int r = tid >> 2;
    const int c4 = (tid & 3) << 2;
    const int bm = blockIdx.y * 64, bn = blockIdx.x * 64;
    A += (size_t)blockIdx.z * (size_t)sAz;
    W += (size_t)blockIdx.z * (size_t)sWz;
    C += (size_t)blockIdx.z * (size_t)sCz;

    float acc[4][4];
    #pragma unroll
    for (int i = 0; i < 4; ++i)
        #pragma unroll
        for (int j = 0; j < 4; ++j) acc[i][j] = 0.f;

    for (int k0 = 0; k0 < K; k0 += 16) {
        float4 av = make_float4(0.f, 0.f, 0.f, 0.f);
        float4 wv = make_float4(0.f, 0.f, 0.f, 0.f);
        const int gm = bm + r;
        const int gn = bn + r;
        if (gm < M) av = *(const float4*)(A + (size_t)gm * lda + k0 + c4);
        if (gn < N) wv = *(const float4*)(W + (size_t)gn * ldw + k0 + c4);
        __syncthreads();
        Ast[c4 + 0][r] = av.x; Ast[c4 + 1][r] = av.y;
        Ast[c4 + 2][r] = av.z; Ast[c4 + 3][r] = av.w;
        Bst[c4 + 0][r] = wv.x; Bst[c4 + 1][r] = wv.y;
        Bst[c4 + 2][r] = wv.z; Bst[c4 + 3][r] = wv.w;
        __syncthreads();
        #pragma unroll
        for (int kk = 0; kk < 16; ++kk) {
            const float4 a = *(const float4*)&Ast[kk][ty << 2];
            const float4 b = *(const float4*)&Bst[kk][tx << 2];
            const float aa[4] = {a.x, a.y, a.z, a.w};
            const float bb4[4] = {b.x, b.y, b.z, b.w};
            #pragma unroll
            for (int i = 0; i < 4; ++i)
                #pragma unroll
                for (int j = 0; j < 4; ++j)
                    acc[i][j] += aa[i] * bb4[j];
        }
    }
    #pragma unroll
    for (int i = 0; i < 4; ++i) {
        const int gm = bm + (ty << 2) + i;
        if (gm >= M) continue;
        #pragma unroll
        for (int j = 0; j < 4; ++j) {
            const int gn = bn + (tx << 2) + j;
            if (gn >= N) continue;
            float v = acc[i][j] * alpha;
            if (bias) v += bias[gn];
            C[(size_t)gm * ldc + gn] = v;
        }
    }
}

// ---------------------------------------------------------------------------
// Stage-1 softmax over n=2000 (bf16 scores) + per-wave partial column sums.
// 128 blocks x 4 waves = 512 slots x 8 rows. dword loads = 2 bf16 each.
// ---------------------------------------------------------------------------
__global__ __launch_bounds__(256) void softmax_colsum_kernel(
    const ushort* __restrict__ sc, float* __restrict__ part)
{
    const int wave = threadIdx.x >> 6, lane = threadIdx.x & 63;
    const int slot = blockIdx.x * 4 + wave;      // 0..511
    float acc[32];
    #pragma unroll
    for (int i = 0; i < 32; ++i) acc[i] = 0.f;
    for (int rr = 0; rr < 8; ++rr) {
        const unsigned int* row =
            (const unsigned int*)(sc + (size_t)(slot * 8 + rr) * 2000);
        float v[32];
        float m = -1e30f;
        #pragma unroll
        for (int ii = 0; ii < 16; ++ii) {
            const int di = lane + 64 * ii;       // dword index, 1000 per row
            const unsigned int u = (di < 1000) ? row[di] : 0xFF80FF80u; // -inf|-inf
            v[2 * ii]     = bf2f((short)(u & 0xffff));
            v[2 * ii + 1] = bf2f((short)(u >> 16));
            m = fmaxf(m, fmaxf(v[2 * ii], v[2 * ii + 1]));
        }
        #pragma unroll
        for (int off = 32; off; off >>= 1) m = fmaxf(m, __shfl_xor(m, off));
        float sum = 0.f;
        #pragma unroll
        for (int i = 0; i < 32; ++i) { v[i] = __expf(v[i] - m); sum += v[i]; }
        #pragma unroll
        for (int off = 32; off; off >>= 1) sum += __shfl_xor(sum, off);
        const float inv = 1.f / sum;
        #pragma unroll
        for (int i = 0; i < 32; ++i) acc[i] += v[i] * inv;
    }
    float* p = part + (size_t)slot * 2000;
    #pragma unroll
    for (int ii = 0; ii < 16; ++ii) {
        const int di = lane + 64 * ii;
        if (di < 1000) {
            float2 w; w.x = acc[2 * ii]; w.y = acc[2 * ii + 1];
            ((float2*)p)[di] = w;
        }
    }
}

// part[512][2000] -> part2[4][2000]; grid (8,4)
__global__ void reduce_partials_kernel(const float* __restrict__ part,
                                       float* __restrict__ part2)
{
    const int n = blockIdx.x * 256 + threadIdx.x;
    if (n >= 2000) return;
    const int q = blockIdx.y;
    float s = 0.f;
    for (int sl = q * 128; sl < q * 128 + 128; ++sl) s += part[(size_t)sl * 2000 + n];
    part2[(size_t)q * 2000 + n] = s;
}

// ---------------------------------------------------------------------------
// Top-101 of 2000 (sums 4 part2 slices on load). Tie -> lowest index.
// ---------------------------------------------------------------------------
__global__ __launch_bounds__(256) void topk_kernel(const float* __restrict__ part2,
                                                   int* __restrict__ idx)
{
    __shared__ float scs[2048];
    __shared__ float bvw[4];
    __shared__ int biw[4];
    const int tid = threadIdx.x, wave = tid >> 6, lane = tid & 63;
    for (int n = tid; n < 2048; n += 256)
        scs[n] = (n < 2000)
            ? part2[n] + part2[2000 + n] + part2[4000 + n] + part2[6000 + n]
            : -1e30f;
    __syncthreads();
    for (int it = 0; it < 101; ++it) {
        float bv = -1e30f; int bi = 1 << 30;
        #pragma unroll
        for (int j = 0; j < 8; ++j) {
            const int n = tid + 256 * j;
            const float v = scs[n];
            if (v > bv) { bv = v; bi = n; }
        }
        #pragma unroll
        for (int off = 32; off; off >>= 1) {
            const float ov = __shfl_xor(bv, off);
            const int oi = __shfl_xor(bi, off);
            if (ov > bv || (ov == bv && oi < bi)) { bv = ov; bi = oi; }
        }
        if (lane == 0) { bvw[wave] = bv; biw[wave] = bi; }
        __syncthreads();
        if (tid == 0) {
            float fv = bvw[0]; int fi = biw[0];
            #pragma unroll
            for (int w = 1; w < 4; ++w)
                if (bvw[w] > fv || (bvw[w] == fv && biw[w] < fi)) { fv = bvw[w]; fi = biw[w]; }
            idx[it] = fi; scs[fi] = -1e30f;
        }
        __syncthreads();
    }
}

__global__ void gather_kernel(const float* __restrict__ ce,
                              const int* __restrict__ idx,
                              float* __restrict__ ctxf)
{
    const int r = blockIdx.x;
    const int src = idx[r];
    const int tid = threadIdx.x;
    const float2 v = *(const float2*)(ce + (size_t)src * 512 + tid * 2);
    *(float2*)(ctxf + (size_t)r * 512 + tid * 2) = v;
}

// wo [512][512] f32 -> woT bf16 (woT[j][k] = wo[k][j])
__global__ void transpose512_bf(const float* __restrict__ in, ushort* __restrict__ out)
{
    __shared__ float tile[32][33];
    const int tx = threadIdx.x & 31, ty = threadIdx.x >> 5;  // 32x8
    const int bx = blockIdx.x * 32, by = blockIdx.y * 32;
    #pragma unroll
    for (int rr = 0; rr < 4; ++rr)
        tile[ty + 8 * rr][tx] = in[(size_t)(by + ty + 8 * rr) * 512 + bx + tx];
    __syncthreads();
    #pragma unroll
    for (int rr = 0; rr < 4; ++rr)
        out[(size_t)(bx + ty + 8 * rr) * 512 + by + tx] = f2b(tile[tx][ty + 8 * rr]);
}

__global__ void bc2_kernel(const float* __restrict__ wc, const float* __restrict__ bo,
                           const float* __restrict__ bcb, float* __restrict__ bc2)
{
    const int d = blockIdx.x * 256 + threadIdx.x;
    float s = bcb[d];
    const float4* wr = (const float4*)(wc + (size_t)d * 512);
    const float4* br = (const float4*)bo;
    for (int m4 = 0; m4 < 128; ++m4) {
        const float4 w4 = wr[m4], b4 = br[m4];
        s += w4.x * b4.x + w4.y * b4.y + w4.z * b4.z + w4.w * b4.w;
    }
    bc2[d] = s;
}

// ---------------------------------------------------------------------------
// Stage-2 attention over 101 selected contexts (bf16 q in, bf16 o out).
// Same structure as R3 (barrier-free t-loop), q loaded as bf16 dwords.
// ---------------------------------------------------------------------------
__global__ __launch_bounds__(256) void attn2_kernel(
    const ushort* __restrict__ qb, const float* __restrict__ k2,
    const float* __restrict__ v2, ushort* __restrict__ o)
{
    __shared__ __align__(16) __hip_bfloat16 ks[101 * 128];
    __shared__ __align__(16) __hip_bfloat16 vs[104 * 128];
    __shared__ float qs[4][128];
    __shared__ float as[4][104];
    const int tid = threadIdx.x, wave = tid >> 6, lane = tid & 63;
    const int bh = blockIdx.y, b = bh >> 2, h = bh & 3;
    const int t0 = blockIdx.x * 64 + wave * 16;

    for (int e = tid; e < 101 * 128; e += 256) {
        const int n = e >> 7, d = e & 127;
        const int c = d >> 3;
        ks[n * 128 + (((c ^ (n & 7)) << 3) | (d & 7))] =
            __float2bfloat16(k2[(size_t)n * 512 + h * 128 + d]);
        vs[e] = __float2bfloat16(v2[(size_t)n * 512 + h * 128 + d]);
    }
    for (int e = tid; e < 3 * 128; e += 256)
        vs[101 * 128 + e] = __float2bfloat16(0.f);   // finite pad rows 101..103
    if (lane >= 37 && lane < 40) as[wave][64 + lane] = 0.f;
    __syncthreads();
    const unsigned int* vsp = (const unsigned int*)vs;

    for (int tt = 0; tt < 16; ++tt) {
        const int t = t0 + tt;
        const unsigned int* qrow =
            (const unsigned int*)(qb + ((size_t)(b * 1024 + t)) * 512 + h * 128);
        const unsigned int qu = qrow[lane];
        qs[wave][2 * lane]     = bf2f((short)(qu & 0xffff));
        qs[wave][2 * lane + 1] = bf2f((short)(qu >> 16));

        const int n1 = (lane < 37) ? 64 + lane : 100;
        float s0 = 0.f, s1 = 0.f;
        #pragma unroll
        for (int c = 0; c < 16; ++c) {
            const short8v kv0 = *(const short8v*)&ks[lane * 128 + ((c ^ (lane & 7)) << 3)];
            const short8v kv1 = *(const short8v*)&ks[n1 * 128 + ((c ^ (n1 & 7)) << 3)];
            const float4 qa = *(const float4*)&qs[wave][c * 8];
            const float4 qb4 = *(const float4*)&qs[wave][c * 8 + 4];
            s0 += qa.x * bf2f(kv0[0]) + qa.y * bf2f(kv0[1])
                + qa.z * bf2f(kv0[2]) + qa.w * bf2f(kv0[3])
                + qb4.x * bf2f(kv0[4]) + qb4.y * bf2f(kv0[5])
                + qb4.z * bf2f(kv0[6]) + qb4.w * bf2f(kv0[7]);
            s1 += qa.x * bf2f(kv1[0]) + qa.y * bf2f(kv1[1])
                + qa.z * bf2f(kv1[2]) + qa.w * bf2f(kv1[3])
                + qb4.x * bf2f(kv1[4]) + qb4.y * bf2f(kv1[5])
                + qb4.z * bf2f(kv1[6]) + qb4.w * bf2f(kv1[7]);
        }
        s0 *= SCALE; s1 *= SCALE;
        float m = (lane < 37) ? fmaxf(s0, s1) : s0;
        #pragma unroll
        for (int off = 32; off; off >>= 1) m = fmaxf(m, __shfl_xor(m, off));
        const float p0 = __expf(s0 - m);
        const float p1 = (lane < 37) ? __expf(s1 - m) : 0.f;
        float sum = p0 + p1;
        #pragma unroll
        for (int off = 32; off; off >>= 1) sum += __shfl_xor(sum, off);
        const float inv = 1.f / sum;
        as[wave][lane] = p0 * inv;
        if (lane < 37) as[wave][64 + lane] = p1 * inv;

        float o0 = 0.f, o1 = 0.f;
        #pragma unroll
        for (int c26 = 0; c26 < 26; ++c26) {
            const float4 a4 = *(const float4*)&as[wave][c26 * 4];
            const float aa[4] = {a4.x, a4.y, a4.z, a4.w};
            #pragma unroll
            for (int j = 0; j < 4; ++j) {
                const unsigned int vv = vsp[(c26 * 4 + j) * 64 + lane];
                o0 += aa[j] * bf2f((short)(vv & 0xffff));
                o1 += aa[j] * bf2f((short)(vv >> 16));
            }
        }
        const unsigned int ow = (unsigned int)f2b(o0) | ((unsigned int)f2b(o1) << 16);
        ((unsigned int*)o)[(((size_t)(b * 1024 + t)) * 512 + h * 128) / 2 + lane] = ow;
    }
}

// ---------------------------------------------------------------------------
// Residual + LayerNorm
// ---------------------------------------------------------------------------
__global__ __launch_bounds__(256) void ln_kernel(
    const float* __restrict__ tmp, const float* __restrict__ enc,
    const float* __restrict__ g, const float* __restrict__ bta,
    float* __restrict__ out)
{
    __shared__ float rs[4], rv[4];
    const int row = blockIdx.x, tid = threadIdx.x;
    const int wave = tid >> 6, lane = tid & 63;
    const size_t base = (size_t)row * 512;
    const float x0 = tmp[base + tid] + enc[base + tid];
    const float x1 = tmp[base + tid + 256] + enc[base + tid + 256];
    float s = x0 + x1;
    #pragma unroll
    for (int off = 32; off; off >>= 1) s += __shfl_xor(s, off);
    if (lane == 0) rs[wave] = s;
    __syncthreads();
    const float mu = (rs[0] + rs[1] + rs[2] + rs[3]) * (1.f / 512.f);
    const float d0 = x0 - mu, d1 = x1 - mu;
    float vv = d0 * d0 + d1 * d1;
    #pragma unroll
    for (int off = 32; off; off >>= 1) vv += __shfl_xor(vv, off);
    if (lane == 0) rv[wave] = vv;
    __syncthreads();
    const float var = (rv[0] + rv[1] + rv[2] + rv[3]) * (1.f / 512.f);
    const float rstd = rsqrtf(var + 1e-5f);
    out[base + tid] = d0 * rstd * g[tid] + bta[tid];
    out[base + tid + 256] = d1 * rstd * g[tid + 256] + bta[tid + 256];
}

extern "C" void kernel_launch(void* const* d_in, const int* in_sizes, int n_in,
                              void* d_out, int out_size, void* d_ws, size_t ws_size,
                              hipStream_t stream)
{
    const float* ce  = (const float*)d_in[0];
    const float* enc = (const float*)d_in[1];
    const float* wq  = (const float*)d_in[2];
    const float* bq  = (const float*)d_in[3];
    const float* wk  = (const float*)d_in[4];
    const float* bk  = (const float*)d_in[5];
    const float* wv  = (const float*)d_in[6];
    const float* bv  = (const float*)d_in[7];
    const float* wo  = (const float*)d_in[8];
    const float* bo  = (const float*)d_in[9];
    const float* wc  = (const float*)d_in[10];
    const float* bcb = (const float*)d_in[11];
    const float* lng = (const float*)d_in[12];
    const float* lnb = (const float*)d_in[13];
    float* ws  = (float*)d_ws;
    float* out = (float*)d_out;

    ushort* qbf   = (ushort*)(ws + OFF_QBF);
    ushort* encbf = (ushort*)(ws + OFF_SC);      // dead before scores written
    ushort* scb   = (ushort*)(ws + OFF_SC);      // bf16 scores [4][1024][2000]
    ushort* obf   = (ushort*)(ws + OFF_SC);      // bf16 o [8192][512], after sc dead
    ushort* kcbf  = (ushort*)(ws + OFF_KCBF);
    ushort* cebf  = (ushort*)(ws + OFF_CEBF);    // dead before part written
    float* part   = ws + OFF_PART;
    float* part2  = ws + OFF_PART2;
    int*   idx    = (int*)(ws + OFF_IDX);
    float* ctxf   = ws + OFF_CTXF;
    float* k2     = ws + OFF_K2;
    float* v2     = ws + OFF_V2;
    float* tmp    = ws + OFF_TMP;
    ushort* wqbf  = (ushort*)(ws + OFF_WQBF);
    ushort* wkbf  = (ushort*)(ws + OFF_WKBF);
    ushort* wcbf  = (ushort*)(ws + OFF_WCBF);
    ushort* wotbf = (ushort*)(ws + OFF_WOTBF);
    ushort* wc2bf = (ushort*)(ws + OFF_WC2BF);
    float* bc2    = ws + OFF_BC2;

    // bf16 conversions
    cvt_bf16_kernel<<<4096, 256, 0, stream>>>(enc, encbf, 1048576);
    cvt_bf16_kernel<<<1000, 256, 0, stream>>>(ce, cebf, 256000);
    cvt_bf16_kernel<<<256, 256, 0, stream>>>(wq, wqbf, 65536);
    cvt_bf16_kernel<<<256, 256, 0, stream>>>(wk, wkbf, 65536);
    cvt_bf16_kernel<<<256, 256, 0, stream>>>(wc, wcbf, 65536);
    transpose512_bf<<<dim3(16, 16), 256, 0, stream>>>(wo, wotbf);

    // q = enc @ wq^T + bq -> bf16 [8192][512]
    gemm_mfma<<<dim3(4, 64, 1), 256, 0, stream>>>(encbf, 512, 0, wqbf, 512, 0, bq,
                                                  nullptr, qbf, 512, 0,
                                                  8192, 512, 512, 1.f);
    // kc = ctx @ wk^T + bk -> bf16 [2000][512]
    gemm_mfma<<<dim3(4, 16, 1), 256, 0, stream>>>(cebf, 512, 0, wkbf, 512, 0, bk,
                                                  nullptr, kcbf, 512, 0,
                                                  2000, 512, 512, 1.f);
    // stage-1 scores (b=0, batched over h): bf16 [4][1024][2000]
    gemm_mfma<<<dim3(16, 8, 4), 256, 0, stream>>>(qbf, 512, 128, kcbf, 512, 128,
                                                  nullptr, nullptr, scb,
                                                  2000, 2048000LL,
                                                  1024, 2000, 128, SCALE);
    softmax_colsum_kernel<<<128, 256, 0, stream>>>(scb, part);
    reduce_partials_kernel<<<dim3(8, 4), 256, 0, stream>>>(part, part2);
    topk_kernel<<<1, 256, 0, stream>>>(part2, idx);
    gather_kernel<<<101, 256, 0, stream>>>(ce, idx, ctxf);
    // k2/v2 projections (tiny, f32)
    gemm_nt<<<dim3(8, 2, 1), 256, 0, stream>>>(ctxf, 512, 0, wk, 512, 0, bk,
                                               k2, 512, 0, 101, 512, 512, 1.f);
    gemm_nt<<<dim3(8, 2, 1), 256, 0, stream>>>(ctxf, 512, 0, wv, 512, 0, bv,
                                               v2, 512, 0, 101, 512, 512, 1.f);
    // fold wo/w_comb
    bc2_kernel<<<2, 256, 0, stream>>>(wc, bo, bcb, bc2);
    gemm_mfma<<<dim3(4, 4, 1), 256, 0, stream>>>(wcbf, 512, 0, wotbf, 512, 0, nullptr,
                                                 nullptr, wc2bf, 512, 0,
                                                 512, 512, 512, 1.f);
    // stage-2 attention -> bf16 o
    attn2_kernel<<<dim3(16, 32), 256, 0, stream>>>(qbf, k2, v2, obf);
    // tmp = o @ Wc2^T + bc2 (f32)
    gemm_mfma<<<dim3(4, 64, 1), 256, 0, stream>>>(obf, 512, 0, wc2bf, 512, 0, bc2,
                                                  tmp, nullptr, 512, 0,
                                                  8192, 512, 512, 1.f);
    // residual + LayerNorm
    ln_kernel<<<8192, 256, 0, stream>>>(tmp, enc, lng, lnb, out);
    (void)in_sizes; (void)n_in; (void)out_size; (void)ws_size;
}

// Round 5
// 390.852 us; speedup vs baseline: 1.5885x; 1.1871x over previous
//
#include <hip/hip_runtime.h>
#include <hip/hip_bf16.h>

// ContextModule R5: stage-2 attention -> MFMA (s2 gemm + softmax2 + o gemm).
// Workspace re-planned, exact sizes, all aliases time-disjoint (stream order).
// ws total 13,894,320 fl = 55.6 MB.

typedef short bhalf8 __attribute__((ext_vector_type(8)));   // 8 bf16 = 4 VGPR
typedef float f32x4 __attribute__((ext_vector_type(4)));

#define SCALE 0.08838834764831845f  // 1/sqrt(128)

// ---- ws layout (float offsets) ----
// region QBF: qbf bf16 [8192][512] (2,097,152 fl); later obf bf16 [8192][512]
#define OFF_QBF    ((size_t)0)
// region RA (4,096,000 fl): scb bf16 [4][1024][2000]; later s2 f32 [4][8192][104]
#define OFF_RA     ((size_t)2097152)
// region RB (2,097,152 fl): encbf bf16 [8192][512] -> kcbf bf16 [2000][512]
//                           -> attn_p bf16 [4][8192][128]
#define OFF_RB     ((size_t)6193152)
// region TMP (4,194,304 fl): part/part2/idx early; tmp f32 [8192][512] late
#define OFF_TMP    ((size_t)8290304)
#define OFF_PART   (OFF_TMP)                 // [512][2000] f32
#define OFF_PART2  (OFF_TMP + 1024000)       // [4][2000] f32
#define OFF_IDX    (OFF_TMP + 1032000)       // 128 ints
#define OFF_CEBF   ((size_t)12484608)        // ce bf16 [2000][512] (512,000 fl)
#define OFF_CTXFBF ((size_t)12996608)        // ctxf bf16 [101][512] (26,000 fl)
#define OFF_K2BF   ((size_t)13022608)        // k2 bf16 [101][512]
#define OFF_V2BF   ((size_t)13048608)        // v2 bf16 [101][512]
#define OFF_V2TP   ((size_t)13074608)        // v2tp bf16 [4][128][128] (32,768 fl)
#define OFF_WQBF   ((size_t)13107376)        // 131,072 fl each
#define OFF_WKBF   ((size_t)13238448)
#define OFF_WVBF   ((size_t)13369520)
#define OFF_WCBF   ((size_t)13500592)
#define OFF_WOTBF  ((size_t)13631664)
#define OFF_WC2BF  ((size_t)13762736)
#define OFF_BC2    ((size_t)13893808)        // 512
// total 13,894,320 fl = 55.6 MB

__device__ __forceinline__ float bf2f(short u) {
    union { float f; unsigned int i; } x;
    x.i = ((unsigned int)(unsigned short)u) << 16;
    return x.f;
}
__device__ __forceinline__ ushort f2b(float f) {
    union { float f; unsigned int i; } x; x.f = f;
    return (ushort)((x.i + 0x7fff + ((x.i >> 16) & 1)) >> 16);  // RNE
}

// f32 -> bf16 bulk convert, 4 elems/thread
__global__ __launch_bounds__(256) void cvt_bf16_kernel(
    const float* __restrict__ in, ushort* __restrict__ out, int n4)
{
    const int i = blockIdx.x * 256 + threadIdx.x;
    if (i >= n4) return;
    const float4 v = ((const float4*)in)[i];
    ushort4 r;
    r.x = f2b(v.x); r.y = f2b(v.y); r.z = f2b(v.z); r.w = f2b(v.w);
    ((ushort4*)out)[i] = r;
}

// ---------------------------------------------------------------------------
// bf16 MFMA NT GEMM: C[m][n] = alpha*sum_k A[m][k]*W[n][k] (+bias[n])
// 128x128 tile, BK=32, 4 waves (2x2), wave tile 64x64. LDS 16B-chunk XOR
// swizzle -> ds_write/read_b128 at conflict-free floor. Out-of-range loads
// return zeros; epilogue fully guarded.
// ---------------------------------------------------------------------------
__global__ __launch_bounds__(256) void gemm_mfma(
    const ushort* __restrict__ A, int lda, long long sAz,
    const ushort* __restrict__ W, int ldw, long long sWz,
    const float* __restrict__ bias,
    float* __restrict__ C, ushort* __restrict__ Cbf,
    int ldc, long long sCz,
    int M, int N, int K, float alpha)
{
    __shared__ __align__(16) ushort As[128 * 32];
    __shared__ __align__(16) ushort Bs[128 * 32];
    const int tid = threadIdx.x;
    const int wave = tid >> 6, lane = tid & 63;
    const int wm = wave >> 1, wn = wave & 1;
    const int mr = lane & 15, g = lane >> 4;
    const int bm = blockIdx.y * 128, bn = blockIdx.x * 128;
    A += (size_t)blockIdx.z * (size_t)sAz;
    W += (size_t)blockIdx.z * (size_t)sWz;

    f32x4 acc[4][4];
    #pragma unroll
    for (int i = 0; i < 4; ++i)
        #pragma unroll
        for (int j = 0; j < 4; ++j)
            #pragma unroll
            for (int p = 0; p < 4; ++p) acc[i][j][p] = 0.f;

    const int r0 = tid >> 2;     // 0..63
    const int c0 = tid & 3;      // 16B chunk in 32-k row
    const int sw0 = (r0 * 4 + (c0 ^ (r0 & 3))) * 8;
    const int sw1 = ((r0 + 64) * 4 + (c0 ^ (r0 & 3))) * 8;
    const uint4 zz = make_uint4(0u, 0u, 0u, 0u);

    for (int k0 = 0; k0 < K; k0 += 32) {
        const int ka = k0 + c0 * 8;
        uint4 av0 = zz, av1 = zz, bv0 = zz, bv1 = zz;
        if (bm + r0 < M)      av0 = *(const uint4*)(A + (size_t)(bm + r0) * lda + ka);
        if (bm + r0 + 64 < M) av1 = *(const uint4*)(A + (size_t)(bm + r0 + 64) * lda + ka);
        if (bn + r0 < N)      bv0 = *(const uint4*)(W + (size_t)(bn + r0) * ldw + ka);
        if (bn + r0 + 64 < N) bv1 = *(const uint4*)(W + (size_t)(bn + r0 + 64) * ldw + ka);
        __syncthreads();   // previous tile fully consumed
        *(uint4*)&As[sw0] = av0;
        *(uint4*)&As[sw1] = av1;
        *(uint4*)&Bs[sw0] = bv0;
        *(uint4*)&Bs[sw1] = bv1;
        __syncthreads();
        bhalf8 a[4], b[4];
        const int ksw = (g ^ (mr & 3)) << 3;
        #pragma unroll
        for (int i = 0; i < 4; ++i)
            a[i] = *(const bhalf8*)&As[(wm * 64 + i * 16 + mr) * 32 + ksw];
        #pragma unroll
        for (int j = 0; j < 4; ++j)
            b[j] = *(const bhalf8*)&Bs[(wn * 64 + j * 16 + mr) * 32 + ksw];
        #pragma unroll
        for (int i = 0; i < 4; ++i)
            #pragma unroll
            for (int j = 0; j < 4; ++j)
                acc[i][j] = __builtin_amdgcn_mfma_f32_16x16x32_bf16(
                    a[i], b[j], acc[i][j], 0, 0, 0);
    }

    if (C)   C   += (size_t)blockIdx.z * (size_t)sCz;
    if (Cbf) Cbf += (size_t)blockIdx.z * (size_t)sCz;
    #pragma unroll
    for (int i = 0; i < 4; ++i) {
        #pragma unroll
        for (int j = 0; j < 4; ++j) {
            const int gn = bn + wn * 64 + j * 16 + mr;
            if (gn >= N) continue;
            const float bb = bias ? bias[gn] : 0.f;
            #pragma unroll
            for (int p = 0; p < 4; ++p) {
                const int gm = bm + wm * 64 + i * 16 + g * 4 + p;
                if (gm >= M) continue;
                const float v = acc[i][j][p] * alpha + bb;
                if (C)   C[(size_t)gm * ldc + gn] = v;
                if (Cbf) Cbf[(size_t)gm * ldc + gn] = f2b(v);
            }
        }
    }
}

// ---------------------------------------------------------------------------
// Stage-1 softmax over n=2000 (bf16 scores) + per-wave partial column sums.
// 128 blocks x 4 waves = 512 slots x 8 rows.
// ---------------------------------------------------------------------------
__global__ __launch_bounds__(256) void softmax_colsum_kernel(
    const ushort* __restrict__ sc, float* __restrict__ part)
{
    const int wave = threadIdx.x >> 6, lane = threadIdx.x & 63;
    const int slot = blockIdx.x * 4 + wave;      // 0..511
    float acc[32];
    #pragma unroll
    for (int i = 0; i < 32; ++i) acc[i] = 0.f;
    for (int rr = 0; rr < 8; ++rr) {
        const unsigned int* row =
            (const unsigned int*)(sc + (size_t)(slot * 8 + rr) * 2000);
        float v[32];
        float m = -1e30f;
        #pragma unroll
        for (int ii = 0; ii < 16; ++ii) {
            const int di = lane + 64 * ii;       // dword index, 1000 per row
            const unsigned int u = (di < 1000) ? row[di] : 0xFF80FF80u; // -inf|-inf
            v[2 * ii]     = bf2f((short)(u & 0xffff));
            v[2 * ii + 1] = bf2f((short)(u >> 16));
            m = fmaxf(m, fmaxf(v[2 * ii], v[2 * ii + 1]));
        }
        #pragma unroll
        for (int off = 32; off; off >>= 1) m = fmaxf(m, __shfl_xor(m, off));
        float sum = 0.f;
        #pragma unroll
        for (int i = 0; i < 32; ++i) { v[i] = __expf(v[i] - m); sum += v[i]; }
        #pragma unroll
        for (int off = 32; off; off >>= 1) sum += __shfl_xor(sum, off);
        const float inv = 1.f / sum;
        #pragma unroll
        for (int i = 0; i < 32; ++i) acc[i] += v[i] * inv;
    }
    float* p = part + (size_t)slot * 2000;
    #pragma unroll
    for (int ii = 0; ii < 16; ++ii) {
        const int di = lane + 64 * ii;
        if (di < 1000) {
            float2 w; w.x = acc[2 * ii]; w.y = acc[2 * ii + 1];
            ((float2*)p)[di] = w;
        }
    }
}

// part[512][2000] -> part2[4][2000]; grid (8,4)
__global__ void reduce_partials_kernel(const float* __restrict__ part,
                                       float* __restrict__ part2)
{
    const int n = blockIdx.x * 256 + threadIdx.x;
    if (n >= 2000) return;
    const int q = blockIdx.y;
    float s = 0.f;
    for (int sl = q * 128; sl < q * 128 + 128; ++sl) s += part[(size_t)sl * 2000 + n];
    part2[(size_t)q * 2000 + n] = s;
}

// ---------------------------------------------------------------------------
// Top-101 of 2000 (sums 4 part2 slices on load). Tie -> lowest index.
// ---------------------------------------------------------------------------
__global__ __launch_bounds__(256) void topk_kernel(const float* __restrict__ part2,
                                                   int* __restrict__ idx)
{
    __shared__ float scs[2048];
    __shared__ float bvw[4];
    __shared__ int biw[4];
    const int tid = threadIdx.x, wave = tid >> 6, lane = tid & 63;
    for (int n = tid; n < 2048; n += 256)
        scs[n] = (n < 2000)
            ? part2[n] + part2[2000 + n] + part2[4000 + n] + part2[6000 + n]
            : -1e30f;
    __syncthreads();
    for (int it = 0; it < 101; ++it) {
        float bv = -1e30f; int bi = 1 << 30;
        #pragma unroll
        for (int j = 0; j < 8; ++j) {
            const int n = tid + 256 * j;
            const float v = scs[n];
            if (v > bv) { bv = v; bi = n; }
        }
        #pragma unroll
        for (int off = 32; off; off >>= 1) {
            const float ov = __shfl_xor(bv, off);
            const int oi = __shfl_xor(bi, off);
            if (ov > bv || (ov == bv && oi < bi)) { bv = ov; bi = oi; }
        }
        if (lane == 0) { bvw[wave] = bv; biw[wave] = bi; }
        __syncthreads();
        if (tid == 0) {
            float fv = bvw[0]; int fi = biw[0];
            #pragma unroll
            for (int w = 1; w < 4; ++w)
                if (bvw[w] > fv || (bvw[w] == fv && biw[w] < fi)) { fv = bvw[w]; fi = biw[w]; }
            idx[it] = fi; scs[fi] = -1e30f;
        }
        __syncthreads();
    }
}

// gather selected context rows from bf16 ce: one block per row, uint per thread
__global__ void gather_bf_kernel(const ushort* __restrict__ cebf,
                                 const int* __restrict__ idx,
                                 ushort* __restrict__ ctxfbf)
{
    const int r = blockIdx.x;
    const int src = idx[r];
    const int tid = threadIdx.x;
    ((unsigned int*)ctxfbf)[r * 256 + tid] =
        ((const unsigned int*)cebf)[(size_t)src * 256 + tid];
}

// wo [512][512] f32 -> woT bf16 (woT[j][k] = wo[k][j])
__global__ void transpose512_bf(const float* __restrict__ in, ushort* __restrict__ out)
{
    __shared__ float tile[32][33];
    const int tx = threadIdx.x & 31, ty = threadIdx.x >> 5;  // 32x8
    const int bx = blockIdx.x * 32, by = blockIdx.y * 32;
    #pragma unroll
    for (int rr = 0; rr < 4; ++rr)
        tile[ty + 8 * rr][tx] = in[(size_t)(by + ty + 8 * rr) * 512 + bx + tx];
    __syncthreads();
    #pragma unroll
    for (int rr = 0; rr < 4; ++rr)
        out[(size_t)(bx + ty + 8 * rr) * 512 + by + tx] = f2b(tile[tx][ty + 8 * rr]);
}

// v2bf [101][512] -> v2tp [4][128][128]: v2tp[h][d][n] = v2bf[n][h*128+d], 0 pad
__global__ void v2tp_kernel(const ushort* __restrict__ v2bf, ushort* __restrict__ v2tp)
{
    const int e = blockIdx.x * 256 + threadIdx.x;   // 0..65535
    const int h = e >> 14, rem = e & 16383;
    const int d = rem >> 7, n = rem & 127;
    v2tp[e] = (n < 101) ? v2bf[(size_t)n * 512 + h * 128 + d] : (ushort)0;
}

__global__ void bc2_kernel(const float* __restrict__ wc, const float* __restrict__ bo,
                           const float* __restrict__ bcb, float* __restrict__ bc2)
{
    const int d = blockIdx.x * 256 + threadIdx.x;
    float s = bcb[d];
    const float4* wr = (const float4*)(wc + (size_t)d * 512);
    const float4* br = (const float4*)bo;
    for (int m4 = 0; m4 < 128; ++m4) {
        const float4 w4 = wr[m4], b4 = br[m4];
        s += w4.x * b4.x + w4.y * b4.y + w4.z * b4.z + w4.w * b4.w;
    }
    bc2[d] = s;
}

// ---------------------------------------------------------------------------
// Stage-2 row softmax: s2 f32 [4][8192][104] (101 valid) -> attn_p bf16
// [4][8192][128] (zero pad 101..127). One wave per row, 32 rows/wave.
// ---------------------------------------------------------------------------
__global__ __launch_bounds__(256) void softmax2_kernel(
    const float* __restrict__ s2, ushort* __restrict__ ap)
{
    const int wave = threadIdx.x >> 6, lane = threadIdx.x & 63;
    const int w = blockIdx.x * 4 + wave;       // 0..1023
    const int e0 = 2 * lane, e1 = 2 * lane + 1;
    for (int rr = 0; rr < 32; ++rr) {
        const int row = w * 32 + rr;           // 0..32767
        const float* sr = s2 + (size_t)row * 104;
        float v0 = -1e30f, v1 = -1e30f;
        if (e0 < 101) {
            const float2 t = *(const float2*)(sr + e0);
            v0 = t.x;
            if (e1 < 101) v1 = t.y;
        }
        float m = fmaxf(v0, v1);
        #pragma unroll
        for (int off = 32; off; off >>= 1) m = fmaxf(m, __shfl_xor(m, off));
        const float p0 = (e0 < 101) ? __expf(v0 - m) : 0.f;
        const float p1 = (e1 < 101) ? __expf(v1 - m) : 0.f;
        float sum = p0 + p1;
        #pragma unroll
        for (int off = 32; off; off >>= 1) sum += __shfl_xor(sum, off);
        const float inv = 1.f / sum;
        const unsigned int ow =
            (unsigned int)f2b(p0 * inv) | ((unsigned int)f2b(p1 * inv) << 16);
        ((unsigned int*)ap)[(size_t)row * 64 + lane] = ow;
    }
}

// ---------------------------------------------------------------------------
// Residual + LayerNorm
// ---------------------------------------------------------------------------
__global__ __launch_bounds__(256) void ln_kernel(
    const float* __restrict__ tmp, const float* __restrict__ enc,
    const float* __restrict__ g, const float* __restrict__ bta,
    float* __restrict__ out)
{
    __shared__ float rs[4], rv[4];
    const int row = blockIdx.x, tid = threadIdx.x;
    const int wave = tid >> 6, lane = tid & 63;
    const size_t base = (size_t)row * 512;
    const float x0 = tmp[base + tid] + enc[base + tid];
    const float x1 = tmp[base + tid + 256] + enc[base + tid + 256];
    float s = x0 + x1;
    #pragma unroll
    for (int off = 32; off; off >>= 1) s += __shfl_xor(s, off);
    if (lane == 0) rs[wave] = s;
    __syncthreads();
    const float mu = (rs[0] + rs[1] + rs[2] + rs[3]) * (1.f / 512.f);
    const float d0 = x0 - mu, d1 = x1 - mu;
    float vv = d0 * d0 + d1 * d1;
    #pragma unroll
    for (int off = 32; off; off >>= 1) vv += __shfl_xor(vv, off);
    if (lane == 0) rv[wave] = vv;
    __syncthreads();
    const float var = (rv[0] + rv[1] + rv[2] + rv[3]) * (1.f / 512.f);
    const float rstd = rsqrtf(var + 1e-5f);
    out[base + tid] = d0 * rstd * g[tid] + bta[tid];
    out[base + tid + 256] = d1 * rstd * g[tid + 256] + bta[tid + 256];
}

extern "C" void kernel_launch(void* const* d_in, const int* in_sizes, int n_in,
                              void* d_out, int out_size, void* d_ws, size_t ws_size,
                              hipStream_t stream)
{
    const float* ce  = (const float*)d_in[0];
    const float* enc = (const float*)d_in[1];
    const float* wq  = (const float*)d_in[2];
    const float* bq  = (const float*)d_in[3];
    const float* wk  = (const float*)d_in[4];
    const float* bk  = (const float*)d_in[5];
    const float* wv  = (const float*)d_in[6];
    const float* bv  = (const float*)d_in[7];
    const float* wo  = (const float*)d_in[8];
    const float* bo  = (const float*)d_in[9];
    const float* wc  = (const float*)d_in[10];
    const float* bcb = (const float*)d_in[11];
    const float* lng = (const float*)d_in[12];
    const float* lnb = (const float*)d_in[13];
    float* ws  = (float*)d_ws;
    float* out = (float*)d_out;

    ushort* qbf    = (ushort*)(ws + OFF_QBF);    // later: obf
    ushort* obf    = (ushort*)(ws + OFF_QBF);
    ushort* scb    = (ushort*)(ws + OFF_RA);     // later: s2 (f32)
    float*  s2     = ws + OFF_RA;
    ushort* encbf  = (ushort*)(ws + OFF_RB);     // -> kcbf -> attn_p
    ushort* kcbf   = (ushort*)(ws + OFF_RB);
    ushort* attnp  = (ushort*)(ws + OFF_RB);
    float*  part   = ws + OFF_PART;
    float*  part2  = ws + OFF_PART2;
    int*    idx    = (int*)(ws + OFF_IDX);
    float*  tmp    = ws + OFF_TMP;
    ushort* cebf   = (ushort*)(ws + OFF_CEBF);
    ushort* ctxfbf = (ushort*)(ws + OFF_CTXFBF);
    ushort* k2bf   = (ushort*)(ws + OFF_K2BF);
    ushort* v2bf   = (ushort*)(ws + OFF_V2BF);
    ushort* v2tp   = (ushort*)(ws + OFF_V2TP);
    ushort* wqbf   = (ushort*)(ws + OFF_WQBF);
    ushort* wkbf   = (ushort*)(ws + OFF_WKBF);
    ushort* wvbf   = (ushort*)(ws + OFF_WVBF);
    ushort* wcbf   = (ushort*)(ws + OFF_WCBF);
    ushort* wotbf  = (ushort*)(ws + OFF_WOTBF);
    ushort* wc2bf  = (ushort*)(ws + OFF_WC2BF);
    float*  bc2    = ws + OFF_BC2;

    // bf16 conversions
    cvt_bf16_kernel<<<4096, 256, 0, stream>>>(enc, encbf, 1048576);
    cvt_bf16_kernel<<<1000, 256, 0, stream>>>(ce, cebf, 256000);
    cvt_bf16_kernel<<<256, 256, 0, stream>>>(wq, wqbf, 65536);
    cvt_bf16_kernel<<<256, 256, 0, stream>>>(wk, wkbf, 65536);
    cvt_bf16_kernel<<<256, 256, 0, stream>>>(wv, wvbf, 65536);
    cvt_bf16_kernel<<<256, 256, 0, stream>>>(wc, wcbf, 65536);
    transpose512_bf<<<dim3(16, 16), 256, 0, stream>>>(wo, wotbf);

    // q = enc @ wq^T + bq -> bf16 [8192][512]
    gemm_mfma<<<dim3(4, 64, 1), 256, 0, stream>>>(encbf, 512, 0, wqbf, 512, 0, bq,
                                                  nullptr, qbf, 512, 0,
                                                  8192, 512, 512, 1.f);
    // kc = ctx @ wk^T + bk -> bf16 [2000][512]  (kcbf overwrites dead encbf)
    gemm_mfma<<<dim3(4, 16, 1), 256, 0, stream>>>(cebf, 512, 0, wkbf, 512, 0, bk,
                                                  nullptr, kcbf, 512, 0,
                                                  2000, 512, 512, 1.f);
    // stage-1 scores (b=0, batched over h): bf16 [4][1024][2000]
    gemm_mfma<<<dim3(16, 8, 4), 256, 0, stream>>>(qbf, 512, 128, kcbf, 512, 128,
                                                  nullptr, nullptr, scb,
                                                  2000, 2048000LL,
                                                  1024, 2000, 128, SCALE);
    softmax_colsum_kernel<<<128, 256, 0, stream>>>(scb, part);
    reduce_partials_kernel<<<dim3(8, 4), 256, 0, stream>>>(part, part2);
    topk_kernel<<<1, 256, 0, stream>>>(part2, idx);
    gather_bf_kernel<<<101, 256, 0, stream>>>(cebf, idx, ctxfbf);
    // k2/v2 projections of the 101 selected contexts (MFMA, bf16 out)
    gemm_mfma<<<dim3(4, 1, 1), 256, 0, stream>>>(ctxfbf, 512, 0, wkbf, 512, 0, bk,
                                                 nullptr, k2bf, 512, 0,
                                                 101, 512, 512, 1.f);
    gemm_mfma<<<dim3(4, 1, 1), 256, 0, stream>>>(ctxfbf, 512, 0, wvbf, 512, 0, bv,
                                                 nullptr, v2bf, 512, 0,
                                                 101, 512, 512, 1.f);
    v2tp_kernel<<<256, 256, 0, stream>>>(v2bf, v2tp);
    // fold wo/w_comb: Wc2 = wc @ wo, bc2 = wc @ bo + bc
    bc2_kernel<<<2, 256, 0, stream>>>(wc, bo, bcb, bc2);
    gemm_mfma<<<dim3(4, 4, 1), 256, 0, stream>>>(wcbf, 512, 0, wotbf, 512, 0, nullptr,
                                                 nullptr, wc2bf, 512, 0,
                                                 512, 512, 512, 1.f);
    // stage-2 scores: s2[h][m][n] = SCALE * q_h[m] . k2_h[n], f32, ldc=104
    gemm_mfma<<<dim3(1, 64, 4), 256, 0, stream>>>(qbf, 512, 128, k2bf, 512, 128,
                                                  nullptr, s2, nullptr,
                                                  104, 851968LL,
                                                  8192, 101, 128, SCALE);
    // row softmax over 101 -> bf16 probs padded to 128
    softmax2_kernel<<<256, 256, 0, stream>>>(s2, attnp);
    // o = attn_p @ v2tp^T (per head) -> obf [8192][512] head-interleaved
    gemm_mfma<<<dim3(1, 64, 4), 256, 0, stream>>>(attnp, 128, 1048576LL,
                                                  v2tp, 128, 16384LL, nullptr,
                                                  nullptr, obf, 512, 128,
                                                  8192, 128, 128, 1.f);
    // tmp = o @ Wc2^T + bc2 (f32)
    gemm_mfma<<<dim3(4, 64, 1), 256, 0, stream>>>(obf, 512, 0, wc2bf, 512, 0, bc2,
                                                  tmp, nullptr, 512, 0,
                                                  8192, 512, 512, 1.f);
    // residual + LayerNorm
    ln_kernel<<<8192, 256, 0, stream>>>(tmp, enc, lng, lnb, out);
    (void)in_sizes; (void)n_in; (void)out_size; (void)ws_size;
}

// Round 6
// 389.628 us; speedup vs baseline: 1.5935x; 1.0031x over previous
//
#include <hip/hip_runtime.h>
#include <hip/hip_bf16.h>

// ContextModule R6: = R5 + register-resident single-wave top-k (no barriers,
// no LDS in the argmax loop). ws 55.6 MB, aliases time-disjoint.

typedef short bhalf8 __attribute__((ext_vector_type(8)));   // 8 bf16 = 4 VGPR
typedef float f32x4 __attribute__((ext_vector_type(4)));

#define SCALE 0.08838834764831845f  // 1/sqrt(128)

// ---- ws layout (float offsets) ----
#define OFF_QBF    ((size_t)0)               // qbf bf16 [8192][512]; later obf
#define OFF_RA     ((size_t)2097152)         // scb bf16 [4][1024][2000]; later s2 f32 [4][8192][104]
#define OFF_RB     ((size_t)6193152)         // encbf -> kcbf -> attn_p
#define OFF_TMP    ((size_t)8290304)         // part/part2/idx early; tmp f32 late
#define OFF_PART   (OFF_TMP)                 // [512][2000] f32
#define OFF_PART2  (OFF_TMP + 1024000)       // [4][2000] f32
#define OFF_IDX    (OFF_TMP + 1032000)       // 128 ints
#define OFF_CEBF   ((size_t)12484608)        // ce bf16 [2000][512]
#define OFF_CTXFBF ((size_t)12996608)        // ctxf bf16 [101][512]
#define OFF_K2BF   ((size_t)13022608)        // k2 bf16 [101][512]
#define OFF_V2BF   ((size_t)13048608)        // v2 bf16 [101][512]
#define OFF_V2TP   ((size_t)13074608)        // v2tp bf16 [4][128][128]
#define OFF_WQBF   ((size_t)13107376)
#define OFF_WKBF   ((size_t)13238448)
#define OFF_WVBF   ((size_t)13369520)
#define OFF_WCBF   ((size_t)13500592)
#define OFF_WOTBF  ((size_t)13631664)
#define OFF_WC2BF  ((size_t)13762736)
#define OFF_BC2    ((size_t)13893808)        // 512
// total 13,894,320 fl = 55.6 MB

__device__ __forceinline__ float bf2f(short u) {
    union { float f; unsigned int i; } x;
    x.i = ((unsigned int)(unsigned short)u) << 16;
    return x.f;
}
__device__ __forceinline__ ushort f2b(float f) {
    union { float f; unsigned int i; } x; x.f = f;
    return (ushort)((x.i + 0x7fff + ((x.i >> 16) & 1)) >> 16);  // RNE
}

// f32 -> bf16 bulk convert, 4 elems/thread
__global__ __launch_bounds__(256) void cvt_bf16_kernel(
    const float* __restrict__ in, ushort* __restrict__ out, int n4)
{
    const int i = blockIdx.x * 256 + threadIdx.x;
    if (i >= n4) return;
    const float4 v = ((const float4*)in)[i];
    ushort4 r;
    r.x = f2b(v.x); r.y = f2b(v.y); r.z = f2b(v.z); r.w = f2b(v.w);
    ((ushort4*)out)[i] = r;
}

// ---------------------------------------------------------------------------
// bf16 MFMA NT GEMM: C[m][n] = alpha*sum_k A[m][k]*W[n][k] (+bias[n])
// 128x128 tile, BK=32, 4 waves (2x2), wave tile 64x64. LDS 16B-chunk XOR
// swizzle -> ds_write/read_b128 at conflict-free floor.
// ---------------------------------------------------------------------------
__global__ __launch_bounds__(256) void gemm_mfma(
    const ushort* __restrict__ A, int lda, long long sAz,
    const ushort* __restrict__ W, int ldw, long long sWz,
    const float* __restrict__ bias,
    float* __restrict__ C, ushort* __restrict__ Cbf,
    int ldc, long long sCz,
    int M, int N, int K, float alpha)
{
    __shared__ __align__(16) ushort As[128 * 32];
    __shared__ __align__(16) ushort Bs[128 * 32];
    const int tid = threadIdx.x;
    const int wave = tid >> 6, lane = tid & 63;
    const int wm = wave >> 1, wn = wave & 1;
    const int mr = lane & 15, g = lane >> 4;
    const int bm = blockIdx.y * 128, bn = blockIdx.x * 128;
    A += (size_t)blockIdx.z * (size_t)sAz;
    W += (size_t)blockIdx.z * (size_t)sWz;

    f32x4 acc[4][4];
    #pragma unroll
    for (int i = 0; i < 4; ++i)
        #pragma unroll
        for (int j = 0; j < 4; ++j)
            #pragma unroll
            for (int p = 0; p < 4; ++p) acc[i][j][p] = 0.f;

    const int r0 = tid >> 2;     // 0..63
    const int c0 = tid & 3;      // 16B chunk in 32-k row
    const int sw0 = (r0 * 4 + (c0 ^ (r0 & 3))) * 8;
    const int sw1 = ((r0 + 64) * 4 + (c0 ^ (r0 & 3))) * 8;
    const uint4 zz = make_uint4(0u, 0u, 0u, 0u);

    for (int k0 = 0; k0 < K; k0 += 32) {
        const int ka = k0 + c0 * 8;
        uint4 av0 = zz, av1 = zz, bv0 = zz, bv1 = zz;
        if (bm + r0 < M)      av0 = *(const uint4*)(A + (size_t)(bm + r0) * lda + ka);
        if (bm + r0 + 64 < M) av1 = *(const uint4*)(A + (size_t)(bm + r0 + 64) * lda + ka);
        if (bn + r0 < N)      bv0 = *(const uint4*)(W + (size_t)(bn + r0) * ldw + ka);
        if (bn + r0 + 64 < N) bv1 = *(const uint4*)(W + (size_t)(bn + r0 + 64) * ldw + ka);
        __syncthreads();   // previous tile fully consumed
        *(uint4*)&As[sw0] = av0;
        *(uint4*)&As[sw1] = av1;
        *(uint4*)&Bs[sw0] = bv0;
        *(uint4*)&Bs[sw1] = bv1;
        __syncthreads();
        bhalf8 a[4], b[4];
        const int ksw = (g ^ (mr & 3)) << 3;
        #pragma unroll
        for (int i = 0; i < 4; ++i)
            a[i] = *(const bhalf8*)&As[(wm * 64 + i * 16 + mr) * 32 + ksw];
        #pragma unroll
        for (int j = 0; j < 4; ++j)
            b[j] = *(const bhalf8*)&Bs[(wn * 64 + j * 16 + mr) * 32 + ksw];
        #pragma unroll
        for (int i = 0; i < 4; ++i)
            #pragma unroll
            for (int j = 0; j < 4; ++j)
                acc[i][j] = __builtin_amdgcn_mfma_f32_16x16x32_bf16(
                    a[i], b[j], acc[i][j], 0, 0, 0);
    }

    if (C)   C   += (size_t)blockIdx.z * (size_t)sCz;
    if (Cbf) Cbf += (size_t)blockIdx.z * (size_t)sCz;
    #pragma unroll
    for (int i = 0; i < 4; ++i) {
        #pragma unroll
        for (int j = 0; j < 4; ++j) {
            const int gn = bn + wn * 64 + j * 16 + mr;
            if (gn >= N) continue;
            const float bb = bias ? bias[gn] : 0.f;
            #pragma unroll
            for (int p = 0; p < 4; ++p) {
                const int gm = bm + wm * 64 + i * 16 + g * 4 + p;
                if (gm >= M) continue;
                const float v = acc[i][j][p] * alpha + bb;
                if (C)   C[(size_t)gm * ldc + gn] = v;
                if (Cbf) Cbf[(size_t)gm * ldc + gn] = f2b(v);
            }
        }
    }
}

// ---------------------------------------------------------------------------
// Stage-1 softmax over n=2000 (bf16 scores) + per-wave partial column sums.
// ---------------------------------------------------------------------------
__global__ __launch_bounds__(256) void softmax_colsum_kernel(
    const ushort* __restrict__ sc, float* __restrict__ part)
{
    const int wave = threadIdx.x >> 6, lane = threadIdx.x & 63;
    const int slot = blockIdx.x * 4 + wave;      // 0..511
    float acc[32];
    #pragma unroll
    for (int i = 0; i < 32; ++i) acc[i] = 0.f;
    for (int rr = 0; rr < 8; ++rr) {
        const unsigned int* row =
            (const unsigned int*)(sc + (size_t)(slot * 8 + rr) * 2000);
        float v[32];
        float m = -1e30f;
        #pragma unroll
        for (int ii = 0; ii < 16; ++ii) {
            const int di = lane + 64 * ii;       // dword index, 1000 per row
            const unsigned int u = (di < 1000) ? row[di] : 0xFF80FF80u;
            v[2 * ii]     = bf2f((short)(u & 0xffff));
            v[2 * ii + 1] = bf2f((short)(u >> 16));
            m = fmaxf(m, fmaxf(v[2 * ii], v[2 * ii + 1]));
        }
        #pragma unroll
        for (int off = 32; off; off >>= 1) m = fmaxf(m, __shfl_xor(m, off));
        float sum = 0.f;
        #pragma unroll
        for (int i = 0; i < 32; ++i) { v[i] = __expf(v[i] - m); sum += v[i]; }
        #pragma unroll
        for (int off = 32; off; off >>= 1) sum += __shfl_xor(sum, off);
        const float inv = 1.f / sum;
        #pragma unroll
        for (int i = 0; i < 32; ++i) acc[i] += v[i] * inv;
    }
    float* p = part + (size_t)slot * 2000;
    #pragma unroll
    for (int ii = 0; ii < 16; ++ii) {
        const int di = lane + 64 * ii;
        if (di < 1000) {
            float2 w; w.x = acc[2 * ii]; w.y = acc[2 * ii + 1];
            ((float2*)p)[di] = w;
        }
    }
}

// part[512][2000] -> part2[4][2000]; grid (8,4)
__global__ void reduce_partials_kernel(const float* __restrict__ part,
                                       float* __restrict__ part2)
{
    const int n = blockIdx.x * 256 + threadIdx.x;
    if (n >= 2000) return;
    const int q = blockIdx.y;
    float s = 0.f;
    for (int sl = q * 128; sl < q * 128 + 128; ++sl) s += part[(size_t)sl * 2000 + n];
    part2[(size_t)q * 2000 + n] = s;
}

// ---------------------------------------------------------------------------
// Top-101 of 2000: SINGLE WAVE, all candidates register-resident (32/lane,
// n = lane + 64*i). Per iter: 32-reg scan (strict > keeps lowest index),
// 6-step shfl butterfly w/ index tie-break, owner masks via unrolled select.
// No barriers, no LDS. Deterministic, matches jax.lax.top_k semantics.
// ---------------------------------------------------------------------------
__global__ void topk_kernel(const float* __restrict__ part2,
                            int* __restrict__ idx)
{
    const int lane = threadIdx.x;   // block = 64
    float v[32];
    #pragma unroll
    for (int i = 0; i < 32; ++i) {
        const int n = lane + 64 * i;
        v[i] = (n < 2000)
            ? part2[n] + part2[2000 + n] + part2[4000 + n] + part2[6000 + n]
            : -1e30f;
    }
    for (int it = 0; it < 101; ++it) {
        float bv = -1e30f; int bi = 1 << 30;
        #pragma unroll
        for (int i = 0; i < 32; ++i) {
            // ascending n within lane: strict > keeps lowest index on tie
            if (v[i] > bv) { bv = v[i]; bi = lane + 64 * i; }
        }
        #pragma unroll
        for (int off = 32; off; off >>= 1) {
            const float ov = __shfl_xor(bv, off);
            const int oi = __shfl_xor(bi, off);
            if (ov > bv || (ov == bv && oi < bi)) { bv = ov; bi = oi; }
        }
        if (lane == 0) idx[it] = bi;
        // owner lane masks the selected slot (no dynamic reg indexing)
        if ((bi & 63) == lane) {
            const int isel = bi >> 6;
            #pragma unroll
            for (int i = 0; i < 32; ++i)
                if (i == isel) v[i] = -1e30f;
        }
    }
}

// gather selected context rows from bf16 ce: one block per row, uint per thread
__global__ void gather_bf_kernel(const ushort* __restrict__ cebf,
                                 const int* __restrict__ idx,
                                 ushort* __restrict__ ctxfbf)
{
    const int r = blockIdx.x;
    const int src = idx[r];
    const int tid = threadIdx.x;
    ((unsigned int*)ctxfbf)[r * 256 + tid] =
        ((const unsigned int*)cebf)[(size_t)src * 256 + tid];
}

// wo [512][512] f32 -> woT bf16 (woT[j][k] = wo[k][j])
__global__ void transpose512_bf(const float* __restrict__ in, ushort* __restrict__ out)
{
    __shared__ float tile[32][33];
    const int tx = threadIdx.x & 31, ty = threadIdx.x >> 5;  // 32x8
    const int bx = blockIdx.x * 32, by = blockIdx.y * 32;
    #pragma unroll
    for (int rr = 0; rr < 4; ++rr)
        tile[ty + 8 * rr][tx] = in[(size_t)(by + ty + 8 * rr) * 512 + bx + tx];
    __syncthreads();
    #pragma unroll
    for (int rr = 0; rr < 4; ++rr)
        out[(size_t)(bx + ty + 8 * rr) * 512 + by + tx] = f2b(tile[tx][ty + 8 * rr]);
}

// v2bf [101][512] -> v2tp [4][128][128]: v2tp[h][d][n] = v2bf[n][h*128+d], 0 pad
__global__ void v2tp_kernel(const ushort* __restrict__ v2bf, ushort* __restrict__ v2tp)
{
    const int e = blockIdx.x * 256 + threadIdx.x;   // 0..65535
    const int h = e >> 14, rem = e & 16383;
    const int d = rem >> 7, n = rem & 127;
    v2tp[e] = (n < 101) ? v2bf[(size_t)n * 512 + h * 128 + d] : (ushort)0;
}

__global__ void bc2_kernel(const float* __restrict__ wc, const float* __restrict__ bo,
                           const float* __restrict__ bcb, float* __restrict__ bc2)
{
    const int d = blockIdx.x * 256 + threadIdx.x;
    float s = bcb[d];
    const float4* wr = (const float4*)(wc + (size_t)d * 512);
    const float4* br = (const float4*)bo;
    for (int m4 = 0; m4 < 128; ++m4) {
        const float4 w4 = wr[m4], b4 = br[m4];
        s += w4.x * b4.x + w4.y * b4.y + w4.z * b4.z + w4.w * b4.w;
    }
    bc2[d] = s;
}

// ---------------------------------------------------------------------------
// Stage-2 row softmax: s2 f32 [4][8192][104] -> attn_p bf16 [4][8192][128]
// ---------------------------------------------------------------------------
__global__ __launch_bounds__(256) void softmax2_kernel(
    const float* __restrict__ s2, ushort* __restrict__ ap)
{
    const int wave = threadIdx.x >> 6, lane = threadIdx.x & 63;
    const int w = blockIdx.x * 4 + wave;       // 0..1023
    const int e0 = 2 * lane, e1 = 2 * lane + 1;
    for (int rr = 0; rr < 32; ++rr) {
        const int row = w * 32 + rr;           // 0..32767
        const float* sr = s2 + (size_t)row * 104;
        float v0 = -1e30f, v1 = -1e30f;
        if (e0 < 101) {
            const float2 t = *(const float2*)(sr + e0);
            v0 = t.x;
            if (e1 < 101) v1 = t.y;
        }
        float m = fmaxf(v0, v1);
        #pragma unroll
        for (int off = 32; off; off >>= 1) m = fmaxf(m, __shfl_xor(m, off));
        const float p0 = (e0 < 101) ? __expf(v0 - m) : 0.f;
        const float p1 = (e1 < 101) ? __expf(v1 - m) : 0.f;
        float sum = p0 + p1;
        #pragma unroll
        for (int off = 32; off; off >>= 1) sum += __shfl_xor(sum, off);
        const float inv = 1.f / sum;
        const unsigned int ow =
            (unsigned int)f2b(p0 * inv) | ((unsigned int)f2b(p1 * inv) << 16);
        ((unsigned int*)ap)[(size_t)row * 64 + lane] = ow;
    }
}

// ---------------------------------------------------------------------------
// Residual + LayerNorm
// ---------------------------------------------------------------------------
__global__ __launch_bounds__(256) void ln_kernel(
    const float* __restrict__ tmp, const float* __restrict__ enc,
    const float* __restrict__ g, const float* __restrict__ bta,
    float* __restrict__ out)
{
    __shared__ float rs[4], rv[4];
    const int row = blockIdx.x, tid = threadIdx.x;
    const int wave = tid >> 6, lane = tid & 63;
    const size_t base = (size_t)row * 512;
    const float x0 = tmp[base + tid] + enc[base + tid];
    const float x1 = tmp[base + tid + 256] + enc[base + tid + 256];
    float s = x0 + x1;
    #pragma unroll
    for (int off = 32; off; off >>= 1) s += __shfl_xor(s, off);
    if (lane == 0) rs[wave] = s;
    __syncthreads();
    const float mu = (rs[0] + rs[1] + rs[2] + rs[3]) * (1.f / 512.f);
    const float d0 = x0 - mu, d1 = x1 - mu;
    float vv = d0 * d0 + d1 * d1;
    #pragma unroll
    for (int off = 32; off; off >>= 1) vv += __shfl_xor(vv, off);
    if (lane == 0) rv[wave] = vv;
    __syncthreads();
    const float var = (rv[0] + rv[1] + rv[2] + rv[3]) * (1.f / 512.f);
    const float rstd = rsqrtf(var + 1e-5f);
    out[base + tid] = d0 * rstd * g[tid] + bta[tid];
    out[base + tid + 256] = d1 * rstd * g[tid + 256] + bta[tid + 256];
}

extern "C" void kernel_launch(void* const* d_in, const int* in_sizes, int n_in,
                              void* d_out, int out_size, void* d_ws, size_t ws_size,
                              hipStream_t stream)
{
    const float* ce  = (const float*)d_in[0];
    const float* enc = (const float*)d_in[1];
    const float* wq  = (const float*)d_in[2];
    const float* bq  = (const float*)d_in[3];
    const float* wk  = (const float*)d_in[4];
    const float* bk  = (const float*)d_in[5];
    const float* wv  = (const float*)d_in[6];
    const float* bv  = (const float*)d_in[7];
    const float* wo  = (const float*)d_in[8];
    const float* bo  = (const float*)d_in[9];
    const float* wc  = (const float*)d_in[10];
    const float* bcb = (const float*)d_in[11];
    const float* lng = (const float*)d_in[12];
    const float* lnb = (const float*)d_in[13];
    float* ws  = (float*)d_ws;
    float* out = (float*)d_out;

    ushort* qbf    = (ushort*)(ws + OFF_QBF);    // later: obf
    ushort* obf    = (ushort*)(ws + OFF_QBF);
    ushort* scb    = (ushort*)(ws + OFF_RA);     // later: s2 (f32)
    float*  s2     = ws + OFF_RA;
    ushort* encbf  = (ushort*)(ws + OFF_RB);     // -> kcbf -> attn_p
    ushort* kcbf   = (ushort*)(ws + OFF_RB);
    ushort* attnp  = (ushort*)(ws + OFF_RB);
    float*  part   = ws + OFF_PART;
    float*  part2  = ws + OFF_PART2;
    int*    idx    = (int*)(ws + OFF_IDX);
    float*  tmp    = ws + OFF_TMP;
    ushort* cebf   = (ushort*)(ws + OFF_CEBF);
    ushort* ctxfbf = (ushort*)(ws + OFF_CTXFBF);
    ushort* k2bf   = (ushort*)(ws + OFF_K2BF);
    ushort* v2bf   = (ushort*)(ws + OFF_V2BF);
    ushort* v2tp   = (ushort*)(ws + OFF_V2TP);
    ushort* wqbf   = (ushort*)(ws + OFF_WQBF);
    ushort* wkbf   = (ushort*)(ws + OFF_WKBF);
    ushort* wvbf   = (ushort*)(ws + OFF_WVBF);
    ushort* wcbf   = (ushort*)(ws + OFF_WCBF);
    ushort* wotbf  = (ushort*)(ws + OFF_WOTBF);
    ushort* wc2bf  = (ushort*)(ws + OFF_WC2BF);
    float*  bc2    = ws + OFF_BC2;

    // bf16 conversions
    cvt_bf16_kernel<<<4096, 256, 0, stream>>>(enc, encbf, 1048576);
    cvt_bf16_kernel<<<1000, 256, 0, stream>>>(ce, cebf, 256000);
    cvt_bf16_kernel<<<256, 256, 0, stream>>>(wq, wqbf, 65536);
    cvt_bf16_kernel<<<256, 256, 0, stream>>>(wk, wkbf, 65536);
    cvt_bf16_kernel<<<256, 256, 0, stream>>>(wv, wvbf, 65536);
    cvt_bf16_kernel<<<256, 256, 0, stream>>>(wc, wcbf, 65536);
    transpose512_bf<<<dim3(16, 16), 256, 0, stream>>>(wo, wotbf);

    // q = enc @ wq^T + bq -> bf16 [8192][512]
    gemm_mfma<<<dim3(4, 64, 1), 256, 0, stream>>>(encbf, 512, 0, wqbf, 512, 0, bq,
                                                  nullptr, qbf, 512, 0,
                                                  8192, 512, 512, 1.f);
    // kc = ctx @ wk^T + bk -> bf16 [2000][512]
    gemm_mfma<<<dim3(4, 16, 1), 256, 0, stream>>>(cebf, 512, 0, wkbf, 512, 0, bk,
                                                  nullptr, kcbf, 512, 0,
                                                  2000, 512, 512, 1.f);
    // stage-1 scores (b=0, batched over h): bf16 [4][1024][2000]
    gemm_mfma<<<dim3(16, 8, 4), 256, 0, stream>>>(qbf, 512, 128, kcbf, 512, 128,
                                                  nullptr, nullptr, scb,
                                                  2000, 2048000LL,
                                                  1024, 2000, 128, SCALE);
    softmax_colsum_kernel<<<128, 256, 0, stream>>>(scb, part);
    reduce_partials_kernel<<<dim3(8, 4), 256, 0, stream>>>(part, part2);
    topk_kernel<<<1, 64, 0, stream>>>(part2, idx);
    gather_bf_kernel<<<101, 256, 0, stream>>>(cebf, idx, ctxfbf);
    // k2/v2 projections of the 101 selected contexts (MFMA, bf16 out)
    gemm_mfma<<<dim3(4, 1, 1), 256, 0, stream>>>(ctxfbf, 512, 0, wkbf, 512, 0, bk,
                                                 nullptr, k2bf, 512, 0,
                                                 101, 512, 512, 1.f);
    gemm_mfma<<<dim3(4, 1, 1), 256, 0, stream>>>(ctxfbf, 512, 0, wvbf, 512, 0, bv,
                                                 nullptr, v2bf, 512, 0,
                                                 101, 512, 512, 1.f);
    v2tp_kernel<<<256, 256, 0, stream>>>(v2bf, v2tp);
    // fold wo/w_comb: Wc2 = wc @ wo, bc2 = wc @ bo + bc
    bc2_kernel<<<2, 256, 0, stream>>>(wc, bo, bcb, bc2);
    gemm_mfma<<<dim3(4, 4, 1), 256, 0, stream>>>(wcbf, 512, 0, wotbf, 512, 0, nullptr,
                                                 nullptr, wc2bf, 512, 0,
                                                 512, 512, 512, 1.f);
    // stage-2 scores: s2[h][m][n] = SCALE * q_h[m] . k2_h[n], f32, ldc=104
    gemm_mfma<<<dim3(1, 64, 4), 256, 0, stream>>>(qbf, 512, 128, k2bf, 512, 128,
                                                  nullptr, s2, nullptr,
                                                  104, 851968LL,
                                                  8192, 101, 128, SCALE);
    // row softmax over 101 -> bf16 probs padded to 128
    softmax2_kernel<<<256, 256, 0, stream>>>(s2, attnp);
    // o = attn_p @ v2tp^T (per head) -> obf [8192][512] head-interleaved
    gemm_mfma<<<dim3(1, 64, 4), 256, 0, stream>>>(attnp, 128, 1048576LL,
                                                  v2tp, 128, 16384LL, nullptr,
                                                  nullptr, obf, 512, 128,
                                                  8192, 128, 128, 1.f);
    // tmp = o @ Wc2^T + bc2 (f32)
    gemm_mfma<<<dim3(4, 64, 1), 256, 0, stream>>>(obf, 512, 0, wc2bf, 512, 0, bc2,
                                                  tmp, nullptr, 512, 0,
                                                  8192, 512, 512, 1.f);
    // residual + LayerNorm
    ln_kernel<<<8192, 256, 0, stream>>>(tmp, enc, lng, lnb, out);
    (void)in_sizes; (void)n_in; (void)out_size; (void)ws_size;
}

// Round 7
// 311.657 us; speedup vs baseline: 1.9922x; 1.2502x over previous
//
#include <hip/hip_runtime.h>
#include <hip/hip_bf16.h>

// ContextModule R7: = R6 + radix-select top-k (ballot/popcount, zero cross-lane
// data movement, zero LDS, zero barriers). ws 55.6 MB, aliases time-disjoint.

typedef short bhalf8 __attribute__((ext_vector_type(8)));   // 8 bf16 = 4 VGPR
typedef float f32x4 __attribute__((ext_vector_type(4)));

#define SCALE 0.08838834764831845f  // 1/sqrt(128)

// ---- ws layout (float offsets) ----
#define OFF_QBF    ((size_t)0)               // qbf bf16 [8192][512]; later obf
#define OFF_RA     ((size_t)2097152)         // scb bf16 [4][1024][2000]; later s2 f32 [4][8192][104]
#define OFF_RB     ((size_t)6193152)         // encbf -> kcbf -> attn_p
#define OFF_TMP    ((size_t)8290304)         // part/part2/idx early; tmp f32 late
#define OFF_PART   (OFF_TMP)                 // [512][2000] f32
#define OFF_PART2  (OFF_TMP + 1024000)       // [4][2000] f32
#define OFF_IDX    (OFF_TMP + 1032000)       // 128 ints
#define OFF_CEBF   ((size_t)12484608)        // ce bf16 [2000][512]
#define OFF_CTXFBF ((size_t)12996608)        // ctxf bf16 [101][512]
#define OFF_K2BF   ((size_t)13022608)        // k2 bf16 [101][512]
#define OFF_V2BF   ((size_t)13048608)        // v2 bf16 [101][512]
#define OFF_V2TP   ((size_t)13074608)        // v2tp bf16 [4][128][128]
#define OFF_WQBF   ((size_t)13107376)
#define OFF_WKBF   ((size_t)13238448)
#define OFF_WVBF   ((size_t)13369520)
#define OFF_WCBF   ((size_t)13500592)
#define OFF_WOTBF  ((size_t)13631664)
#define OFF_WC2BF  ((size_t)13762736)
#define OFF_BC2    ((size_t)13893808)        // 512
// total 13,894,320 fl = 55.6 MB

__device__ __forceinline__ float bf2f(short u) {
    union { float f; unsigned int i; } x;
    x.i = ((unsigned int)(unsigned short)u) << 16;
    return x.f;
}
__device__ __forceinline__ ushort f2b(float f) {
    union { float f; unsigned int i; } x; x.f = f;
    return (ushort)((x.i + 0x7fff + ((x.i >> 16) & 1)) >> 16);  // RNE
}

// f32 -> bf16 bulk convert, 4 elems/thread
__global__ __launch_bounds__(256) void cvt_bf16_kernel(
    const float* __restrict__ in, ushort* __restrict__ out, int n4)
{
    const int i = blockIdx.x * 256 + threadIdx.x;
    if (i >= n4) return;
    const float4 v = ((const float4*)in)[i];
    ushort4 r;
    r.x = f2b(v.x); r.y = f2b(v.y); r.z = f2b(v.z); r.w = f2b(v.w);
    ((ushort4*)out)[i] = r;
}

// ---------------------------------------------------------------------------
// bf16 MFMA NT GEMM: C[m][n] = alpha*sum_k A[m][k]*W[n][k] (+bias[n])
// 128x128 tile, BK=32, 4 waves (2x2), wave tile 64x64. LDS 16B-chunk XOR
// swizzle -> ds_write/read_b128 at conflict-free floor.
// ---------------------------------------------------------------------------
__global__ __launch_bounds__(256) void gemm_mfma(
    const ushort* __restrict__ A, int lda, long long sAz,
    const ushort* __restrict__ W, int ldw, long long sWz,
    const float* __restrict__ bias,
    float* __restrict__ C, ushort* __restrict__ Cbf,
    int ldc, long long sCz,
    int M, int N, int K, float alpha)
{
    __shared__ __align__(16) ushort As[128 * 32];
    __shared__ __align__(16) ushort Bs[128 * 32];
    const int tid = threadIdx.x;
    const int wave = tid >> 6, lane = tid & 63;
    const int wm = wave >> 1, wn = wave & 1;
    const int mr = lane & 15, g = lane >> 4;
    const int bm = blockIdx.y * 128, bn = blockIdx.x * 128;
    A += (size_t)blockIdx.z * (size_t)sAz;
    W += (size_t)blockIdx.z * (size_t)sWz;

    f32x4 acc[4][4];
    #pragma unroll
    for (int i = 0; i < 4; ++i)
        #pragma unroll
        for (int j = 0; j < 4; ++j)
            #pragma unroll
            for (int p = 0; p < 4; ++p) acc[i][j][p] = 0.f;

    const int r0 = tid >> 2;     // 0..63
    const int c0 = tid & 3;      // 16B chunk in 32-k row
    const int sw0 = (r0 * 4 + (c0 ^ (r0 & 3))) * 8;
    const int sw1 = ((r0 + 64) * 4 + (c0 ^ (r0 & 3))) * 8;
    const uint4 zz = make_uint4(0u, 0u, 0u, 0u);

    for (int k0 = 0; k0 < K; k0 += 32) {
        const int ka = k0 + c0 * 8;
        uint4 av0 = zz, av1 = zz, bv0 = zz, bv1 = zz;
        if (bm + r0 < M)      av0 = *(const uint4*)(A + (size_t)(bm + r0) * lda + ka);
        if (bm + r0 + 64 < M) av1 = *(const uint4*)(A + (size_t)(bm + r0 + 64) * lda + ka);
        if (bn + r0 < N)      bv0 = *(const uint4*)(W + (size_t)(bn + r0) * ldw + ka);
        if (bn + r0 + 64 < N) bv1 = *(const uint4*)(W + (size_t)(bn + r0 + 64) * ldw + ka);
        __syncthreads();   // previous tile fully consumed
        *(uint4*)&As[sw0] = av0;
        *(uint4*)&As[sw1] = av1;
        *(uint4*)&Bs[sw0] = bv0;
        *(uint4*)&Bs[sw1] = bv1;
        __syncthreads();
        bhalf8 a[4], b[4];
        const int ksw = (g ^ (mr & 3)) << 3;
        #pragma unroll
        for (int i = 0; i < 4; ++i)
            a[i] = *(const bhalf8*)&As[(wm * 64 + i * 16 + mr) * 32 + ksw];
        #pragma unroll
        for (int j = 0; j < 4; ++j)
            b[j] = *(const bhalf8*)&Bs[(wn * 64 + j * 16 + mr) * 32 + ksw];
        #pragma unroll
        for (int i = 0; i < 4; ++i)
            #pragma unroll
            for (int j = 0; j < 4; ++j)
                acc[i][j] = __builtin_amdgcn_mfma_f32_16x16x32_bf16(
                    a[i], b[j], acc[i][j], 0, 0, 0);
    }

    if (C)   C   += (size_t)blockIdx.z * (size_t)sCz;
    if (Cbf) Cbf += (size_t)blockIdx.z * (size_t)sCz;
    #pragma unroll
    for (int i = 0; i < 4; ++i) {
        #pragma unroll
        for (int j = 0; j < 4; ++j) {
            const int gn = bn + wn * 64 + j * 16 + mr;
            if (gn >= N) continue;
            const float bb = bias ? bias[gn] : 0.f;
            #pragma unroll
            for (int p = 0; p < 4; ++p) {
                const int gm = bm + wm * 64 + i * 16 + g * 4 + p;
                if (gm >= M) continue;
                const float v = acc[i][j][p] * alpha + bb;
                if (C)   C[(size_t)gm * ldc + gn] = v;
                if (Cbf) Cbf[(size_t)gm * ldc + gn] = f2b(v);
            }
        }
    }
}

// ---------------------------------------------------------------------------
// Stage-1 softmax over n=2000 (bf16 scores) + per-wave partial column sums.
// ---------------------------------------------------------------------------
__global__ __launch_bounds__(256) void softmax_colsum_kernel(
    const ushort* __restrict__ sc, float* __restrict__ part)
{
    const int wave = threadIdx.x >> 6, lane = threadIdx.x & 63;
    const int slot = blockIdx.x * 4 + wave;      // 0..511
    float acc[32];
    #pragma unroll
    for (int i = 0; i < 32; ++i) acc[i] = 0.f;
    for (int rr = 0; rr < 8; ++rr) {
        const unsigned int* row =
            (const unsigned int*)(sc + (size_t)(slot * 8 + rr) * 2000);
        float v[32];
        float m = -1e30f;
        #pragma unroll
        for (int ii = 0; ii < 16; ++ii) {
            const int di = lane + 64 * ii;       // dword index, 1000 per row
            const unsigned int u = (di < 1000) ? row[di] : 0xFF80FF80u;
            v[2 * ii]     = bf2f((short)(u & 0xffff));
            v[2 * ii + 1] = bf2f((short)(u >> 16));
            m = fmaxf(m, fmaxf(v[2 * ii], v[2 * ii + 1]));
        }
        #pragma unroll
        for (int off = 32; off; off >>= 1) m = fmaxf(m, __shfl_xor(m, off));
        float sum = 0.f;
        #pragma unroll
        for (int i = 0; i < 32; ++i) { v[i] = __expf(v[i] - m); sum += v[i]; }
        #pragma unroll
        for (int off = 32; off; off >>= 1) sum += __shfl_xor(sum, off);
        const float inv = 1.f / sum;
        #pragma unroll
        for (int i = 0; i < 32; ++i) acc[i] += v[i] * inv;
    }
    float* p = part + (size_t)slot * 2000;
    #pragma unroll
    for (int ii = 0; ii < 16; ++ii) {
        const int di = lane + 64 * ii;
        if (di < 1000) {
            float2 w; w.x = acc[2 * ii]; w.y = acc[2 * ii + 1];
            ((float2*)p)[di] = w;
        }
    }
}

// part[512][2000] -> part2[4][2000]; grid (8,4)
__global__ void reduce_partials_kernel(const float* __restrict__ part,
                                       float* __restrict__ part2)
{
    const int n = blockIdx.x * 256 + threadIdx.x;
    if (n >= 2000) return;
    const int q = blockIdx.y;
    float s = 0.f;
    for (int sl = q * 128; sl < q * 128 + 128; ++sl) s += part[(size_t)sl * 2000 + n];
    part2[(size_t)q * 2000 + n] = s;
}

// ---------------------------------------------------------------------------
// Top-101 of 2000 via MSB-first radix-select on monotonic uint keys.
// Single wave, 32 candidates/lane (n = lane + 64*i). Wave-wide counts use
// __ballot (v_cmp side-effect -> SGPR mask) + popcount: NO shuffles, NO LDS,
// NO barriers anywhere. Selection == jax.lax.top_k (lowest index on ties);
// output order is deterministic (downstream is permutation-invariant).
// ---------------------------------------------------------------------------
__global__ void topk_kernel(const float* __restrict__ part2,
                            int* __restrict__ idx)
{
    const int lane = threadIdx.x;   // block = 64
    const unsigned long long below = (1ull << lane) - 1ull;

    // load + monotonic key transform (values are >=0, but full transform for safety)
    unsigned key[32];
    #pragma unroll
    for (int i = 0; i < 32; ++i) {
        const int n = lane + 64 * i;
        float s = -1e30f;
        if (n < 2000)
            s = part2[n] + part2[2000 + n] + part2[4000 + n] + part2[6000 + n];
        const unsigned u = __float_as_uint(s);
        key[i] = u ^ ((unsigned)((int)u >> 31) | 0x80000000u);
    }

    // radix-select the 101st-largest key T
    unsigned prefix = 0;
    int remaining = 101;
    for (int b = 31; b >= 0; --b) {
        const unsigned tgt = (prefix << 1) | 1u;
        int cnt = 0;
        #pragma unroll
        for (int i = 0; i < 32; ++i)
            cnt += (int)__popcll(__ballot((key[i] >> b) == tgt));
        if (cnt >= remaining) prefix = tgt;
        else { remaining -= cnt; prefix = prefix << 1; }
    }
    const unsigned T = prefix;

    // compact: all keys > T, then `remaining` lowest-index keys == T
    int base = 0;
    #pragma unroll
    for (int i = 0; i < 32; ++i) {
        const unsigned long long m = __ballot(key[i] > T);
        if (key[i] > T) idx[base + (int)__popcll(m & below)] = lane + 64 * i;
        base += (int)__popcll(m);
    }
    int r = remaining;
    #pragma unroll
    for (int i = 0; i < 32; ++i) {
        const unsigned long long m = __ballot(key[i] == T);
        const int cb = (int)__popcll(m & below);
        if (key[i] == T && cb < r) idx[base + cb] = lane + 64 * i;
        const int take = min(r, (int)__popcll(m));
        base += take; r -= take;
    }
}

// gather selected context rows from bf16 ce: one block per row, uint per thread
__global__ void gather_bf_kernel(const ushort* __restrict__ cebf,
                                 const int* __restrict__ idx,
                                 ushort* __restrict__ ctxfbf)
{
    const int r = blockIdx.x;
    const int src = idx[r];
    const int tid = threadIdx.x;
    ((unsigned int*)ctxfbf)[r * 256 + tid] =
        ((const unsigned int*)cebf)[(size_t)src * 256 + tid];
}

// wo [512][512] f32 -> woT bf16 (woT[j][k] = wo[k][j])
__global__ void transpose512_bf(const float* __restrict__ in, ushort* __restrict__ out)
{
    __shared__ float tile[32][33];
    const int tx = threadIdx.x & 31, ty = threadIdx.x >> 5;  // 32x8
    const int bx = blockIdx.x * 32, by = blockIdx.y * 32;
    #pragma unroll
    for (int rr = 0; rr < 4; ++rr)
        tile[ty + 8 * rr][tx] = in[(size_t)(by + ty + 8 * rr) * 512 + bx + tx];
    __syncthreads();
    #pragma unroll
    for (int rr = 0; rr < 4; ++rr)
        out[(size_t)(bx + ty + 8 * rr) * 512 + by + tx] = f2b(tile[tx][ty + 8 * rr]);
}

// v2bf [101][512] -> v2tp [4][128][128]: v2tp[h][d][n] = v2bf[n][h*128+d], 0 pad
__global__ void v2tp_kernel(const ushort* __restrict__ v2bf, ushort* __restrict__ v2tp)
{
    const int e = blockIdx.x * 256 + threadIdx.x;   // 0..65535
    const int h = e >> 14, rem = e & 16383;
    const int d = rem >> 7, n = rem & 127;
    v2tp[e] = (n < 101) ? v2bf[(size_t)n * 512 + h * 128 + d] : (ushort)0;
}

__global__ void bc2_kernel(const float* __restrict__ wc, const float* __restrict__ bo,
                           const float* __restrict__ bcb, float* __restrict__ bc2)
{
    const int d = blockIdx.x * 256 + threadIdx.x;
    float s = bcb[d];
    const float4* wr = (const float4*)(wc + (size_t)d * 512);
    const float4* br = (const float4*)bo;
    for (int m4 = 0; m4 < 128; ++m4) {
        const float4 w4 = wr[m4], b4 = br[m4];
        s += w4.x * b4.x + w4.y * b4.y + w4.z * b4.z + w4.w * b4.w;
    }
    bc2[d] = s;
}

// ---------------------------------------------------------------------------
// Stage-2 row softmax: s2 f32 [4][8192][104] -> attn_p bf16 [4][8192][128]
// ---------------------------------------------------------------------------
__global__ __launch_bounds__(256) void softmax2_kernel(
    const float* __restrict__ s2, ushort* __restrict__ ap)
{
    const int wave = threadIdx.x >> 6, lane = threadIdx.x & 63;
    const int w = blockIdx.x * 4 + wave;       // 0..1023
    const int e0 = 2 * lane, e1 = 2 * lane + 1;
    for (int rr = 0; rr < 32; ++rr) {
        const int row = w * 32 + rr;           // 0..32767
        const float* sr = s2 + (size_t)row * 104;
        float v0 = -1e30f, v1 = -1e30f;
        if (e0 < 101) {
            const float2 t = *(const float2*)(sr + e0);
            v0 = t.x;
            if (e1 < 101) v1 = t.y;
        }
        float m = fmaxf(v0, v1);
        #pragma unroll
        for (int off = 32; off; off >>= 1) m = fmaxf(m, __shfl_xor(m, off));
        const float p0 = (e0 < 101) ? __expf(v0 - m) : 0.f;
        const float p1 = (e1 < 101) ? __expf(v1 - m) : 0.f;
        float sum = p0 + p1;
        #pragma unroll
        for (int off = 32; off; off >>= 1) sum += __shfl_xor(sum, off);
        const float inv = 1.f / sum;
        const unsigned int ow =
            (unsigned int)f2b(p0 * inv) | ((unsigned int)f2b(p1 * inv) << 16);
        ((unsigned int*)ap)[(size_t)row * 64 + lane] = ow;
    }
}

// ---------------------------------------------------------------------------
// Residual + LayerNorm
// ---------------------------------------------------------------------------
__global__ __launch_bounds__(256) void ln_kernel(
    const float* __restrict__ tmp, const float* __restrict__ enc,
    const float* __restrict__ g, const float* __restrict__ bta,
    float* __restrict__ out)
{
    __shared__ float rs[4], rv[4];
    const int row = blockIdx.x, tid = threadIdx.x;
    const int wave = tid >> 6, lane = tid & 63;
    const size_t base = (size_t)row * 512;
    const float x0 = tmp[base + tid] + enc[base + tid];
    const float x1 = tmp[base + tid + 256] + enc[base + tid + 256];
    float s = x0 + x1;
    #pragma unroll
    for (int off = 32; off; off >>= 1) s += __shfl_xor(s, off);
    if (lane == 0) rs[wave] = s;
    __syncthreads();
    const float mu = (rs[0] + rs[1] + rs[2] + rs[3]) * (1.f / 512.f);
    const float d0 = x0 - mu, d1 = x1 - mu;
    float vv = d0 * d0 + d1 * d1;
    #pragma unroll
    for (int off = 32; off; off >>= 1) vv += __shfl_xor(vv, off);
    if (lane == 0) rv[wave] = vv;
    __syncthreads();
    const float var = (rv[0] + rv[1] + rv[2] + rv[3]) * (1.f / 512.f);
    const float rstd = rsqrtf(var + 1e-5f);
    out[base + tid] = d0 * rstd * g[tid] + bta[tid];
    out[base + tid + 256] = d1 * rstd * g[tid + 256] + bta[tid + 256];
}

extern "C" void kernel_launch(void* const* d_in, const int* in_sizes, int n_in,
                              void* d_out, int out_size, void* d_ws, size_t ws_size,
                              hipStream_t stream)
{
    const float* ce  = (const float*)d_in[0];
    const float* enc = (const float*)d_in[1];
    const float* wq  = (const float*)d_in[2];
    const float* bq  = (const float*)d_in[3];
    const float* wk  = (const float*)d_in[4];
    const float* bk  = (const float*)d_in[5];
    const float* wv  = (const float*)d_in[6];
    const float* bv  = (const float*)d_in[7];
    const float* wo  = (const float*)d_in[8];
    const float* bo  = (const float*)d_in[9];
    const float* wc  = (const float*)d_in[10];
    const float* bcb = (const float*)d_in[11];
    const float* lng = (const float*)d_in[12];
    const float* lnb = (const float*)d_in[13];
    float* ws  = (float*)d_ws;
    float* out = (float*)d_out;

    ushort* qbf    = (ushort*)(ws + OFF_QBF);    // later: obf
    ushort* obf    = (ushort*)(ws + OFF_QBF);
    ushort* scb    = (ushort*)(ws + OFF_RA);     // later: s2 (f32)
    float*  s2     = ws + OFF_RA;
    ushort* encbf  = (ushort*)(ws + OFF_RB);     // -> kcbf -> attn_p
    ushort* kcbf   = (ushort*)(ws + OFF_RB);
    ushort* attnp  = (ushort*)(ws + OFF_RB);
    float*  part   = ws + OFF_PART;
    float*  part2  = ws + OFF_PART2;
    int*    idx    = (int*)(ws + OFF_IDX);
    float*  tmp    = ws + OFF_TMP;
    ushort* cebf   = (ushort*)(ws + OFF_CEBF);
    ushort* ctxfbf = (ushort*)(ws + OFF_CTXFBF);
    ushort* k2bf   = (ushort*)(ws + OFF_K2BF);
    ushort* v2bf   = (ushort*)(ws + OFF_V2BF);
    ushort* v2tp   = (ushort*)(ws + OFF_V2TP);
    ushort* wqbf   = (ushort*)(ws + OFF_WQBF);
    ushort* wkbf   = (ushort*)(ws + OFF_WKBF);
    ushort* wvbf   = (ushort*)(ws + OFF_WVBF);
    ushort* wcbf   = (ushort*)(ws + OFF_WCBF);
    ushort* wotbf  = (ushort*)(ws + OFF_WOTBF);
    ushort* wc2bf  = (ushort*)(ws + OFF_WC2BF);
    float*  bc2    = ws + OFF_BC2;

    // bf16 conversions
    cvt_bf16_kernel<<<4096, 256, 0, stream>>>(enc, encbf, 1048576);
    cvt_bf16_kernel<<<1000, 256, 0, stream>>>(ce, cebf, 256000);
    cvt_bf16_kernel<<<256, 256, 0, stream>>>(wq, wqbf, 65536);
    cvt_bf16_kernel<<<256, 256, 0, stream>>>(wk, wkbf, 65536);
    cvt_bf16_kernel<<<256, 256, 0, stream>>>(wv, wvbf, 65536);
    cvt_bf16_kernel<<<256, 256, 0, stream>>>(wc, wcbf, 65536);
    transpose512_bf<<<dim3(16, 16), 256, 0, stream>>>(wo, wotbf);

    // q = enc @ wq^T + bq -> bf16 [8192][512]
    gemm_mfma<<<dim3(4, 64, 1), 256, 0, stream>>>(encbf, 512, 0, wqbf, 512, 0, bq,
                                                  nullptr, qbf, 512, 0,
                                                  8192, 512, 512, 1.f);
    // kc = ctx @ wk^T + bk -> bf16 [2000][512]
    gemm_mfma<<<dim3(4, 16, 1), 256, 0, stream>>>(cebf, 512, 0, wkbf, 512, 0, bk,
                                                  nullptr, kcbf, 512, 0,
                                                  2000, 512, 512, 1.f);
    // stage-1 scores (b=0, batched over h): bf16 [4][1024][2000]
    gemm_mfma<<<dim3(16, 8, 4), 256, 0, stream>>>(qbf, 512, 128, kcbf, 512, 128,
                                                  nullptr, nullptr, scb,
                                                  2000, 2048000LL,
                                                  1024, 2000, 128, SCALE);
    softmax_colsum_kernel<<<128, 256, 0, stream>>>(scb, part);
    reduce_partials_kernel<<<dim3(8, 4), 256, 0, stream>>>(part, part2);
    topk_kernel<<<1, 64, 0, stream>>>(part2, idx);
    gather_bf_kernel<<<101, 256, 0, stream>>>(cebf, idx, ctxfbf);
    // k2/v2 projections of the 101 selected contexts (MFMA, bf16 out)
    gemm_mfma<<<dim3(4, 1, 1), 256, 0, stream>>>(ctxfbf, 512, 0, wkbf, 512, 0, bk,
                                                 nullptr, k2bf, 512, 0,
                                                 101, 512, 512, 1.f);
    gemm_mfma<<<dim3(4, 1, 1), 256, 0, stream>>>(ctxfbf, 512, 0, wvbf, 512, 0, bv,
                                                 nullptr, v2bf, 512, 0,
                                                 101, 512, 512, 1.f);
    v2tp_kernel<<<256, 256, 0, stream>>>(v2bf, v2tp);
    // fold wo/w_comb: Wc2 = wc @ wo, bc2 = wc @ bo + bc
    bc2_kernel<<<2, 256, 0, stream>>>(wc, bo, bcb, bc2);
    gemm_mfma<<<dim3(4, 4, 1), 256, 0, stream>>>(wcbf, 512, 0, wotbf, 512, 0, nullptr,
                                                 nullptr, wc2bf, 512, 0,
                                                 512, 512, 512, 1.f);
    // stage-2 scores: s2[h][m][n] = SCALE * q_h[m] . k2_h[n], f32, ldc=104
    gemm_mfma<<<dim3(1, 64, 4), 256, 0, stream>>>(qbf, 512, 128, k2bf, 512, 128,
                                                  nullptr, s2, nullptr,
                                                  104, 851968LL,
                                                  8192, 101, 128, SCALE);
    // row softmax over 101 -> bf16 probs padded to 128
    softmax2_kernel<<<256, 256, 0, stream>>>(s2, attnp);
    // o = attn_p @ v2tp^T (per head) -> obf [8192][512] head-interleaved
    gemm_mfma<<<dim3(1, 64, 4), 256, 0, stream>>>(attnp, 128, 1048576LL,
                                                  v2tp, 128, 16384LL, nullptr,
                                                  nullptr, obf, 512, 128,
                                                  8192, 128, 128, 1.f);
    // tmp = o @ Wc2^T + bc2 (f32)
    gemm_mfma<<<dim3(4, 64, 1), 256, 0, stream>>>(obf, 512, 0, wc2bf, 512, 0, bc2,
                                                  tmp, nullptr, 512, 0,
                                                  8192, 512, 512, 1.f);
    // residual + LayerNorm
    ln_kernel<<<8192, 256, 0, stream>>>(tmp, enc, lng, lnb, out);
    (void)in_sizes; (void)n_in; (void)out_size; (void)ws_size;
}

// Round 8
// 249.060 us; speedup vs baseline: 2.4929x; 1.2513x over previous
//
#include <hip/hip_runtime.h>
#include <hip/hip_bf16.h>

// ContextModule R8: gemm_mfma -> BM64xBN128 tile + global_load_lds(16B)
// staging (pre-swizzled global src, linear LDS dest). ws 55.6 MB.

typedef short bhalf8 __attribute__((ext_vector_type(8)));   // 8 bf16 = 4 VGPR
typedef float f32x4 __attribute__((ext_vector_type(4)));

#define SCALE 0.08838834764831845f  // 1/sqrt(128)

// ---- ws layout (float offsets) ----
#define OFF_QBF    ((size_t)0)               // qbf bf16 [8192][512]; later obf
#define OFF_RA     ((size_t)2097152)         // scb bf16 [4][1024][2000]; later s2 f32 [4][8192][104]
#define OFF_RB     ((size_t)6193152)         // encbf -> kcbf -> attn_p
#define OFF_TMP    ((size_t)8290304)         // part/part2/idx early; tmp f32 late
#define OFF_PART   (OFF_TMP)                 // [512][2000] f32
#define OFF_PART2  (OFF_TMP + 1024000)       // [4][2000] f32
#define OFF_IDX    (OFF_TMP + 1032000)       // 128 ints
#define OFF_CEBF   ((size_t)12484608)        // ce bf16 [2000][512]
#define OFF_CTXFBF ((size_t)12996608)        // ctxf bf16 [101][512]
#define OFF_K2BF   ((size_t)13022608)        // k2 bf16 [101][512]
#define OFF_V2BF   ((size_t)13048608)        // v2 bf16 [101][512]
#define OFF_V2TP   ((size_t)13074608)        // v2tp bf16 [4][128][128]
#define OFF_WQBF   ((size_t)13107376)
#define OFF_WKBF   ((size_t)13238448)
#define OFF_WVBF   ((size_t)13369520)
#define OFF_WCBF   ((size_t)13500592)
#define OFF_WOTBF  ((size_t)13631664)
#define OFF_WC2BF  ((size_t)13762736)
#define OFF_BC2    ((size_t)13893808)        // 512
// total 13,894,320 fl = 55.6 MB

__device__ __forceinline__ float bf2f(short u) {
    union { float f; unsigned int i; } x;
    x.i = ((unsigned int)(unsigned short)u) << 16;
    return x.f;
}
__device__ __forceinline__ ushort f2b(float f) {
    union { float f; unsigned int i; } x; x.f = f;
    return (ushort)((x.i + 0x7fff + ((x.i >> 16) & 1)) >> 16);  // RNE
}

// async global->LDS, 16B per lane; LDS dest = wave-uniform base + lane*16
__device__ __forceinline__ void gld16(ushort* lds, const ushort* g) {
    __builtin_amdgcn_global_load_lds(
        (const __attribute__((address_space(1))) unsigned int*)g,
        (__attribute__((address_space(3))) unsigned int*)lds, 16, 0, 0);
}

// f32 -> bf16 bulk convert, 4 elems/thread
__global__ __launch_bounds__(256) void cvt_bf16_kernel(
    const float* __restrict__ in, ushort* __restrict__ out, int n4)
{
    const int i = blockIdx.x * 256 + threadIdx.x;
    if (i >= n4) return;
    const float4 v = ((const float4*)in)[i];
    ushort4 r;
    r.x = f2b(v.x); r.y = f2b(v.y); r.z = f2b(v.z); r.w = f2b(v.w);
    ((ushort4*)out)[i] = r;
}

// 4 x [512][512] weight converts in one launch (blockIdx.y selects matrix)
__global__ __launch_bounds__(256) void cvt4_kernel(
    const float* __restrict__ s0, const float* __restrict__ s1,
    const float* __restrict__ s2p, const float* __restrict__ s3,
    ushort* __restrict__ d0, ushort* __restrict__ d1,
    ushort* __restrict__ d2, ushort* __restrict__ d3)
{
    const int i = blockIdx.x * 256 + threadIdx.x;   // 0..65535
    const float* s; ushort* d;
    switch (blockIdx.y) {
        case 0: s = s0; d = d0; break;
        case 1: s = s1; d = d1; break;
        case 2: s = s2p; d = d2; break;
        default: s = s3; d = d3; break;
    }
    const float4 v = ((const float4*)s)[i];
    ushort4 r;
    r.x = f2b(v.x); r.y = f2b(v.y); r.z = f2b(v.z); r.w = f2b(v.w);
    ((ushort4*)d)[i] = r;
}

// ---------------------------------------------------------------------------
// bf16 MFMA NT GEMM: C[m][n] = alpha*sum_k A[m][k]*W[n][k] (+bias[n])
// Tile 64x128, BK=32, 4 waves (2x2), wave tile 32x64 (2x4 16x16 frags).
// Staging via global_load_lds(16B): LINEAR LDS dest, PRE-SWIZZLED global
// source chunk (c0 ^ (r0&3)); ds_read side swizzle unchanged. OOB rows
// clamp to last valid row (coherent garbage, masked at the store).
// ---------------------------------------------------------------------------
__global__ __launch_bounds__(256) void gemm_mfma(
    const ushort* __restrict__ A, int lda, long long sAz,
    const ushort* __restrict__ W, int ldw, long long sWz,
    const float* __restrict__ bias,
    float* __restrict__ C, ushort* __restrict__ Cbf,
    int ldc, long long sCz,
    int M, int N, int K, float alpha)
{
    __shared__ __align__(16) ushort As[64 * 32];
    __shared__ __align__(16) ushort Bs[128 * 32];
    const int tid = threadIdx.x;
    const int wave = tid >> 6, lane = tid & 63;
    const int wm = wave >> 1, wn = wave & 1;
    const int mr = lane & 15, g = lane >> 4;
    const int bm = blockIdx.y * 64, bn = blockIdx.x * 128;
    A += (size_t)blockIdx.z * (size_t)sAz;
    W += (size_t)blockIdx.z * (size_t)sWz;

    f32x4 acc[2][4];
    #pragma unroll
    for (int i = 0; i < 2; ++i)
        #pragma unroll
        for (int j = 0; j < 4; ++j)
            #pragma unroll
            for (int p = 0; p < 4; ++p) acc[i][j][p] = 0.f;

    const int r0 = tid >> 2;            // 0..63 LDS dest row
    const int c0 = tid & 3;             // LDS dest 16B chunk
    const int cA = (c0 ^ (r0 & 3)) * 8; // pre-swizzled global chunk (ushorts)
    const int rA  = min(bm + r0, M - 1);
    const int rB0 = min(bn + r0, N - 1);
    const int rB1 = min(bn + r0 + 64, N - 1);
    ushort* ldsA  = As + wave * 512;           // wave-uniform bases
    ushort* ldsB0 = Bs + wave * 512;
    ushort* ldsB1 = Bs + 2048 + wave * 512;
    const ushort* gA  = A + (size_t)rA  * lda + cA;
    const ushort* gB0 = W + (size_t)rB0 * ldw + cA;
    const ushort* gB1 = W + (size_t)rB1 * ldw + cA;

    for (int k0 = 0; k0 < K; k0 += 32) {
        gld16(ldsA,  gA  + k0);
        gld16(ldsB0, gB0 + k0);
        gld16(ldsB1, gB1 + k0);
        __syncthreads();   // drain LDS-DMA + all waves issued
        bhalf8 a[2], b[4];
        const int ksw = (g ^ (mr & 3)) << 3;
        #pragma unroll
        for (int i = 0; i < 2; ++i)
            a[i] = *(const bhalf8*)&As[(wm * 32 + i * 16 + mr) * 32 + ksw];
        #pragma unroll
        for (int j = 0; j < 4; ++j)
            b[j] = *(const bhalf8*)&Bs[(wn * 64 + j * 16 + mr) * 32 + ksw];
        #pragma unroll
        for (int i = 0; i < 2; ++i)
            #pragma unroll
            for (int j = 0; j < 4; ++j)
                acc[i][j] = __builtin_amdgcn_mfma_f32_16x16x32_bf16(
                    a[i], b[j], acc[i][j], 0, 0, 0);
        __syncthreads();   // reads done before next overwrite
    }

    if (C)   C   += (size_t)blockIdx.z * (size_t)sCz;
    if (Cbf) Cbf += (size_t)blockIdx.z * (size_t)sCz;
    #pragma unroll
    for (int i = 0; i < 2; ++i) {
        #pragma unroll
        for (int j = 0; j < 4; ++j) {
            const int gn = bn + wn * 64 + j * 16 + mr;
            if (gn >= N) continue;
            const float bb = bias ? bias[gn] : 0.f;
            #pragma unroll
            for (int p = 0; p < 4; ++p) {
                const int gm = bm + wm * 32 + i * 16 + g * 4 + p;
                if (gm >= M) continue;
                const float v = acc[i][j][p] * alpha + bb;
                if (C)   C[(size_t)gm * ldc + gn] = v;
                if (Cbf) Cbf[(size_t)gm * ldc + gn] = f2b(v);
            }
        }
    }
}

// ---------------------------------------------------------------------------
// Stage-1 softmax over n=2000 (bf16 scores) + per-wave partial column sums.
// ---------------------------------------------------------------------------
__global__ __launch_bounds__(256) void softmax_colsum_kernel(
    const ushort* __restrict__ sc, float* __restrict__ part)
{
    const int wave = threadIdx.x >> 6, lane = threadIdx.x & 63;
    const int slot = blockIdx.x * 4 + wave;      // 0..511
    float acc[32];
    #pragma unroll
    for (int i = 0; i < 32; ++i) acc[i] = 0.f;
    for (int rr = 0; rr < 8; ++rr) {
        const unsigned int* row =
            (const unsigned int*)(sc + (size_t)(slot * 8 + rr) * 2000);
        float v[32];
        float m = -1e30f;
        #pragma unroll
        for (int ii = 0; ii < 16; ++ii) {
            const int di = lane + 64 * ii;       // dword index, 1000 per row
            const unsigned int u = (di < 1000) ? row[di] : 0xFF80FF80u;
            v[2 * ii]     = bf2f((short)(u & 0xffff));
            v[2 * ii + 1] = bf2f((short)(u >> 16));
            m = fmaxf(m, fmaxf(v[2 * ii], v[2 * ii + 1]));
        }
        #pragma unroll
        for (int off = 32; off; off >>= 1) m = fmaxf(m, __shfl_xor(m, off));
        float sum = 0.f;
        #pragma unroll
        for (int i = 0; i < 32; ++i) { v[i] = __expf(v[i] - m); sum += v[i]; }
        #pragma unroll
        for (int off = 32; off; off >>= 1) sum += __shfl_xor(sum, off);
        const float inv = 1.f / sum;
        #pragma unroll
        for (int i = 0; i < 32; ++i) acc[i] += v[i] * inv;
    }
    float* p = part + (size_t)slot * 2000;
    #pragma unroll
    for (int ii = 0; ii < 16; ++ii) {
        const int di = lane + 64 * ii;
        if (di < 1000) {
            float2 w; w.x = acc[2 * ii]; w.y = acc[2 * ii + 1];
            ((float2*)p)[di] = w;
        }
    }
}

// part[512][2000] -> part2[4][2000]; grid (8,4)
__global__ void reduce_partials_kernel(const float* __restrict__ part,
                                       float* __restrict__ part2)
{
    const int n = blockIdx.x * 256 + threadIdx.x;
    if (n >= 2000) return;
    const int q = blockIdx.y;
    float s = 0.f;
    for (int sl = q * 128; sl < q * 128 + 128; ++sl) s += part[(size_t)sl * 2000 + n];
    part2[(size_t)q * 2000 + n] = s;
}

// ---------------------------------------------------------------------------
// Top-101 of 2000 via MSB-first radix-select (ballot/popcount; no shuffles,
// no LDS, no barriers). Selection == jax.lax.top_k (lowest index on ties).
// ---------------------------------------------------------------------------
__global__ void topk_kernel(const float* __restrict__ part2,
                            int* __restrict__ idx)
{
    const int lane = threadIdx.x;   // block = 64
    const unsigned long long below = (1ull << lane) - 1ull;

    unsigned key[32];
    #pragma unroll
    for (int i = 0; i < 32; ++i) {
        const int n = lane + 64 * i;
        float s = -1e30f;
        if (n < 2000)
            s = part2[n] + part2[2000 + n] + part2[4000 + n] + part2[6000 + n];
        const unsigned u = __float_as_uint(s);
        key[i] = u ^ ((unsigned)((int)u >> 31) | 0x80000000u);
    }

    unsigned prefix = 0;
    int remaining = 101;
    for (int b = 31; b >= 0; --b) {
        const unsigned tgt = (prefix << 1) | 1u;
        int cnt = 0;
        #pragma unroll
        for (int i = 0; i < 32; ++i)
            cnt += (int)__popcll(__ballot((key[i] >> b) == tgt));
        if (cnt >= remaining) prefix = tgt;
        else { remaining -= cnt; prefix = prefix << 1; }
    }
    const unsigned T = prefix;

    int base = 0;
    #pragma unroll
    for (int i = 0; i < 32; ++i) {
        const unsigned long long m = __ballot(key[i] > T);
        if (key[i] > T) idx[base + (int)__popcll(m & below)] = lane + 64 * i;
        base += (int)__popcll(m);
    }
    int r = remaining;
    #pragma unroll
    for (int i = 0; i < 32; ++i) {
        const unsigned long long m = __ballot(key[i] == T);
        const int cb = (int)__popcll(m & below);
        if (key[i] == T && cb < r) idx[base + cb] = lane + 64 * i;
        const int take = min(r, (int)__popcll(m));
        base += take; r -= take;
    }
}

// gather selected context rows from bf16 ce: one block per row, uint per thread
__global__ void gather_bf_kernel(const ushort* __restrict__ cebf,
                                 const int* __restrict__ idx,
                                 ushort* __restrict__ ctxfbf)
{
    const int r = blockIdx.x;
    const int src = idx[r];
    const int tid = threadIdx.x;
    ((unsigned int*)ctxfbf)[r * 256 + tid] =
        ((const unsigned int*)cebf)[(size_t)src * 256 + tid];
}

// wo [512][512] f32 -> woT bf16 (woT[j][k] = wo[k][j])
__global__ void transpose512_bf(const float* __restrict__ in, ushort* __restrict__ out)
{
    __shared__ float tile[32][33];
    const int tx = threadIdx.x & 31, ty = threadIdx.x >> 5;  // 32x8
    const int bx = blockIdx.x * 32, by = blockIdx.y * 32;
    #pragma unroll
    for (int rr = 0; rr < 4; ++rr)
        tile[ty + 8 * rr][tx] = in[(size_t)(by + ty + 8 * rr) * 512 + bx + tx];
    __syncthreads();
    #pragma unroll
    for (int rr = 0; rr < 4; ++rr)
        out[(size_t)(bx + ty + 8 * rr) * 512 + by + tx] = f2b(tile[tx][ty + 8 * rr]);
}

// v2bf [101][512] -> v2tp [4][128][128]: v2tp[h][d][n] = v2bf[n][h*128+d], 0 pad
__global__ void v2tp_kernel(const ushort* __restrict__ v2bf, ushort* __restrict__ v2tp)
{
    const int e = blockIdx.x * 256 + threadIdx.x;   // 0..65535
    const int h = e >> 14, rem = e & 16383;
    const int d = rem >> 7, n = rem & 127;
    v2tp[e] = (n < 101) ? v2bf[(size_t)n * 512 + h * 128 + d] : (ushort)0;
}

__global__ void bc2_kernel(const float* __restrict__ wc, const float* __restrict__ bo,
                           const float* __restrict__ bcb, float* __restrict__ bc2)
{
    const int d = blockIdx.x * 256 + threadIdx.x;
    float s = bcb[d];
    const float4* wr = (const float4*)(wc + (size_t)d * 512);
    const float4* br = (const float4*)bo;
    for (int m4 = 0; m4 < 128; ++m4) {
        const float4 w4 = wr[m4], b4 = br[m4];
        s += w4.x * b4.x + w4.y * b4.y + w4.z * b4.z + w4.w * b4.w;
    }
    bc2[d] = s;
}

// ---------------------------------------------------------------------------
// Stage-2 row softmax: s2 f32 [4][8192][104] -> attn_p bf16 [4][8192][128]
// ---------------------------------------------------------------------------
__global__ __launch_bounds__(256) void softmax2_kernel(
    const float* __restrict__ s2, ushort* __restrict__ ap)
{
    const int wave = threadIdx.x >> 6, lane = threadIdx.x & 63;
    const int w = blockIdx.x * 4 + wave;       // 0..1023
    const int e0 = 2 * lane, e1 = 2 * lane + 1;
    for (int rr = 0; rr < 32; ++rr) {
        const int row = w * 32 + rr;           // 0..32767
        const float* sr = s2 + (size_t)row * 104;
        float v0 = -1e30f, v1 = -1e30f;
        if (e0 < 101) {
            const float2 t = *(const float2*)(sr + e0);
            v0 = t.x;
            if (e1 < 101) v1 = t.y;
        }
        float m = fmaxf(v0, v1);
        #pragma unroll
        for (int off = 32; off; off >>= 1) m = fmaxf(m, __shfl_xor(m, off));
        const float p0 = (e0 < 101) ? __expf(v0 - m) : 0.f;
        const float p1 = (e1 < 101) ? __expf(v1 - m) : 0.f;
        float sum = p0 + p1;
        #pragma unroll
        for (int off = 32; off; off >>= 1) sum += __shfl_xor(sum, off);
        const float inv = 1.f / sum;
        const unsigned int ow =
            (unsigned int)f2b(p0 * inv) | ((unsigned int)f2b(p1 * inv) << 16);
        ((unsigned int*)ap)[(size_t)row * 64 + lane] = ow;
    }
}

// ---------------------------------------------------------------------------
// Residual + LayerNorm
// ---------------------------------------------------------------------------
__global__ __launch_bounds__(256) void ln_kernel(
    const float* __restrict__ tmp, const float* __restrict__ enc,
    const float* __restrict__ g, const float* __restrict__ bta,
    float* __restrict__ out)
{
    __shared__ float rs[4], rv[4];
    const int row = blockIdx.x, tid = threadIdx.x;
    const int wave = tid >> 6, lane = tid & 63;
    const size_t base = (size_t)row * 512;
    const float x0 = tmp[base + tid] + enc[base + tid];
    const float x1 = tmp[base + tid + 256] + enc[base + tid + 256];
    float s = x0 + x1;
    #pragma unroll
    for (int off = 32; off; off >>= 1) s += __shfl_xor(s, off);
    if (lane == 0) rs[wave] = s;
    __syncthreads();
    const float mu = (rs[0] + rs[1] + rs[2] + rs[3]) * (1.f / 512.f);
    const float d0 = x0 - mu, d1 = x1 - mu;
    float vv = d0 * d0 + d1 * d1;
    #pragma unroll
    for (int off = 32; off; off >>= 1) vv += __shfl_xor(vv, off);
    if (lane == 0) rv[wave] = vv;
    __syncthreads();
    const float var = (rv[0] + rv[1] + rv[2] + rv[3]) * (1.f / 512.f);
    const float rstd = rsqrtf(var + 1e-5f);
    out[base + tid] = d0 * rstd * g[tid] + bta[tid];
    out[base + tid + 256] = d1 * rstd * g[tid + 256] + bta[tid + 256];
}

extern "C" void kernel_launch(void* const* d_in, const int* in_sizes, int n_in,
                              void* d_out, int out_size, void* d_ws, size_t ws_size,
                              hipStream_t stream)
{
    const float* ce  = (const float*)d_in[0];
    const float* enc = (const float*)d_in[1];
    const float* wq  = (const float*)d_in[2];
    const float* bq  = (const float*)d_in[3];
    const float* wk  = (const float*)d_in[4];
    const float* bk  = (const float*)d_in[5];
    const float* wv  = (const float*)d_in[6];
    const float* bv  = (const float*)d_in[7];
    const float* wo  = (const float*)d_in[8];
    const float* bo  = (const float*)d_in[9];
    const float* wc  = (const float*)d_in[10];
    const float* bcb = (const float*)d_in[11];
    const float* lng = (const float*)d_in[12];
    const float* lnb = (const float*)d_in[13];
    float* ws  = (float*)d_ws;
    float* out = (float*)d_out;

    ushort* qbf    = (ushort*)(ws + OFF_QBF);    // later: obf
    ushort* obf    = (ushort*)(ws + OFF_QBF);
    ushort* scb    = (ushort*)(ws + OFF_RA);     // later: s2 (f32)
    float*  s2     = ws + OFF_RA;
    ushort* encbf  = (ushort*)(ws + OFF_RB);     // -> kcbf -> attn_p
    ushort* kcbf   = (ushort*)(ws + OFF_RB);
    ushort* attnp  = (ushort*)(ws + OFF_RB);
    float*  part   = ws + OFF_PART;
    float*  part2  = ws + OFF_PART2;
    int*    idx    = (int*)(ws + OFF_IDX);
    float*  tmp    = ws + OFF_TMP;
    ushort* cebf   = (ushort*)(ws + OFF_CEBF);
    ushort* ctxfbf = (ushort*)(ws + OFF_CTXFBF);
    ushort* k2bf   = (ushort*)(ws + OFF_K2BF);
    ushort* v2bf   = (ushort*)(ws + OFF_V2BF);
    ushort* v2tp   = (ushort*)(ws + OFF_V2TP);
    ushort* wqbf   = (ushort*)(ws + OFF_WQBF);
    ushort* wkbf   = (ushort*)(ws + OFF_WKBF);
    ushort* wvbf   = (ushort*)(ws + OFF_WVBF);
    ushort* wcbf   = (ushort*)(ws + OFF_WCBF);
    ushort* wotbf  = (ushort*)(ws + OFF_WOTBF);
    ushort* wc2bf  = (ushort*)(ws + OFF_WC2BF);
    float*  bc2    = ws + OFF_BC2;

    // bf16 conversions
    cvt_bf16_kernel<<<4096, 256, 0, stream>>>(enc, encbf, 1048576);
    cvt_bf16_kernel<<<1000, 256, 0, stream>>>(ce, cebf, 256000);
    cvt4_kernel<<<dim3(256, 4), 256, 0, stream>>>(wq, wk, wv, wc,
                                                  wqbf, wkbf, wvbf, wcbf);
    transpose512_bf<<<dim3(16, 16), 256, 0, stream>>>(wo, wotbf);

    // q = enc @ wq^T + bq -> bf16 [8192][512]
    gemm_mfma<<<dim3(4, 128, 1), 256, 0, stream>>>(encbf, 512, 0, wqbf, 512, 0, bq,
                                                   nullptr, qbf, 512, 0,
                                                   8192, 512, 512, 1.f);
    // kc = ctx @ wk^T + bk -> bf16 [2000][512]
    gemm_mfma<<<dim3(4, 32, 1), 256, 0, stream>>>(cebf, 512, 0, wkbf, 512, 0, bk,
                                                  nullptr, kcbf, 512, 0,
                                                  2000, 512, 512, 1.f);
    // stage-1 scores (b=0, batched over h): bf16 [4][1024][2000]
    gemm_mfma<<<dim3(16, 16, 4), 256, 0, stream>>>(qbf, 512, 128, kcbf, 512, 128,
                                                   nullptr, nullptr, scb,
                                                   2000, 2048000LL,
                                                   1024, 2000, 128, SCALE);
    softmax_colsum_kernel<<<128, 256, 0, stream>>>(scb, part);
    reduce_partials_kernel<<<dim3(8, 4), 256, 0, stream>>>(part, part2);
    topk_kernel<<<1, 64, 0, stream>>>(part2, idx);
    gather_bf_kernel<<<101, 256, 0, stream>>>(cebf, idx, ctxfbf);
    // k2/v2 projections of the 101 selected contexts (MFMA, bf16 out)
    gemm_mfma<<<dim3(4, 2, 1), 256, 0, stream>>>(ctxfbf, 512, 0, wkbf, 512, 0, bk,
                                                 nullptr, k2bf, 512, 0,
                                                 101, 512, 512, 1.f);
    gemm_mfma<<<dim3(4, 2, 1), 256, 0, stream>>>(ctxfbf, 512, 0, wvbf, 512, 0, bv,
                                                 nullptr, v2bf, 512, 0,
                                                 101, 512, 512, 1.f);
    v2tp_kernel<<<256, 256, 0, stream>>>(v2bf, v2tp);
    // fold wo/w_comb: Wc2 = wc @ wo, bc2 = wc @ bo + bc
    bc2_kernel<<<2, 256, 0, stream>>>(wc, bo, bcb, bc2);
    gemm_mfma<<<dim3(4, 8, 1), 256, 0, stream>>>(wcbf, 512, 0, wotbf, 512, 0, nullptr,
                                                 nullptr, wc2bf, 512, 0,
                                                 512, 512, 512, 1.f);
    // stage-2 scores: s2[h][m][n] = SCALE * q_h[m] . k2_h[n], f32, ldc=104
    gemm_mfma<<<dim3(1, 128, 4), 256, 0, stream>>>(qbf, 512, 128, k2bf, 512, 128,
                                                   nullptr, s2, nullptr,
                                                   104, 851968LL,
                                                   8192, 101, 128, SCALE);
    // row softmax over 101 -> bf16 probs padded to 128
    softmax2_kernel<<<256, 256, 0, stream>>>(s2, attnp);
    // o = attn_p @ v2tp^T (per head) -> obf [8192][512] head-interleaved
    gemm_mfma<<<dim3(1, 128, 4), 256, 0, stream>>>(attnp, 128, 1048576LL,
                                                   v2tp, 128, 16384LL, nullptr,
                                                   nullptr, obf, 512, 128,
                                                   8192, 128, 128, 1.f);
    // tmp = o @ Wc2^T + bc2 (f32)
    gemm_mfma<<<dim3(4, 128, 1), 256, 0, stream>>>(obf, 512, 0, wc2bf, 512, 0, bc2,
                                                   tmp, nullptr, 512, 0,
                                                   8192, 512, 512, 1.f);
    // residual + LayerNorm
    ln_kernel<<<8192, 256, 0, stream>>>(tmp, enc, lng, lnb, out);
    (void)in_sizes; (void)n_in; (void)out_size; (void)ws_size;
}

// Round 9
// 209.669 us; speedup vs baseline: 2.9612x; 1.1879x over previous
//
#include <hip/hip_runtime.h>
#include <hip/hip_bf16.h>

// ContextModule R9: stage-2 attention fused into ONE MFMA kernel
// (QK^T -> in-register softmax -> PV), killing s2/attnp round-trips.
// obf moved to RB region (qbf/obf alias race fixed). ws 55.6 MB.

typedef short bhalf8 __attribute__((ext_vector_type(8)));   // 8 bf16 = 4 VGPR
typedef float f32x4 __attribute__((ext_vector_type(4)));

#define SCALE 0.08838834764831845f  // 1/sqrt(128)

// ---- ws layout (float offsets) ----
#define OFF_QBF    ((size_t)0)               // qbf bf16 [8192][512]
#define OFF_RA     ((size_t)2097152)         // scb bf16 [4][1024][2000]
#define OFF_RB     ((size_t)6193152)         // encbf -> kcbf -> obf bf16 [8192][512]
#define OFF_TMP    ((size_t)8290304)         // part/part2/idx early; tmp f32 late
#define OFF_PART   (OFF_TMP)                 // [512][2000] f32
#define OFF_PART2  (OFF_TMP + 1024000)       // [4][2000] f32
#define OFF_IDX    (OFF_TMP + 1032000)       // 128 ints
#define OFF_CEBF   ((size_t)12484608)        // ce bf16 [2000][512]
#define OFF_CTXFBF ((size_t)12996608)        // ctxf bf16 [101][512]
#define OFF_K2BF   ((size_t)13022608)        // k2 bf16 [101][512]
#define OFF_V2BF   ((size_t)13048608)        // v2 bf16 [101][512]
#define OFF_V2TP   ((size_t)13074608)        // v2tp bf16 [4][128][128]
#define OFF_WQBF   ((size_t)13107376)
#define OFF_WKBF   ((size_t)13238448)
#define OFF_WVBF   ((size_t)13369520)
#define OFF_WCBF   ((size_t)13500592)
#define OFF_WOTBF  ((size_t)13631664)
#define OFF_WC2BF  ((size_t)13762736)
#define OFF_BC2    ((size_t)13893808)        // 512
// total 13,894,320 fl = 55.6 MB

__device__ __forceinline__ float bf2f(short u) {
    union { float f; unsigned int i; } x;
    x.i = ((unsigned int)(unsigned short)u) << 16;
    return x.f;
}
__device__ __forceinline__ ushort f2b(float f) {
    union { float f; unsigned int i; } x; x.f = f;
    return (ushort)((x.i + 0x7fff + ((x.i >> 16) & 1)) >> 16);  // RNE
}

// async global->LDS, 16B per lane; LDS dest = wave-uniform base + lane*16
__device__ __forceinline__ void gld16(ushort* lds, const ushort* g) {
    __builtin_amdgcn_global_load_lds(
        (const __attribute__((address_space(1))) unsigned int*)g,
        (__attribute__((address_space(3))) unsigned int*)lds, 16, 0, 0);
}

// f32 -> bf16 bulk convert, 4 elems/thread
__global__ __launch_bounds__(256) void cvt_bf16_kernel(
    const float* __restrict__ in, ushort* __restrict__ out, int n4)
{
    const int i = blockIdx.x * 256 + threadIdx.x;
    if (i >= n4) return;
    const float4 v = ((const float4*)in)[i];
    ushort4 r;
    r.x = f2b(v.x); r.y = f2b(v.y); r.z = f2b(v.z); r.w = f2b(v.w);
    ((ushort4*)out)[i] = r;
}

// 4 x [512][512] weight converts in one launch (blockIdx.y selects matrix)
__global__ __launch_bounds__(256) void cvt4_kernel(
    const float* __restrict__ s0, const float* __restrict__ s1,
    const float* __restrict__ s2p, const float* __restrict__ s3,
    ushort* __restrict__ d0, ushort* __restrict__ d1,
    ushort* __restrict__ d2, ushort* __restrict__ d3)
{
    const int i = blockIdx.x * 256 + threadIdx.x;   // 0..65535
    const float* s; ushort* d;
    switch (blockIdx.y) {
        case 0: s = s0; d = d0; break;
        case 1: s = s1; d = d1; break;
        case 2: s = s2p; d = d2; break;
        default: s = s3; d = d3; break;
    }
    const float4 v = ((const float4*)s)[i];
    ushort4 r;
    r.x = f2b(v.x); r.y = f2b(v.y); r.z = f2b(v.z); r.w = f2b(v.w);
    ((ushort4*)d)[i] = r;
}

// ---------------------------------------------------------------------------
// bf16 MFMA NT GEMM: C[m][n] = alpha*sum_k A[m][k]*W[n][k] (+bias[n])
// Tile 64x128, BK=32, 4 waves (2x2), global_load_lds staging (pre-swizzled
// global source, linear LDS dest). OOB rows clamp; epilogue guarded.
// ---------------------------------------------------------------------------
__global__ __launch_bounds__(256) void gemm_mfma(
    const ushort* __restrict__ A, int lda, long long sAz,
    const ushort* __restrict__ W, int ldw, long long sWz,
    const float* __restrict__ bias,
    float* __restrict__ C, ushort* __restrict__ Cbf,
    int ldc, long long sCz,
    int M, int N, int K, float alpha)
{
    __shared__ __align__(16) ushort As[64 * 32];
    __shared__ __align__(16) ushort Bs[128 * 32];
    const int tid = threadIdx.x;
    const int wave = tid >> 6, lane = tid & 63;
    const int wm = wave >> 1, wn = wave & 1;
    const int mr = lane & 15, g = lane >> 4;
    const int bm = blockIdx.y * 64, bn = blockIdx.x * 128;
    A += (size_t)blockIdx.z * (size_t)sAz;
    W += (size_t)blockIdx.z * (size_t)sWz;

    f32x4 acc[2][4];
    #pragma unroll
    for (int i = 0; i < 2; ++i)
        #pragma unroll
        for (int j = 0; j < 4; ++j)
            #pragma unroll
            for (int p = 0; p < 4; ++p) acc[i][j][p] = 0.f;

    const int r0 = tid >> 2;            // 0..63 LDS dest row
    const int c0 = tid & 3;             // LDS dest 16B chunk
    const int cA = (c0 ^ (r0 & 3)) * 8; // pre-swizzled global chunk (ushorts)
    const int rA  = min(bm + r0, M - 1);
    const int rB0 = min(bn + r0, N - 1);
    const int rB1 = min(bn + r0 + 64, N - 1);
    ushort* ldsA  = As + wave * 512;           // wave-uniform bases
    ushort* ldsB0 = Bs + wave * 512;
    ushort* ldsB1 = Bs + 2048 + wave * 512;
    const ushort* gA  = A + (size_t)rA  * lda + cA;
    const ushort* gB0 = W + (size_t)rB0 * ldw + cA;
    const ushort* gB1 = W + (size_t)rB1 * ldw + cA;

    for (int k0 = 0; k0 < K; k0 += 32) {
        gld16(ldsA,  gA  + k0);
        gld16(ldsB0, gB0 + k0);
        gld16(ldsB1, gB1 + k0);
        __syncthreads();   // drain LDS-DMA + all waves issued
        bhalf8 a[2], b[4];
        const int ksw = (g ^ (mr & 3)) << 3;
        #pragma unroll
        for (int i = 0; i < 2; ++i)
            a[i] = *(const bhalf8*)&As[(wm * 32 + i * 16 + mr) * 32 + ksw];
        #pragma unroll
        for (int j = 0; j < 4; ++j)
            b[j] = *(const bhalf8*)&Bs[(wn * 64 + j * 16 + mr) * 32 + ksw];
        #pragma unroll
        for (int i = 0; i < 2; ++i)
            #pragma unroll
            for (int j = 0; j < 4; ++j)
                acc[i][j] = __builtin_amdgcn_mfma_f32_16x16x32_bf16(
                    a[i], b[j], acc[i][j], 0, 0, 0);
        __syncthreads();   // reads done before next overwrite
    }

    if (C)   C   += (size_t)blockIdx.z * (size_t)sCz;
    if (Cbf) Cbf += (size_t)blockIdx.z * (size_t)sCz;
    #pragma unroll
    for (int i = 0; i < 2; ++i) {
        #pragma unroll
        for (int j = 0; j < 4; ++j) {
            const int gn = bn + wn * 64 + j * 16 + mr;
            if (gn >= N) continue;
            const float bb = bias ? bias[gn] : 0.f;
            #pragma unroll
            for (int p = 0; p < 4; ++p) {
                const int gm = bm + wm * 32 + i * 16 + g * 4 + p;
                if (gm >= M) continue;
                const float v = acc[i][j][p] * alpha + bb;
                if (C)   C[(size_t)gm * ldc + gn] = v;
                if (Cbf) Cbf[(size_t)gm * ldc + gn] = f2b(v);
            }
        }
    }
}

// ---------------------------------------------------------------------------
// Fused stage-2 attention: per block = 64 Q rows x 1 head.
// LDS: K2s [n][d] (32K), V2s [d][n] (32K), Ps per-wave [r][n] (16K) = 80 KB.
// All LDS reads/writes chunk-XOR swizzled -> conflict-free b128.
// MFMA QK^T (8x4) -> in-register softmax (16-lane-group shfl_xor) ->
// P bf16 -> wave-private LDS -> MFMA PV (8x4) -> obf.
// One barrier total (after K2/V2 staging).
// ---------------------------------------------------------------------------
__global__ __launch_bounds__(256) void attn2_fused(
    const ushort* __restrict__ qb,   // [8192][512]
    const ushort* __restrict__ k2bf, // [101][512]
    const ushort* __restrict__ v2tp, // [4][128][128] d-major, n>=101 zeroed
    ushort* __restrict__ obf)        // [8192][512]
{
    __shared__ __align__(16) ushort K2s[128 * 128];
    __shared__ __align__(16) ushort V2s[128 * 128];
    __shared__ __align__(16) ushort Ps[4 * 16 * 128];
    const int tid = threadIdx.x, w = tid >> 6, lane = tid & 63;
    const int mr = lane & 15, g = lane >> 4;
    const int h = blockIdx.y;
    const int bm = blockIdx.x * 64;

    // stage K2s (rows >= 101 zeroed) and V2s, swizzled chunk ^= (row&7)
    #pragma unroll
    for (int it = 0; it < 8; ++it) {
        const int cl = tid + 256 * it;      // 0..2047
        const int n = cl >> 4, c = cl & 15;
        uint4 kv = make_uint4(0u, 0u, 0u, 0u);
        if (n < 101)
            kv = *(const uint4*)(k2bf + (size_t)n * 512 + h * 128 + c * 8);
        *(uint4*)&K2s[(n << 7) + ((c ^ (n & 7)) << 3)] = kv;
        const uint4 vv = *(const uint4*)(v2tp + (((size_t)h << 7) + n) * 128 + c * 8);
        *(uint4*)&V2s[(n << 7) + ((c ^ (n & 7)) << 3)] = vv;
    }
    __syncthreads();

    // ---- QK^T: s[r][n], r = wave-local rows (16), A direct from global ----
    f32x4 sacc[8];
    #pragma unroll
    for (int jn = 0; jn < 8; ++jn)
        #pragma unroll
        for (int p = 0; p < 4; ++p) sacc[jn][p] = 0.f;
    const ushort* qrow = qb + (size_t)(bm + (w << 4) + mr) * 512 + (h << 7);
    #pragma unroll
    for (int kd = 0; kd < 4; ++kd) {
        const bhalf8 aq = *(const bhalf8*)(qrow + (g << 3) + (kd << 5));
        #pragma unroll
        for (int jn = 0; jn < 8; ++jn) {
            const int n = (jn << 4) + mr;
            const bhalf8 bk = *(const bhalf8*)
                &K2s[(n << 7) + ((((kd << 2) + g) ^ (n & 7)) << 3)];
            sacc[jn] = __builtin_amdgcn_mfma_f32_16x16x32_bf16(aq, bk, sacc[jn], 0, 0, 0);
        }
    }

    // ---- softmax over n (mask n>=101); row r = g*4+p lives in 16-lane group ----
    float mrow[4] = {-1e30f, -1e30f, -1e30f, -1e30f};
    #pragma unroll
    for (int jn = 0; jn < 8; ++jn) {
        const bool valid = (jn < 6) || (jn == 6 && mr < 5);
        #pragma unroll
        for (int p = 0; p < 4; ++p) {
            const float s = valid ? sacc[jn][p] * SCALE : -1e30f;
            sacc[jn][p] = s;
            mrow[p] = fmaxf(mrow[p], s);
        }
    }
    #pragma unroll
    for (int off = 1; off <= 8; off <<= 1)
        #pragma unroll
        for (int p = 0; p < 4; ++p)
            mrow[p] = fmaxf(mrow[p], __shfl_xor(mrow[p], off));
    float srow[4] = {0.f, 0.f, 0.f, 0.f};
    #pragma unroll
    for (int jn = 0; jn < 8; ++jn)
        #pragma unroll
        for (int p = 0; p < 4; ++p) {
            const float e = __expf(sacc[jn][p] - mrow[p]);  // masked -> ~0
            sacc[jn][p] = e;
            srow[p] += e;
        }
    #pragma unroll
    for (int off = 1; off <= 8; off <<= 1)
        #pragma unroll
        for (int p = 0; p < 4; ++p)
            srow[p] += __shfl_xor(srow[p], off);
    float inv[4];
    #pragma unroll
    for (int p = 0; p < 4; ++p) inv[p] = 1.f / srow[p];

    // ---- P -> wave-private LDS (bf16, swizzled) ----
    ushort* pw = Ps + (w << 11);
    #pragma unroll
    for (int jn = 0; jn < 8; ++jn) {
        const int cb = (jn << 1) + (mr >> 3);       // n>>3
        #pragma unroll
        for (int p = 0; p < 4; ++p) {
            const int r = (g << 2) + p;
            pw[(r << 7) + ((cb ^ (r & 7)) << 3) + (mr & 7)] =
                f2b(sacc[jn][p] * inv[p]);
        }
    }

    // ---- PV: o[r][d] = sum_n P[r][n] * V[n][d] (B = V2s[d][n]) ----
    f32x4 oacc[8];
    #pragma unroll
    for (int jd = 0; jd < 8; ++jd)
        #pragma unroll
        for (int p = 0; p < 4; ++p) oacc[jd][p] = 0.f;
    #pragma unroll
    for (int kn = 0; kn < 4; ++kn) {
        const int ck = (kn << 2) + g;               // n>>3 for this k-slice
        const bhalf8 ap = *(const bhalf8*)
            &pw[(mr << 7) + ((ck ^ (mr & 7)) << 3)];
        #pragma unroll
        for (int jd = 0; jd < 8; ++jd) {
            const int d = (jd << 4) + mr;
            const bhalf8 bv = *(const bhalf8*)
                &V2s[(d << 7) + ((ck ^ (d & 7)) << 3)];
            oacc[jd] = __builtin_amdgcn_mfma_f32_16x16x32_bf16(ap, bv, oacc[jd], 0, 0, 0);
        }
    }

    // ---- store o (bf16, head-interleaved [8192][512]) ----
    #pragma unroll
    for (int jd = 0; jd < 8; ++jd)
        #pragma unroll
        for (int p = 0; p < 4; ++p) {
            const int row = bm + (w << 4) + (g << 2) + p;
            obf[(size_t)row * 512 + (h << 7) + (jd << 4) + mr] = f2b(oacc[jd][p]);
        }
}

// ---------------------------------------------------------------------------
// Stage-1 softmax over n=2000 (bf16 scores) + per-wave partial column sums.
// ---------------------------------------------------------------------------
__global__ __launch_bounds__(256) void softmax_colsum_kernel(
    const ushort* __restrict__ sc, float* __restrict__ part)
{
    const int wave = threadIdx.x >> 6, lane = threadIdx.x & 63;
    const int slot = blockIdx.x * 4 + wave;      // 0..511
    float acc[32];
    #pragma unroll
    for (int i = 0; i < 32; ++i) acc[i] = 0.f;
    for (int rr = 0; rr < 8; ++rr) {
        const unsigned int* row =
            (const unsigned int*)(sc + (size_t)(slot * 8 + rr) * 2000);
        float v[32];
        float m = -1e30f;
        #pragma unroll
        for (int ii = 0; ii < 16; ++ii) {
            const int di = lane + 64 * ii;       // dword index, 1000 per row
            const unsigned int u = (di < 1000) ? row[di] : 0xFF80FF80u;
            v[2 * ii]     = bf2f((short)(u & 0xffff));
            v[2 * ii + 1] = bf2f((short)(u >> 16));
            m = fmaxf(m, fmaxf(v[2 * ii], v[2 * ii + 1]));
        }
        #pragma unroll
        for (int off = 32; off; off >>= 1) m = fmaxf(m, __shfl_xor(m, off));
        float sum = 0.f;
        #pragma unroll
        for (int i = 0; i < 32; ++i) { v[i] = __expf(v[i] - m); sum += v[i]; }
        #pragma unroll
        for (int off = 32; off; off >>= 1) sum += __shfl_xor(sum, off);
        const float inv = 1.f / sum;
        #pragma unroll
        for (int i = 0; i < 32; ++i) acc[i] += v[i] * inv;
    }
    float* p = part + (size_t)slot * 2000;
    #pragma unroll
    for (int ii = 0; ii < 16; ++ii) {
        const int di = lane + 64 * ii;
        if (di < 1000) {
            float2 w; w.x = acc[2 * ii]; w.y = acc[2 * ii + 1];
            ((float2*)p)[di] = w;
        }
    }
}

// part[512][2000] -> part2[4][2000]; grid (8,4)
__global__ void reduce_partials_kernel(const float* __restrict__ part,
                                       float* __restrict__ part2)
{
    const int n = blockIdx.x * 256 + threadIdx.x;
    if (n >= 2000) return;
    const int q = blockIdx.y;
    float s = 0.f;
    for (int sl = q * 128; sl < q * 128 + 128; ++sl) s += part[(size_t)sl * 2000 + n];
    part2[(size_t)q * 2000 + n] = s;
}

// ---------------------------------------------------------------------------
// Top-101 of 2000 via MSB-first radix-select (ballot/popcount; no shuffles,
// no LDS, no barriers). Selection == jax.lax.top_k (lowest index on ties).
// ---------------------------------------------------------------------------
__global__ void topk_kernel(const float* __restrict__ part2,
                            int* __restrict__ idx)
{
    const int lane = threadIdx.x;   // block = 64
    const unsigned long long below = (1ull << lane) - 1ull;

    unsigned key[32];
    #pragma unroll
    for (int i = 0; i < 32; ++i) {
        const int n = lane + 64 * i;
        float s = -1e30f;
        if (n < 2000)
            s = part2[n] + part2[2000 + n] + part2[4000 + n] + part2[6000 + n];
        const unsigned u = __float_as_uint(s);
        key[i] = u ^ ((unsigned)((int)u >> 31) | 0x80000000u);
    }

    unsigned prefix = 0;
    int remaining = 101;
    for (int b = 31; b >= 0; --b) {
        const unsigned tgt = (prefix << 1) | 1u;
        int cnt = 0;
        #pragma unroll
        for (int i = 0; i < 32; ++i)
            cnt += (int)__popcll(__ballot((key[i] >> b) == tgt));
        if (cnt >= remaining) prefix = tgt;
        else { remaining -= cnt; prefix = prefix << 1; }
    }
    const unsigned T = prefix;

    int base = 0;
    #pragma unroll
    for (int i = 0; i < 32; ++i) {
        const unsigned long long m = __ballot(key[i] > T);
        if (key[i] > T) idx[base + (int)__popcll(m & below)] = lane + 64 * i;
        base += (int)__popcll(m);
    }
    int r = remaining;
    #pragma unroll
    for (int i = 0; i < 32; ++i) {
        const unsigned long long m = __ballot(key[i] == T);
        const int cb = (int)__popcll(m & below);
        if (key[i] == T && cb < r) idx[base + cb] = lane + 64 * i;
        const int take = min(r, (int)__popcll(m));
        base += take; r -= take;
    }
}

// gather selected context rows from bf16 ce: one block per row, uint per thread
__global__ void gather_bf_kernel(const ushort* __restrict__ cebf,
                                 const int* __restrict__ idx,
                                 ushort* __restrict__ ctxfbf)
{
    const int r = blockIdx.x;
    const int src = idx[r];
    const int tid = threadIdx.x;
    ((unsigned int*)ctxfbf)[r * 256 + tid] =
        ((const unsigned int*)cebf)[(size_t)src * 256 + tid];
}

// wo [512][512] f32 -> woT bf16 (woT[j][k] = wo[k][j])
__global__ void transpose512_bf(const float* __restrict__ in, ushort* __restrict__ out)
{
    __shared__ float tile[32][33];
    const int tx = threadIdx.x & 31, ty = threadIdx.x >> 5;  // 32x8
    const int bx = blockIdx.x * 32, by = blockIdx.y * 32;
    #pragma unroll
    for (int rr = 0; rr < 4; ++rr)
        tile[ty + 8 * rr][tx] = in[(size_t)(by + ty + 8 * rr) * 512 + bx + tx];
    __syncthreads();
    #pragma unroll
    for (int rr = 0; rr < 4; ++rr)
        out[(size_t)(bx + ty + 8 * rr) * 512 + by + tx] = f2b(tile[tx][ty + 8 * rr]);
}

// v2bf [101][512] -> v2tp [4][128][128]: v2tp[h][d][n] = v2bf[n][h*128+d], 0 pad
__global__ void v2tp_kernel(const ushort* __restrict__ v2bf, ushort* __restrict__ v2tp)
{
    const int e = blockIdx.x * 256 + threadIdx.x;   // 0..65535
    const int h = e >> 14, rem = e & 16383;
    const int d = rem >> 7, n = rem & 127;
    v2tp[e] = (n < 101) ? v2bf[(size_t)n * 512 + h * 128 + d] : (ushort)0;
}

__global__ void bc2_kernel(const float* __restrict__ wc, const float* __restrict__ bo,
                           const float* __restrict__ bcb, float* __restrict__ bc2)
{
    const int d = blockIdx.x * 256 + threadIdx.x;
    float s = bcb[d];
    const float4* wr = (const float4*)(wc + (size_t)d * 512);
    const float4* br = (const float4*)bo;
    for (int m4 = 0; m4 < 128; ++m4) {
        const float4 w4 = wr[m4], b4 = br[m4];
        s += w4.x * b4.x + w4.y * b4.y + w4.z * b4.z + w4.w * b4.w;
    }
    bc2[d] = s;
}

// ---------------------------------------------------------------------------
// Residual + LayerNorm
// ---------------------------------------------------------------------------
__global__ __launch_bounds__(256) void ln_kernel(
    const float* __restrict__ tmp, const float* __restrict__ enc,
    const float* __restrict__ g, const float* __restrict__ bta,
    float* __restrict__ out)
{
    __shared__ float rs[4], rv[4];
    const int row = blockIdx.x, tid = threadIdx.x;
    const int wave = tid >> 6, lane = tid & 63;
    const size_t base = (size_t)row * 512;
    const float x0 = tmp[base + tid] + enc[base + tid];
    const float x1 = tmp[base + tid + 256] + enc[base + tid + 256];
    float s = x0 + x1;
    #pragma unroll
    for (int off = 32; off; off >>= 1) s += __shfl_xor(s, off);
    if (lane == 0) rs[wave] = s;
    __syncthreads();
    const float mu = (rs[0] + rs[1] + rs[2] + rs[3]) * (1.f / 512.f);
    const float d0 = x0 - mu, d1 = x1 - mu;
    float vv = d0 * d0 + d1 * d1;
    #pragma unroll
    for (int off = 32; off; off >>= 1) vv += __shfl_xor(vv, off);
    if (lane == 0) rv[wave] = vv;
    __syncthreads();
    const float var = (rv[0] + rv[1] + rv[2] + rv[3]) * (1.f / 512.f);
    const float rstd = rsqrtf(var + 1e-5f);
    out[base + tid] = d0 * rstd * g[tid] + bta[tid];
    out[base + tid + 256] = d1 * rstd * g[tid + 256] + bta[tid + 256];
}

extern "C" void kernel_launch(void* const* d_in, const int* in_sizes, int n_in,
                              void* d_out, int out_size, void* d_ws, size_t ws_size,
                              hipStream_t stream)
{
    const float* ce  = (const float*)d_in[0];
    const float* enc = (const float*)d_in[1];
    const float* wq  = (const float*)d_in[2];
    const float* bq  = (const float*)d_in[3];
    const float* wk  = (const float*)d_in[4];
    const float* bk  = (const float*)d_in[5];
    const float* wv  = (const float*)d_in[6];
    const float* bv  = (const float*)d_in[7];
    const float* wo  = (const float*)d_in[8];
    const float* bo  = (const float*)d_in[9];
    const float* wc  = (const float*)d_in[10];
    const float* bcb = (const float*)d_in[11];
    const float* lng = (const float*)d_in[12];
    const float* lnb = (const float*)d_in[13];
    float* ws  = (float*)d_ws;
    float* out = (float*)d_out;

    ushort* qbf    = (ushort*)(ws + OFF_QBF);
    ushort* scb    = (ushort*)(ws + OFF_RA);
    ushort* encbf  = (ushort*)(ws + OFF_RB);     // -> kcbf -> obf
    ushort* kcbf   = (ushort*)(ws + OFF_RB);
    ushort* obf    = (ushort*)(ws + OFF_RB);
    float*  part   = ws + OFF_PART;
    float*  part2  = ws + OFF_PART2;
    int*    idx    = (int*)(ws + OFF_IDX);
    float*  tmp    = ws + OFF_TMP;
    ushort* cebf   = (ushort*)(ws + OFF_CEBF);
    ushort* ctxfbf = (ushort*)(ws + OFF_CTXFBF);
    ushort* k2bf   = (ushort*)(ws + OFF_K2BF);
    ushort* v2bf   = (ushort*)(ws + OFF_V2BF);
    ushort* v2tp   = (ushort*)(ws + OFF_V2TP);
    ushort* wqbf   = (ushort*)(ws + OFF_WQBF);
    ushort* wkbf   = (ushort*)(ws + OFF_WKBF);
    ushort* wvbf   = (ushort*)(ws + OFF_WVBF);
    ushort* wcbf   = (ushort*)(ws + OFF_WCBF);
    ushort* wotbf  = (ushort*)(ws + OFF_WOTBF);
    ushort* wc2bf  = (ushort*)(ws + OFF_WC2BF);
    float*  bc2    = ws + OFF_BC2;

    // bf16 conversions
    cvt_bf16_kernel<<<4096, 256, 0, stream>>>(enc, encbf, 1048576);
    cvt_bf16_kernel<<<1000, 256, 0, stream>>>(ce, cebf, 256000);
    cvt4_kernel<<<dim3(256, 4), 256, 0, stream>>>(wq, wk, wv, wc,
                                                  wqbf, wkbf, wvbf, wcbf);
    transpose512_bf<<<dim3(16, 16), 256, 0, stream>>>(wo, wotbf);

    // q = enc @ wq^T + bq -> bf16 [8192][512]
    gemm_mfma<<<dim3(4, 128, 1), 256, 0, stream>>>(encbf, 512, 0, wqbf, 512, 0, bq,
                                                   nullptr, qbf, 512, 0,
                                                   8192, 512, 512, 1.f);
    // kc = ctx @ wk^T + bk -> bf16 [2000][512]
    gemm_mfma<<<dim3(4, 32, 1), 256, 0, stream>>>(cebf, 512, 0, wkbf, 512, 0, bk,
                                                  nullptr, kcbf, 512, 0,
                                                  2000, 512, 512, 1.f);
    // stage-1 scores (b=0, batched over h): bf16 [4][1024][2000]
    gemm_mfma<<<dim3(16, 16, 4), 256, 0, stream>>>(qbf, 512, 128, kcbf, 512, 128,
                                                   nullptr, nullptr, scb,
                                                   2000, 2048000LL,
                                                   1024, 2000, 128, SCALE);
    softmax_colsum_kernel<<<128, 256, 0, stream>>>(scb, part);
    reduce_partials_kernel<<<dim3(8, 4), 256, 0, stream>>>(part, part2);
    topk_kernel<<<1, 64, 0, stream>>>(part2, idx);
    gather_bf_kernel<<<101, 256, 0, stream>>>(cebf, idx, ctxfbf);
    // k2/v2 projections of the 101 selected contexts (MFMA, bf16 out)
    gemm_mfma<<<dim3(4, 2, 1), 256, 0, stream>>>(ctxfbf, 512, 0, wkbf, 512, 0, bk,
                                                 nullptr, k2bf, 512, 0,
                                                 101, 512, 512, 1.f);
    gemm_mfma<<<dim3(4, 2, 1), 256, 0, stream>>>(ctxfbf, 512, 0, wvbf, 512, 0, bv,
                                                 nullptr, v2bf, 512, 0,
                                                 101, 512, 512, 1.f);
    v2tp_kernel<<<256, 256, 0, stream>>>(v2bf, v2tp);
    // fold wo/w_comb: Wc2 = wc @ wo, bc2 = wc @ bo + bc
    bc2_kernel<<<2, 256, 0, stream>>>(wc, bo, bcb, bc2);
    gemm_mfma<<<dim3(4, 8, 1), 256, 0, stream>>>(wcbf, 512, 0, wotbf, 512, 0, nullptr,
                                                 nullptr, wc2bf, 512, 0,
                                                 512, 512, 512, 1.f);
    // fused stage-2 attention: qbf x k2bf/v2tp -> obf (RB region)
    attn2_fused<<<dim3(128, 4), 256, 0, stream>>>(qbf, k2bf, v2tp, obf);
    // tmp = o @ Wc2^T + bc2 (f32)
    gemm_mfma<<<dim3(4, 128, 1), 256, 0, stream>>>(obf, 512, 0, wc2bf, 512, 0, bc2,
                                                   tmp, nullptr, 512, 0,
                                                   8192, 512, 512, 1.f);
    // residual + LayerNorm
    ln_kernel<<<8192, 256, 0, stream>>>(tmp, enc, lng, lnb, out);
    (void)in_sizes; (void)n_in; (void)out_size; (void)ws_size;
}

// Round 10
// 188.740 us; speedup vs baseline: 3.2896x; 1.1109x over previous
//
#include <hip/hip_runtime.h>
#include <hip/hip_bf16.h>

// ContextModule R10: proj+residual+LN fused (no tmp); prep merged to 1 launch;
// k2/v2/v2tp fused; colsum uint4 loads. 14 dispatches. ws 55.6 MB.

typedef short bhalf8 __attribute__((ext_vector_type(8)));   // 8 bf16 = 4 VGPR
typedef float f32x4 __attribute__((ext_vector_type(4)));

#define SCALE 0.08838834764831845f  // 1/sqrt(128)

// ---- ws layout (float offsets) ----
#define OFF_QBF    ((size_t)0)               // qbf bf16 [8192][512]
#define OFF_RA     ((size_t)2097152)         // scb bf16 [4][1024][2000]
#define OFF_RB     ((size_t)6193152)         // encbf -> kcbf -> obf bf16 [8192][512]
#define OFF_TMP    ((size_t)8290304)         // part/part2/idx
#define OFF_PART   (OFF_TMP)                 // [512][2000] f32
#define OFF_PART2  (OFF_TMP + 1024000)       // [4][2000] f32
#define OFF_IDX    (OFF_TMP + 1032000)       // 128 ints
#define OFF_CEBF   ((size_t)12484608)        // ce bf16 [2000][512]
#define OFF_CTXFBF ((size_t)12996608)        // ctxf bf16 [101][512]
#define OFF_K2BF   ((size_t)13022608)        // k2 bf16 [101][512]
#define OFF_V2BF   ((size_t)13048608)        // (unused this round)
#define OFF_V2TP   ((size_t)13074608)        // v2tp bf16 [4][128][128]
#define OFF_WQBF   ((size_t)13107376)
#define OFF_WKBF   ((size_t)13238448)
#define OFF_WVBF   ((size_t)13369520)
#define OFF_WCBF   ((size_t)13500592)
#define OFF_WOTBF  ((size_t)13631664)
#define OFF_WC2BF  ((size_t)13762736)
#define OFF_BC2    ((size_t)13893808)        // 512
// total 13,894,320 fl = 55.6 MB

__device__ __forceinline__ float bf2f(short u) {
    union { float f; unsigned int i; } x;
    x.i = ((unsigned int)(unsigned short)u) << 16;
    return x.f;
}
__device__ __forceinline__ ushort f2b(float f) {
    union { float f; unsigned int i; } x; x.f = f;
    return (ushort)((x.i + 0x7fff + ((x.i >> 16) & 1)) >> 16);  // RNE
}

// async global->LDS, 16B per lane; LDS dest = wave-uniform base + lane*16
__device__ __forceinline__ void gld16(ushort* lds, const ushort* g) {
    __builtin_amdgcn_global_load_lds(
        (const __attribute__((address_space(1))) unsigned int*)g,
        (__attribute__((address_space(3))) unsigned int*)lds, 16, 0, 0);
}

// ---------------------------------------------------------------------------
// prep: ALL f32->bf16 conversions + v2tp zero-fill in one launch.
// Flattened grid: [0,4096) enc | [4096,5096) ce | +256 each wq,wk,wv,wc |
// [6120,6152) zero v2tp (8192 uint4).
// ---------------------------------------------------------------------------
__global__ __launch_bounds__(256) void prep_kernel(
    const float* __restrict__ enc, const float* __restrict__ ce,
    const float* __restrict__ wq, const float* __restrict__ wk,
    const float* __restrict__ wv, const float* __restrict__ wc,
    ushort* __restrict__ encbf, ushort* __restrict__ cebf,
    ushort* __restrict__ wqbf, ushort* __restrict__ wkbf,
    ushort* __restrict__ wvbf, ushort* __restrict__ wcbf,
    ushort* __restrict__ v2tp)
{
    const int b = blockIdx.x;
    const float* s; ushort* d; int n4, base;
    if (b < 4096)      { s = enc; d = encbf; n4 = 1048576; base = b; }
    else if (b < 5096) { s = ce;  d = cebf;  n4 = 256000;  base = b - 4096; }
    else if (b < 5352) { s = wq;  d = wqbf;  n4 = 65536;   base = b - 5096; }
    else if (b < 5608) { s = wk;  d = wkbf;  n4 = 65536;   base = b - 5352; }
    else if (b < 5864) { s = wv;  d = wvbf;  n4 = 65536;   base = b - 5608; }
    else if (b < 6120) { s = wc;  d = wcbf;  n4 = 65536;   base = b - 5864; }
    else {
        const int i = (b - 6120) * 256 + threadIdx.x;  // 8192 uint4
        ((uint4*)v2tp)[i] = make_uint4(0u, 0u, 0u, 0u);
        return;
    }
    const int i = base * 256 + threadIdx.x;
    if (i >= n4) return;
    const float4 v = ((const float4*)s)[i];
    ushort4 r;
    r.x = f2b(v.x); r.y = f2b(v.y); r.z = f2b(v.z); r.w = f2b(v.w);
    ((ushort4*)d)[i] = r;
}

// ---------------------------------------------------------------------------
// bf16 MFMA NT GEMM (unchanged from R8/R9): 64x128 tile, BK=32,
// global_load_lds staging with pre-swizzled global source.
// ---------------------------------------------------------------------------
__global__ __launch_bounds__(256) void gemm_mfma(
    const ushort* __restrict__ A, int lda, long long sAz,
    const ushort* __restrict__ W, int ldw, long long sWz,
    const float* __restrict__ bias,
    float* __restrict__ C, ushort* __restrict__ Cbf,
    int ldc, long long sCz,
    int M, int N, int K, float alpha)
{
    __shared__ __align__(16) ushort As[64 * 32];
    __shared__ __align__(16) ushort Bs[128 * 32];
    const int tid = threadIdx.x;
    const int wave = tid >> 6, lane = tid & 63;
    const int wm = wave >> 1, wn = wave & 1;
    const int mr = lane & 15, g = lane >> 4;
    const int bm = blockIdx.y * 64, bn = blockIdx.x * 128;
    A += (size_t)blockIdx.z * (size_t)sAz;
    W += (size_t)blockIdx.z * (size_t)sWz;

    f32x4 acc[2][4];
    #pragma unroll
    for (int i = 0; i < 2; ++i)
        #pragma unroll
        for (int j = 0; j < 4; ++j)
            #pragma unroll
            for (int p = 0; p < 4; ++p) acc[i][j][p] = 0.f;

    const int r0 = tid >> 2;            // 0..63 LDS dest row
    const int c0 = tid & 3;             // LDS dest 16B chunk
    const int cA = (c0 ^ (r0 & 3)) * 8; // pre-swizzled global chunk (ushorts)
    const int rA  = min(bm + r0, M - 1);
    const int rB0 = min(bn + r0, N - 1);
    const int rB1 = min(bn + r0 + 64, N - 1);
    ushort* ldsA  = As + wave * 512;           // wave-uniform bases
    ushort* ldsB0 = Bs + wave * 512;
    ushort* ldsB1 = Bs + 2048 + wave * 512;
    const ushort* gA  = A + (size_t)rA  * lda + cA;
    const ushort* gB0 = W + (size_t)rB0 * ldw + cA;
    const ushort* gB1 = W + (size_t)rB1 * ldw + cA;

    for (int k0 = 0; k0 < K; k0 += 32) {
        gld16(ldsA,  gA  + k0);
        gld16(ldsB0, gB0 + k0);
        gld16(ldsB1, gB1 + k0);
        __syncthreads();
        bhalf8 a[2], b[4];
        const int ksw = (g ^ (mr & 3)) << 3;
        #pragma unroll
        for (int i = 0; i < 2; ++i)
            a[i] = *(const bhalf8*)&As[(wm * 32 + i * 16 + mr) * 32 + ksw];
        #pragma unroll
        for (int j = 0; j < 4; ++j)
            b[j] = *(const bhalf8*)&Bs[(wn * 64 + j * 16 + mr) * 32 + ksw];
        #pragma unroll
        for (int i = 0; i < 2; ++i)
            #pragma unroll
            for (int j = 0; j < 4; ++j)
                acc[i][j] = __builtin_amdgcn_mfma_f32_16x16x32_bf16(
                    a[i], b[j], acc[i][j], 0, 0, 0);
        __syncthreads();
    }

    if (C)   C   += (size_t)blockIdx.z * (size_t)sCz;
    if (Cbf) Cbf += (size_t)blockIdx.z * (size_t)sCz;
    #pragma unroll
    for (int i = 0; i < 2; ++i) {
        #pragma unroll
        for (int j = 0; j < 4; ++j) {
            const int gn = bn + wn * 64 + j * 16 + mr;
            if (gn >= N) continue;
            const float bb = bias ? bias[gn] : 0.f;
            #pragma unroll
            for (int p = 0; p < 4; ++p) {
                const int gm = bm + wm * 32 + i * 16 + g * 4 + p;
                if (gm >= M) continue;
                const float v = acc[i][j][p] * alpha + bb;
                if (C)   C[(size_t)gm * ldc + gn] = v;
                if (Cbf) Cbf[(size_t)gm * ldc + gn] = f2b(v);
            }
        }
    }
}

// ---------------------------------------------------------------------------
// Fused k2/v2 projections of the 101 selected contexts.
// z=0: k2 = ctxf@wk^T+bk -> k2bf [101][512].
// z=1: v2 = ctxf@wv^T+bv -> v2tp[gn*128+gm] (transposed-padded; pad rows
//      pre-zeroed by prep). Same GEMM body as gemm_mfma, M=101 N=512 K=512.
// ---------------------------------------------------------------------------
__global__ __launch_bounds__(256) void kv2_proj(
    const ushort* __restrict__ ctxfbf,
    const ushort* __restrict__ wkbf, const ushort* __restrict__ wvbf,
    const float* __restrict__ bk, const float* __restrict__ bv,
    ushort* __restrict__ k2bf, ushort* __restrict__ v2tp)
{
    __shared__ __align__(16) ushort As[64 * 32];
    __shared__ __align__(16) ushort Bs[128 * 32];
    const int z = blockIdx.z;
    const ushort* W = z ? wvbf : wkbf;
    const float* bias = z ? bv : bk;
    const int tid = threadIdx.x;
    const int wave = tid >> 6, lane = tid & 63;
    const int wm = wave >> 1, wn = wave & 1;
    const int mr = lane & 15, g = lane >> 4;
    const int bm = blockIdx.y * 64, bn = blockIdx.x * 128;

    f32x4 acc[2][4];
    #pragma unroll
    for (int i = 0; i < 2; ++i)
        #pragma unroll
        for (int j = 0; j < 4; ++j)
            #pragma unroll
            for (int p = 0; p < 4; ++p) acc[i][j][p] = 0.f;

    const int r0 = tid >> 2, c0 = tid & 3;
    const int cA = (c0 ^ (r0 & 3)) * 8;
    const int rA  = min(bm + r0, 100);
    ushort* ldsA  = As + wave * 512;
    ushort* ldsB0 = Bs + wave * 512;
    ushort* ldsB1 = Bs + 2048 + wave * 512;
    const ushort* gA  = ctxfbf + (size_t)rA * 512 + cA;
    const ushort* gB0 = W + (size_t)(bn + r0) * 512 + cA;
    const ushort* gB1 = W + (size_t)(bn + r0 + 64) * 512 + cA;

    for (int k0 = 0; k0 < 512; k0 += 32) {
        gld16(ldsA,  gA  + k0);
        gld16(ldsB0, gB0 + k0);
        gld16(ldsB1, gB1 + k0);
        __syncthreads();
        bhalf8 a[2], b[4];
        const int ksw = (g ^ (mr & 3)) << 3;
        #pragma unroll
        for (int i = 0; i < 2; ++i)
            a[i] = *(const bhalf8*)&As[(wm * 32 + i * 16 + mr) * 32 + ksw];
        #pragma unroll
        for (int j = 0; j < 4; ++j)
            b[j] = *(const bhalf8*)&Bs[(wn * 64 + j * 16 + mr) * 32 + ksw];
        #pragma unroll
        for (int i = 0; i < 2; ++i)
            #pragma unroll
            for (int j = 0; j < 4; ++j)
                acc[i][j] = __builtin_amdgcn_mfma_f32_16x16x32_bf16(
                    a[i], b[j], acc[i][j], 0, 0, 0);
        __syncthreads();
    }

    #pragma unroll
    for (int i = 0; i < 2; ++i) {
        #pragma unroll
        for (int j = 0; j < 4; ++j) {
            const int gn = bn + wn * 64 + j * 16 + mr;
            const float bb = bias[gn];
            #pragma unroll
            for (int p = 0; p < 4; ++p) {
                const int gm = bm + wm * 32 + i * 16 + g * 4 + p;
                if (gm >= 101) continue;
                const ushort v = f2b(acc[i][j][p] + bb);
                if (z == 0) k2bf[(size_t)gm * 512 + gn] = v;
                else        v2tp[(size_t)gn * 128 + gm] = v;
            }
        }
    }
}

// ---------------------------------------------------------------------------
// Fused stage-2 attention (unchanged from R9).
// ---------------------------------------------------------------------------
__global__ __launch_bounds__(256) void attn2_fused(
    const ushort* __restrict__ qb, const ushort* __restrict__ k2bf,
    const ushort* __restrict__ v2tp, ushort* __restrict__ obf)
{
    __shared__ __align__(16) ushort K2s[128 * 128];
    __shared__ __align__(16) ushort V2s[128 * 128];
    __shared__ __align__(16) ushort Ps[4 * 16 * 128];
    const int tid = threadIdx.x, w = tid >> 6, lane = tid & 63;
    const int mr = lane & 15, g = lane >> 4;
    const int h = blockIdx.y;
    const int bm = blockIdx.x * 64;

    #pragma unroll
    for (int it = 0; it < 8; ++it) {
        const int cl = tid + 256 * it;      // 0..2047
        const int n = cl >> 4, c = cl & 15;
        uint4 kv = make_uint4(0u, 0u, 0u, 0u);
        if (n < 101)
            kv = *(const uint4*)(k2bf + (size_t)n * 512 + h * 128 + c * 8);
        *(uint4*)&K2s[(n << 7) + ((c ^ (n & 7)) << 3)] = kv;
        const uint4 vv = *(const uint4*)(v2tp + (((size_t)h << 7) + n) * 128 + c * 8);
        *(uint4*)&V2s[(n << 7) + ((c ^ (n & 7)) << 3)] = vv;
    }
    __syncthreads();

    f32x4 sacc[8];
    #pragma unroll
    for (int jn = 0; jn < 8; ++jn)
        #pragma unroll
        for (int p = 0; p < 4; ++p) sacc[jn][p] = 0.f;
    const ushort* qrow = qb + (size_t)(bm + (w << 4) + mr) * 512 + (h << 7);
    #pragma unroll
    for (int kd = 0; kd < 4; ++kd) {
        const bhalf8 aq = *(const bhalf8*)(qrow + (g << 3) + (kd << 5));
        #pragma unroll
        for (int jn = 0; jn < 8; ++jn) {
            const int n = (jn << 4) + mr;
            const bhalf8 bk = *(const bhalf8*)
                &K2s[(n << 7) + ((((kd << 2) + g) ^ (n & 7)) << 3)];
            sacc[jn] = __builtin_amdgcn_mfma_f32_16x16x32_bf16(aq, bk, sacc[jn], 0, 0, 0);
        }
    }

    float mrow[4] = {-1e30f, -1e30f, -1e30f, -1e30f};
    #pragma unroll
    for (int jn = 0; jn < 8; ++jn) {
        const bool valid = (jn < 6) || (jn == 6 && mr < 5);
        #pragma unroll
        for (int p = 0; p < 4; ++p) {
            const float s = valid ? sacc[jn][p] * SCALE : -1e30f;
            sacc[jn][p] = s;
            mrow[p] = fmaxf(mrow[p], s);
        }
    }
    #pragma unroll
    for (int off = 1; off <= 8; off <<= 1)
        #pragma unroll
        for (int p = 0; p < 4; ++p)
            mrow[p] = fmaxf(mrow[p], __shfl_xor(mrow[p], off));
    float srow[4] = {0.f, 0.f, 0.f, 0.f};
    #pragma unroll
    for (int jn = 0; jn < 8; ++jn)
        #pragma unroll
        for (int p = 0; p < 4; ++p) {
            const float e = __expf(sacc[jn][p] - mrow[p]);
            sacc[jn][p] = e;
            srow[p] += e;
        }
    #pragma unroll
    for (int off = 1; off <= 8; off <<= 1)
        #pragma unroll
        for (int p = 0; p < 4; ++p)
            srow[p] += __shfl_xor(srow[p], off);
    float inv[4];
    #pragma unroll
    for (int p = 0; p < 4; ++p) inv[p] = 1.f / srow[p];

    ushort* pw = Ps + (w << 11);
    #pragma unroll
    for (int jn = 0; jn < 8; ++jn) {
        const int cb = (jn << 1) + (mr >> 3);
        #pragma unroll
        for (int p = 0; p < 4; ++p) {
            const int r = (g << 2) + p;
            pw[(r << 7) + ((cb ^ (r & 7)) << 3) + (mr & 7)] =
                f2b(sacc[jn][p] * inv[p]);
        }
    }

    f32x4 oacc[8];
    #pragma unroll
    for (int jd = 0; jd < 8; ++jd)
        #pragma unroll
        for (int p = 0; p < 4; ++p) oacc[jd][p] = 0.f;
    #pragma unroll
    for (int kn = 0; kn < 4; ++kn) {
        const int ck = (kn << 2) + g;
        const bhalf8 ap = *(const bhalf8*)
            &pw[(mr << 7) + ((ck ^ (mr & 7)) << 3)];
        #pragma unroll
        for (int jd = 0; jd < 8; ++jd) {
            const int d = (jd << 4) + mr;
            const bhalf8 bv = *(const bhalf8*)
                &V2s[(d << 7) + ((ck ^ (d & 7)) << 3)];
            oacc[jd] = __builtin_amdgcn_mfma_f32_16x16x32_bf16(ap, bv, oacc[jd], 0, 0, 0);
        }
    }

    #pragma unroll
    for (int jd = 0; jd < 8; ++jd)
        #pragma unroll
        for (int p = 0; p < 4; ++p) {
            const int row = bm + (w << 4) + (g << 2) + p;
            obf[(size_t)row * 512 + (h << 7) + (jd << 4) + mr] = f2b(oacc[jd][p]);
        }
}

// ---------------------------------------------------------------------------
// Stage-1 softmax + colsum partials; uint4 loads (250 uint4 = one 2000-row).
// ---------------------------------------------------------------------------
__global__ __launch_bounds__(256) void softmax_colsum_kernel(
    const ushort* __restrict__ sc, float* __restrict__ part)
{
    const int wave = threadIdx.x >> 6, lane = threadIdx.x & 63;
    const int slot = blockIdx.x * 4 + wave;      // 0..511
    float acc[32];
    #pragma unroll
    for (int i = 0; i < 32; ++i) acc[i] = 0.f;
    for (int rr = 0; rr < 8; ++rr) {
        const uint4* row = (const uint4*)(sc + (size_t)(slot * 8 + rr) * 2000);
        float v[32];
        float m = -1e30f;
        #pragma unroll
        for (int ii = 0; ii < 4; ++ii) {
            const int di4 = lane + 64 * ii;      // uint4 index, 250 per row
            uint4 u = make_uint4(0xFF80FF80u, 0xFF80FF80u, 0xFF80FF80u, 0xFF80FF80u);
            if (di4 < 250) u = row[di4];
            const unsigned uu[4] = {u.x, u.y, u.z, u.w};
            #pragma unroll
            for (int q = 0; q < 4; ++q) {
                v[ii * 8 + 2 * q]     = bf2f((short)(uu[q] & 0xffff));
                v[ii * 8 + 2 * q + 1] = bf2f((short)(uu[q] >> 16));
                m = fmaxf(m, fmaxf(v[ii * 8 + 2 * q], v[ii * 8 + 2 * q + 1]));
            }
        }
        #pragma unroll
        for (int off = 32; off; off >>= 1) m = fmaxf(m, __shfl_xor(m, off));
        float sum = 0.f;
        #pragma unroll
        for (int i = 0; i < 32; ++i) { v[i] = __expf(v[i] - m); sum += v[i]; }
        #pragma unroll
        for (int off = 32; off; off >>= 1) sum += __shfl_xor(sum, off);
        const float inv = 1.f / sum;
        #pragma unroll
        for (int i = 0; i < 32; ++i) acc[i] += v[i] * inv;
    }
    float* p = part + (size_t)slot * 2000;
    #pragma unroll
    for (int ii = 0; ii < 4; ++ii) {
        const int di4 = lane + 64 * ii;
        if (di4 < 250) {
            float4 a0, a1;
            a0.x = acc[ii*8+0]; a0.y = acc[ii*8+1]; a0.z = acc[ii*8+2]; a0.w = acc[ii*8+3];
            a1.x = acc[ii*8+4]; a1.y = acc[ii*8+5]; a1.z = acc[ii*8+6]; a1.w = acc[ii*8+7];
            ((float4*)(p + 8 * di4))[0] = a0;
            ((float4*)(p + 8 * di4))[1] = a1;
        }
    }
}

// part[512][2000] -> part2[4][2000]; grid (8,4)
__global__ void reduce_partials_kernel(const float* __restrict__ part,
                                       float* __restrict__ part2)
{
    const int n = blockIdx.x * 256 + threadIdx.x;
    if (n >= 2000) return;
    const int q = blockIdx.y;
    float s = 0.f;
    for (int sl = q * 128; sl < q * 128 + 128; ++sl) s += part[(size_t)sl * 2000 + n];
    part2[(size_t)q * 2000 + n] = s;
}

// ---------------------------------------------------------------------------
// Top-101 of 2000 via MSB-first radix-select (ballot/popcount).
// ---------------------------------------------------------------------------
__global__ void topk_kernel(const float* __restrict__ part2,
                            int* __restrict__ idx)
{
    const int lane = threadIdx.x;   // block = 64
    const unsigned long long below = (1ull << lane) - 1ull;

    unsigned key[32];
    #pragma unroll
    for (int i = 0; i < 32; ++i) {
        const int n = lane + 64 * i;
        float s = -1e30f;
        if (n < 2000)
            s = part2[n] + part2[2000 + n] + part2[4000 + n] + part2[6000 + n];
        const unsigned u = __float_as_uint(s);
        key[i] = u ^ ((unsigned)((int)u >> 31) | 0x80000000u);
    }

    unsigned prefix = 0;
    int remaining = 101;
    for (int b = 31; b >= 0; --b) {
        const unsigned tgt = (prefix << 1) | 1u;
        int cnt = 0;
        #pragma unroll
        for (int i = 0; i < 32; ++i)
            cnt += (int)__popcll(__ballot((key[i] >> b) == tgt));
        if (cnt >= remaining) prefix = tgt;
        else { remaining -= cnt; prefix = prefix << 1; }
    }
    const unsigned T = prefix;

    int base = 0;
    #pragma unroll
    for (int i = 0; i < 32; ++i) {
        const unsigned long long m = __ballot(key[i] > T);
        if (key[i] > T) idx[base + (int)__popcll(m & below)] = lane + 64 * i;
        base += (int)__popcll(m);
    }
    int r = remaining;
    #pragma unroll
    for (int i = 0; i < 32; ++i) {
        const unsigned long long m = __ballot(key[i] == T);
        const int cb = (int)__popcll(m & below);
        if (key[i] == T && cb < r) idx[base + cb] = lane + 64 * i;
        const int take = min(r, (int)__popcll(m));
        base += take; r -= take;
    }
}

__global__ void gather_bf_kernel(const ushort* __restrict__ cebf,
                                 const int* __restrict__ idx,
                                 ushort* __restrict__ ctxfbf)
{
    const int r = blockIdx.x;
    const int src = idx[r];
    const int tid = threadIdx.x;
    ((unsigned int*)ctxfbf)[r * 256 + tid] =
        ((const unsigned int*)cebf)[(size_t)src * 256 + tid];
}

// wo [512][512] f32 -> woT bf16
__global__ void transpose512_bf(const float* __restrict__ in, ushort* __restrict__ out)
{
    __shared__ float tile[32][33];
    const int tx = threadIdx.x & 31, ty = threadIdx.x >> 5;  // 32x8
    const int bx = blockIdx.x * 32, by = blockIdx.y * 32;
    #pragma unroll
    for (int rr = 0; rr < 4; ++rr)
        tile[ty + 8 * rr][tx] = in[(size_t)(by + ty + 8 * rr) * 512 + bx + tx];
    __syncthreads();
    #pragma unroll
    for (int rr = 0; rr < 4; ++rr)
        out[(size_t)(bx + ty + 8 * rr) * 512 + by + tx] = f2b(tile[tx][ty + 8 * rr]);
}

__global__ void bc2_kernel(const float* __restrict__ wc, const float* __restrict__ bo,
                           const float* __restrict__ bcb, float* __restrict__ bc2)
{
    const int d = blockIdx.x * 256 + threadIdx.x;
    float s = bcb[d];
    const float4* wr = (const float4*)(wc + (size_t)d * 512);
    const float4* br = (const float4*)bo;
    for (int m4 = 0; m4 < 128; ++m4) {
        const float4 w4 = wr[m4], b4 = br[m4];
        s += w4.x * b4.x + w4.y * b4.y + w4.z * b4.z + w4.w * b4.w;
    }
    bc2[d] = s;
}

// ---------------------------------------------------------------------------
// Fused final projection + residual + LayerNorm:
// out = LN(obf@Wc2^T + bc2 + enc) * g + b. BM=32, BN=512 (full rows), grid
// 256. Wave w: row-half rh=w&1 (16 rows), col-half ch=w>>1 (256 cols,
// 16 j-frags). Row stats: 16-lane shfl reduce + LDS cross-col-half combine.
// ---------------------------------------------------------------------------
__global__ __launch_bounds__(256) void proj_ln(
    const ushort* __restrict__ obf, const ushort* __restrict__ wc2bf,
    const float* __restrict__ bc2, const float* __restrict__ enc,
    const float* __restrict__ gw, const float* __restrict__ bta,
    float* __restrict__ out)
{
    __shared__ __align__(16) ushort As[32 * 32];
    __shared__ __align__(16) ushort Bs[512 * 32];
    __shared__ float red1[2][32], red2[2][32];
    const int tid = threadIdx.x, w = tid >> 6, lane = tid & 63;
    const int mr = lane & 15, gq = lane >> 4;
    const int rh = w & 1, ch = w >> 1;
    const int bm = blockIdx.x * 32;

    f32x4 acc[16];
    #pragma unroll
    for (int j = 0; j < 16; ++j)
        #pragma unroll
        for (int p = 0; p < 4; ++p) acc[j][p] = 0.f;

    const int lr = lane >> 2, lc = lane & 3;
    const int swc = (lc ^ (lr & 3)) * 8;
    // A: waves 0,1 load 16 rows each
    ushort* ldsA = As + ((w & 1) << 9);
    const ushort* gA = obf + (size_t)(bm + ((w & 1) << 4) + lr) * 512 + swc;

    for (int k0 = 0; k0 < 512; k0 += 32) {
        if (w < 2) gld16(ldsA, gA + k0);
        #pragma unroll
        for (int r = 0; r < 8; ++r) {
            const int nb = r * 4 + w;          // 0..31, 16 B-rows each
            gld16(Bs + nb * 512,
                  wc2bf + (size_t)(nb * 16 + lr) * 512 + swc + k0);
        }
        __syncthreads();
        const int ksw = (gq ^ (mr & 3)) << 3;
        const bhalf8 a = *(const bhalf8*)&As[(((rh << 4) + mr) << 5) + ksw];
        #pragma unroll
        for (int j = 0; j < 16; ++j) {
            const int n = (ch << 8) + (j << 4) + mr;
            const bhalf8 b = *(const bhalf8*)&Bs[(n << 5) + ksw];
            acc[j] = __builtin_amdgcn_mfma_f32_16x16x32_bf16(a, b, acc[j], 0, 0, 0);
        }
        __syncthreads();
    }

    // add bc2 + enc residual; accumulate row sums s1,s2 per p
    float s1[4] = {0.f, 0.f, 0.f, 0.f}, s2[4] = {0.f, 0.f, 0.f, 0.f};
    #pragma unroll
    for (int j = 0; j < 16; ++j) {
        const int gcol = (ch << 8) + (j << 4) + mr;
        const float bb = bc2[gcol];
        #pragma unroll
        for (int p = 0; p < 4; ++p) {
            const int grow = bm + (rh << 4) + (gq << 2) + p;
            const float x = acc[j][p] + bb + enc[(size_t)grow * 512 + gcol];
            acc[j][p] = x;
            s1[p] += x;
            s2[p] += x * x;
        }
    }
    #pragma unroll
    for (int off = 1; off <= 8; off <<= 1)
        #pragma unroll
        for (int p = 0; p < 4; ++p) {
            s1[p] += __shfl_xor(s1[p], off);
            s2[p] += __shfl_xor(s2[p], off);
        }
    if (mr == 0) {
        #pragma unroll
        for (int p = 0; p < 4; ++p) {
            red1[ch][(rh << 4) + (gq << 2) + p] = s1[p];
            red2[ch][(rh << 4) + (gq << 2) + p] = s2[p];
        }
    }
    __syncthreads();
    float mu[4], rstd[4];
    #pragma unroll
    for (int p = 0; p < 4; ++p) {
        const int ri = (rh << 4) + (gq << 2) + p;
        const float t1 = red1[0][ri] + red1[1][ri];
        const float t2 = red2[0][ri] + red2[1][ri];
        const float m = t1 * (1.f / 512.f);
        mu[p] = m;
        rstd[p] = rsqrtf(t2 * (1.f / 512.f) - m * m + 1e-5f);
    }
    #pragma unroll
    for (int j = 0; j < 16; ++j) {
        const int gcol = (ch << 8) + (j << 4) + mr;
        const float gg = gw[gcol], bb = bta[gcol];
        #pragma unroll
        for (int p = 0; p < 4; ++p) {
            const int grow = bm + (rh << 4) + (gq << 2) + p;
            out[(size_t)grow * 512 + gcol] = (acc[j][p] - mu[p]) * rstd[p] * gg + bb;
        }
    }
}

extern "C" void kernel_launch(void* const* d_in, const int* in_sizes, int n_in,
                              void* d_out, int out_size, void* d_ws, size_t ws_size,
                              hipStream_t stream)
{
    const float* ce  = (const float*)d_in[0];
    const float* enc = (const float*)d_in[1];
    const float* wq  = (const float*)d_in[2];
    const float* bq  = (const float*)d_in[3];
    const float* wk  = (const float*)d_in[4];
    const float* bk  = (const float*)d_in[5];
    const float* wv  = (const float*)d_in[6];
    const float* bv  = (const float*)d_in[7];
    const float* wo  = (const float*)d_in[8];
    const float* bo  = (const float*)d_in[9];
    const float* wc  = (const float*)d_in[10];
    const float* bcb = (const float*)d_in[11];
    const float* lng = (const float*)d_in[12];
    const float* lnb = (const float*)d_in[13];
    float* ws  = (float*)d_ws;
    float* out = (float*)d_out;

    ushort* qbf    = (ushort*)(ws + OFF_QBF);
    ushort* scb    = (ushort*)(ws + OFF_RA);
    ushort* encbf  = (ushort*)(ws + OFF_RB);     // -> kcbf -> obf
    ushort* kcbf   = (ushort*)(ws + OFF_RB);
    ushort* obf    = (ushort*)(ws + OFF_RB);
    float*  part   = ws + OFF_PART;
    float*  part2  = ws + OFF_PART2;
    int*    idx    = (int*)(ws + OFF_IDX);
    ushort* cebf   = (ushort*)(ws + OFF_CEBF);
    ushort* ctxfbf = (ushort*)(ws + OFF_CTXFBF);
    ushort* k2bf   = (ushort*)(ws + OFF_K2BF);
    ushort* v2tp   = (ushort*)(ws + OFF_V2TP);
    ushort* wqbf   = (ushort*)(ws + OFF_WQBF);
    ushort* wkbf   = (ushort*)(ws + OFF_WKBF);
    ushort* wvbf   = (ushort*)(ws + OFF_WVBF);
    ushort* wcbf   = (ushort*)(ws + OFF_WCBF);
    ushort* wotbf  = (ushort*)(ws + OFF_WOTBF);
    ushort* wc2bf  = (ushort*)(ws + OFF_WC2BF);
    float*  bc2    = ws + OFF_BC2;

    // all conversions + v2tp zero in one launch
    prep_kernel<<<6152, 256, 0, stream>>>(enc, ce, wq, wk, wv, wc,
                                          encbf, cebf, wqbf, wkbf, wvbf, wcbf,
                                          v2tp);
    transpose512_bf<<<dim3(16, 16), 256, 0, stream>>>(wo, wotbf);

    // q = enc @ wq^T + bq -> bf16 [8192][512]
    gemm_mfma<<<dim3(4, 128, 1), 256, 0, stream>>>(encbf, 512, 0, wqbf, 512, 0, bq,
                                                   nullptr, qbf, 512, 0,
                                                   8192, 512, 512, 1.f);
    // kc = ctx @ wk^T + bk -> bf16 [2000][512]
    gemm_mfma<<<dim3(4, 32, 1), 256, 0, stream>>>(cebf, 512, 0, wkbf, 512, 0, bk,
                                                  nullptr, kcbf, 512, 0,
                                                  2000, 512, 512, 1.f);
    // stage-1 scores (b=0, batched over h): bf16 [4][1024][2000]
    gemm_mfma<<<dim3(16, 16, 4), 256, 0, stream>>>(qbf, 512, 128, kcbf, 512, 128,
                                                   nullptr, nullptr, scb,
                                                   2000, 2048000LL,
                                                   1024, 2000, 128, SCALE);
    softmax_colsum_kernel<<<128, 256, 0, stream>>>(scb, part);
    reduce_partials_kernel<<<dim3(8, 4), 256, 0, stream>>>(part, part2);
    topk_kernel<<<1, 64, 0, stream>>>(part2, idx);
    gather_bf_kernel<<<101, 256, 0, stream>>>(cebf, idx, ctxfbf);
    // fused k2 (z=0) / v2-transposed (z=1) projections
    kv2_proj<<<dim3(4, 2, 2), 256, 0, stream>>>(ctxfbf, wkbf, wvbf, bk, bv,
                                                k2bf, v2tp);
    // fold wo/w_comb: Wc2 = wc @ wo, bc2 = wc @ bo + bc
    bc2_kernel<<<2, 256, 0, stream>>>(wc, bo, bcb, bc2);
    gemm_mfma<<<dim3(4, 8, 1), 256, 0, stream>>>(wcbf, 512, 0, wotbf, 512, 0, nullptr,
                                                 nullptr, wc2bf, 512, 0,
                                                 512, 512, 512, 1.f);
    // fused stage-2 attention -> obf (RB region)
    attn2_fused<<<dim3(128, 4), 256, 0, stream>>>(qbf, k2bf, v2tp, obf);
    // fused final projection + residual + LayerNorm -> out
    proj_ln<<<256, 256, 0, stream>>>(obf, wc2bf, bc2, enc, lng, lnb, out);
    (void)in_sizes; (void)n_in; (void)out_size; (void)ws_size;
}